// Round 2
// baseline (1028.220 us; speedup 1.0000x reference)
//
#include <hip/hip_runtime.h>
#include <hip/hip_cooperative_groups.h>
#include <math.h>

namespace cg = cooperative_groups;

#define GRID 512
#define NBLK 512
#define NTHR 256
static const int Bb = 32, Ls = 512, Dd = 768, Cc = 97;

struct KArgs {
    const float *x0, *pos1, *pos2;
    const int* mask;
    const float *emb, *rel_w, *rel_b, *kw, *vw, *vb, *sw, *gw, *gb;
    const float *fc1w, *fc1b, *fc2w, *fc2b;
    float* out;
    float *p0b, *pp, *sc, *avx1, *avx2, *av1, *av2, *aw1, *aw2, *S0, *S1, *xp1, *xp2, *geb;
    float *kvecs, *pdots, *g1buf, *xd, *gx1, *gx2, *awb;
    float* zbase;
    int zcount;
};

__device__ __forceinline__ float sigm(float x) { return 1.f / (1.f + expf(-x)); }

__device__ __forceinline__ float wred(float v) {
#pragma unroll
    for (int o = 32; o > 0; o >>= 1) v += __shfl_down(v, o, 64);
    return v;
}

__device__ __forceinline__ float blk_sum4(float v, float* shr) {
    v = wred(v);
    int t = threadIdx.x;
    if ((t & 63) == 0) shr[t >> 6] = v;
    __syncthreads();
    float r = shr[0] + shr[1] + shr[2] + shr[3];
    __syncthreads();
    return r;
}

// ---- split-K SGEMM tile: C += A[:,kb:kb+KC]@W[kb:kb+KC,:] (+bias at bz==0); C pre-zeroed
__device__ void sgemm_dev(const float* __restrict__ A, const float* __restrict__ W,
                          const float* __restrict__ bias, float* __restrict__ C,
                          int M, int N, int K, int KC, int bx, int by, int bz,
                          float* As, float* Ws) {
    int tid = threadIdx.x;
    int tx = tid & 15, ty = tid >> 4;
    int bn = bx * 64, bm = by * 64;
    int kb = bz * KC;
    int arow = tid >> 2, akq = (tid & 3) << 2;
    int wrow = tid >> 4, wcol = (tid & 15) << 2;
    int gar = bm + arow;
    bool aval = gar < M;
    const float* Ap = A + (size_t)gar * K + kb + akq;
    const float* Wp = W + (size_t)(kb + wrow) * N + bn + wcol;
    float acc[4][4] = {{0.f}};
    float4 a4 = make_float4(0.f, 0.f, 0.f, 0.f);
    if (aval) a4 = *(const float4*)Ap;
    float4 w4 = *(const float4*)Wp;
    for (int k0 = 0; k0 < KC; k0 += 16) {
        __syncthreads();
        As[(akq + 0) * 64 + arow] = a4.x; As[(akq + 1) * 64 + arow] = a4.y;
        As[(akq + 2) * 64 + arow] = a4.z; As[(akq + 3) * 64 + arow] = a4.w;
        *(float4*)&Ws[wrow * 64 + wcol] = w4;
        __syncthreads();
        if (k0 + 16 < KC) {
            if (aval) a4 = *(const float4*)(Ap + k0 + 16);
            w4 = *(const float4*)(Wp + (size_t)(k0 + 16) * N);
        }
#pragma unroll
        for (int kk = 0; kk < 16; ++kk) {
            float4 a = *(const float4*)&As[kk * 64 + (ty << 2)];
            float4 b = *(const float4*)&Ws[kk * 64 + (tx << 2)];
            acc[0][0]+=a.x*b.x; acc[0][1]+=a.x*b.y; acc[0][2]+=a.x*b.z; acc[0][3]+=a.x*b.w;
            acc[1][0]+=a.y*b.x; acc[1][1]+=a.y*b.y; acc[1][2]+=a.y*b.z; acc[1][3]+=a.y*b.w;
            acc[2][0]+=a.z*b.x; acc[2][1]+=a.z*b.y; acc[2][2]+=a.z*b.z; acc[2][3]+=a.z*b.w;
            acc[3][0]+=a.w*b.x; acc[3][1]+=a.w*b.y; acc[3][2]+=a.w*b.z; acc[3][3]+=a.w*b.w;
        }
    }
    int gc = bn + (tx << 2);
    float4 bz4 = make_float4(0.f, 0.f, 0.f, 0.f);
    if (bz == 0 && bias) bz4 = *(const float4*)(bias + gc);
#pragma unroll
    for (int i = 0; i < 4; ++i) {
        int gr = bm + (ty << 2) + i;
        if (gr < M) {
            float* cp = C + (size_t)gr * N + gc;
            atomicAdd(cp + 0, acc[i][0] + bz4.x); atomicAdd(cp + 1, acc[i][1] + bz4.y);
            atomicAdd(cp + 2, acc[i][2] + bz4.z); atomicAdd(cp + 3, acc[i][3] + bz4.w);
        }
    }
}

// ---- fused relation-attention + V-GEMV bank; jlin in [0,768): jt%3, b, kseg/96
__device__ void attn_gemv(const KArgs& a, int phase, int jlin,
                          float* xs, float* lw, float* shr) {
    int t = threadIdx.x;
    int jt = jlin % 3, b = (jlin / 3) % 32, kseg = jlin / 96;
    float v = -3.0e38f, g1 = 0.f;
    if (t < Cc) {
        if (phase == 0) v = a.pdots[t];
        else {
            g1 = sigm(a.pdots[194 + t] + a.sc[128 + b] + a.gb[1]);
            v = 2.f * a.pdots[97 + t] + g1 * a.sc[160 + b];
        }
    }
    if (phase == 1 && jt == 0 && kseg == 0 && t < Cc) a.g1buf[(size_t)b * Cc + t] = g1;
    float m = v;
#pragma unroll
    for (int o = 32; o > 0; o >>= 1) m = fmaxf(m, __shfl_down(m, o, 64));
    if ((t & 63) == 0) shr[t >> 6] = m;
    __syncthreads();
    m = fmaxf(fmaxf(shr[0], shr[1]), fmaxf(shr[2], shr[3]));
    __syncthreads();
    float e = (t < Cc) ? expf(v - m) : 0.f;
    float s = blk_sum4(e, shr);
    float wc = e / s;
    if (t < Cc) lw[t] = wc;
    float cg1 = blk_sum4(wc * g1, shr);   // publishes lw
    float alpha = (phase == 0) ? 1.f : 2.f;
    if (t < 96) {
        int d = kseg * 96 + t;
        const float* pc = a.p0b + d;
        float acc2 = 0.f;
#pragma unroll 4
        for (int c = 0; c < Cc; ++c) acc2 += lw[c] * pc[(size_t)c * Dd];
        float val = alpha * acc2;
        if (phase == 1) val += cg1 * a.av1[(size_t)b * Dd + d];
        xs[t] = val;
    }
    __syncthreads();
    const float* W = a.vw + (size_t)(phase == 0 ? 0 : 2) * Dd * Dd;
    const float* bias = a.vb + (phase == 0 ? 0 : 2) * Dd;
    float* outp = (phase == 0) ? a.avx1 : a.avx2;
    int j = jt * 256 + t;
    float acc = (kseg == 0) ? bias[j] : 0.f;
    const float* wp = W + (size_t)(kseg * 96) * Dd + j;
#pragma unroll 8
    for (int dd = 0; dd < 96; ++dd) acc += xs[dd] * wp[(size_t)dd * Dd];
    atomicAdd(&outp[(size_t)b * Dd + j], acc);
    const float* da[4]; const float* db[4]; int nd; float* dout;
    if (phase == 0) {
        da[0]=a.gw;          db[0]=nullptr;
        da[1]=a.kvecs+Dd;    db[1]=nullptr;
        da[2]=a.gw+3072;     db[2]=a.gw+3840;
        da[3]=a.kvecs+3*Dd;  db[3]=nullptr;
        nd = 4; dout = a.sc;
    } else {
        da[0]=a.gw+3072;     db[0]=nullptr;
        da[1]=a.kvecs+3*Dd;  db[1]=nullptr;
        nd = 2; dout = a.sc + 224;
    }
    for (int vv = 0; vv < nd; ++vv) {
        float wv = da[vv][j] + (db[vv] ? db[vv][j] : 0.f);
        float p = blk_sum4(acc * wv, shr);
        if (t == 0) atomicAdd(&dout[vv * 32 + b], p);
    }
    __syncthreads();
}

// ---- GEMV bank: out[b,:] += xs@Wseg; xs = gamma*S + multA*coefA[b]*avA + multB*coefB[b]*avB
__device__ void mm_dev(const KArgs& a, int jlin, const float* S, float gamma,
                       const float* avA, const float* coefA, float multA,
                       const float* avB, const float* coefB, float multB,
                       const float* W, const float* bias, float* outp,
                       int ndots, const float* d0a, const float* d0b,
                       const float* d1a, const float* d2a, const float* d2b,
                       float* dout, float* xs, float* shr) {
    int t = threadIdx.x;
    int jt = jlin % 3, b = (jlin / 3) % 32, kseg = jlin / 96;
    if (t < 96) {
        int d = kseg * 96 + t;
        float v = gamma * S[(size_t)b * Dd + d];
        if (avA) v += multA * coefA[b] * avA[(size_t)b * Dd + d];
        if (avB) v += multB * coefB[b] * avB[(size_t)b * Dd + d];
        xs[t] = v;
    }
    __syncthreads();
    int j = jt * 256 + t;
    float acc = (kseg == 0 && bias) ? bias[j] : 0.f;
    const float* wp = W + (size_t)(kseg * 96) * Dd + j;
#pragma unroll 8
    for (int dd = 0; dd < 96; ++dd) acc += xs[dd] * wp[(size_t)dd * Dd];
    atomicAdd(&outp[(size_t)b * Dd + j], acc);
    if (ndots > 0) {
        float wv = d0a[j] + (d0b ? d0b[j] : 0.f);
        float p = blk_sum4(acc * wv, shr);
        if (t == 0) atomicAdd(&dout[b], p);
    }
    if (ndots > 1) {
        float p = blk_sum4(acc * d1a[j], shr);
        if (t == 0) atomicAdd(&dout[32 + b], p);
    }
    if (ndots > 2) {
        float wv = d2a[j] + (d2b ? d2b[j] : 0.f);
        float p = blk_sum4(acc * wv, shr);
        if (t == 0) atomicAdd(&dout[64 + b], p);
    }
    __syncthreads();
}

// ---- ge bank: geb[b,:] += e1@W1seg + e2@W2seg (+fc1b at kseg 0)
__device__ void ge_dev(const KArgs& a, int jlin, float* xs, float* xs2) {
    int t = threadIdx.x;
    int jt = jlin % 3, b = (jlin / 3) % 32, kseg = jlin / 96;
    __syncthreads();
    if (t < 96) {
        int d = kseg * 96 + t;
        float a1 = a.avx1[(size_t)b * Dd + d], a2 = a.avx2[(size_t)b * Dd + d];
        xs[t]  = (4.f * a.xp1[(size_t)b * Dd + d] + 2.f * a.sc[448 + b] * a1 + a.sc[480 + b] * a2) * a.sc[576 + b];
        xs2[t] = (4.f * a.xp2[(size_t)b * Dd + d] + 2.f * a.sc[512 + b] * a1 + a.sc[544 + b] * a2) * a.sc[608 + b];
    }
    __syncthreads();
    int j = jt * 256 + t;
    float a1 = 0.f, a2 = 0.f;
    const float* w1 = a.fc1w + (size_t)(Dd + kseg * 96) * Dd + j;
    const float* w2 = a.fc1w + (size_t)(2 * Dd + kseg * 96) * Dd + j;
#pragma unroll 8
    for (int dd = 0; dd < 96; ++dd) {
        a1 += xs[dd] * w1[(size_t)dd * Dd];
        a2 += xs2[dd] * w2[(size_t)dd * Dd];
    }
    float res = a1 + a2 + (kseg == 0 ? a.fc1b[j] : 0.f);
    atomicAdd(&a.geb[(size_t)b * Dd + j], res);
}

// ---- dual bank sharing fc1w0: aw1 += av1@W, aw2 += av2@W (one W read)
__device__ void aw_dual_dev(const KArgs& a, int jlin, float* xs, float* xs2) {
    int t = threadIdx.x;
    int jt = jlin % 3, b = (jlin / 3) % 32, kseg = jlin / 96;
    __syncthreads();
    if (t < 96) {
        int d = kseg * 96 + t;
        xs[t]  = a.av1[(size_t)b * Dd + d];
        xs2[t] = a.av2[(size_t)b * Dd + d];
    }
    __syncthreads();
    int j = jt * 256 + t;
    float a1 = 0.f, a2 = 0.f;
    const float* wp = a.fc1w + (size_t)(kseg * 96) * Dd + j;
#pragma unroll 8
    for (int dd = 0; dd < 96; ++dd) {
        float w = wp[(size_t)dd * Dd];
        a1 += xs[dd] * w;
        a2 += xs2[dd] * w;
    }
    atomicAdd(&a.aw1[(size_t)b * Dd + j], a1);
    atomicAdd(&a.aw2[(size_t)b * Dd + j], a2);
}

// ---- softgate: gate coeffs + masked softmax over L (+ pool coeffs at phase 1)
__device__ void softgate_dev(const KArgs& a, int phase, int b, float* shr) {
    int t = threadIdx.x;
    float ks[2], ga[2] = {0.f, 0.f}, gb2[2] = {0.f, 0.f};
#pragma unroll
    for (int i = 0; i < 2; ++i) {
        int l = t + (i << 8);
        size_t r = (size_t)b * Ls + l;
        float4 x = *(const float4*)(a.xd + r * 4);
        if (phase == 0) {
            float g = sigm(x.x + a.sc[b] + a.gb[0]);
            a.gx1[r] = g;
            ga[i] = g;
            ks[i] = 2.f * x.y + g * a.sc[32 + b];
        } else {
            float gp = a.gx1[r];
            float g = sigm(2.f * x.z + gp * a.sc[64 + b] + a.sc[224 + b] + a.gb[2]);
            a.gx2[r] = g;
            ga[i] = gp; gb2[i] = g;
            ks[i] = 4.f * x.w + 2.f * gp * a.sc[96 + b] + g * a.sc[256 + b];
        }
        if (a.mask[r] == 0) ks[i] = -1e9f;
    }
    float mx = fmaxf(ks[0], ks[1]);
#pragma unroll
    for (int o = 32; o > 0; o >>= 1) mx = fmaxf(mx, __shfl_down(mx, o, 64));
    if ((t & 63) == 0) shr[t >> 6] = mx;
    __syncthreads();
    mx = fmaxf(fmaxf(shr[0], shr[1]), fmaxf(shr[2], shr[3]));
    __syncthreads();
    float e0 = expf(ks[0] - mx), e1 = expf(ks[1] - mx);
    float s = blk_sum4(e0 + e1, shr);
    float inv = 1.f / s;
    float w0 = e0 * inv, w1 = e1 * inv;
    a.awb[(size_t)b * Ls + t] = w0;
    a.awb[(size_t)b * Ls + t + 256] = w1;
    float ca = blk_sum4(w0 * ga[0] + w1 * ga[1], shr);
    if (phase == 0) {
        if (t == 0) a.sc[320 + b] = ca;
    } else {
        if (t == 0) a.sc[352 + b] = ca;
        float cb = blk_sum4(w0 * gb2[0] + w1 * gb2[1], shr);
        if (t == 0) a.sc[384 + b] = cb;
        float q1a = a.pos1[(size_t)b * Ls + t], q1b = a.pos1[(size_t)b * Ls + t + 256];
        float q2a = a.pos2[(size_t)b * Ls + t], q2b = a.pos2[(size_t)b * Ls + t + 256];
        float s1 = blk_sum4(q1a + q1b, shr);
        float s2 = blk_sum4(q2a + q2b, shr);
        float c11 = blk_sum4(q1a * ga[0] + q1b * ga[1], shr);
        float c12 = blk_sum4(q1a * gb2[0] + q1b * gb2[1], shr);
        float c21 = blk_sum4(q2a * ga[0] + q2b * ga[1], shr);
        float c22 = blk_sum4(q2a * gb2[0] + q2b * gb2[1], shr);
        if (t == 0) {
            a.sc[448 + b] = c11; a.sc[480 + b] = c12;
            a.sc[512 + b] = c21; a.sc[544 + b] = c22;
            a.sc[576 + b] = 1.f / s1; a.sc[608 + b] = 1.f / s2;
        }
    }
}

// ---- passX: weighted sums of x0 rows (float4 lanes, t<192)
__device__ void passX_dev(const KArgs& a, int blk, float* S, bool dopos) {
    int t = threadIdx.x;
    if (t >= 192) return;
    int b = blk >> 4, seg = blk & 15, l0 = seg * 32;
    int d4 = t << 2;
    const float* xb = a.x0 + ((size_t)b * Ls + l0) * Dd + d4;
    const float* wb = a.awb + (size_t)b * Ls + l0;
    float4 as = make_float4(0.f,0.f,0.f,0.f);
    float4 a1 = make_float4(0.f,0.f,0.f,0.f);
    float4 a2 = make_float4(0.f,0.f,0.f,0.f);
    for (int l = 0; l < 32; ++l) {
        float4 xv = *(const float4*)(xb + (size_t)l * Dd);
        float wv = wb[l];
        as.x += wv*xv.x; as.y += wv*xv.y; as.z += wv*xv.z; as.w += wv*xv.w;
        if (dopos) {
            float q1 = a.pos1[(size_t)b * Ls + l0 + l], q2 = a.pos2[(size_t)b * Ls + l0 + l];
            a1.x += q1*xv.x; a1.y += q1*xv.y; a1.z += q1*xv.z; a1.w += q1*xv.w;
            a2.x += q2*xv.x; a2.y += q2*xv.y; a2.z += q2*xv.z; a2.w += q2*xv.w;
        }
    }
    float* ds = S + (size_t)b * Dd + d4;
    atomicAdd(ds+0, as.x); atomicAdd(ds+1, as.y); atomicAdd(ds+2, as.z); atomicAdd(ds+3, as.w);
    if (dopos) {
        float* d1 = a.xp1 + (size_t)b * Dd + d4;
        float* d2 = a.xp2 + (size_t)b * Dd + d4;
        atomicAdd(d1+0, a1.x); atomicAdd(d1+1, a1.y); atomicAdd(d1+2, a1.z); atomicAdd(d1+3, a1.w);
        atomicAdd(d2+0, a2.x); atomicAdd(d2+1, a2.y); atomicAdd(d2+2, a2.z); atomicAdd(d2+3, a2.w);
    }
}

// ---- kvec dots body (grid-strided externally)
__device__ void kvec_dot(const KArgs& a, int dot, int lane) {
    int idx = dot / Dd, d = dot - idx * Dd;
    const float* row = a.kw + ((size_t)idx * Dd + d) * Dd;
    const float* swk = a.sw + (size_t)idx * 2 * Dd + Dd;
    float sA = 0.f;
    for (int j = lane; j < Dd; j += 64) sA += row[j] * swk[j];
    sA = wred(sA);
    if (lane == 0) a.kvecs[dot] = sA;
}

// ---- xdots body: wave-per-row over rows [r0, Bb*Ls) step rstep
__device__ void xdots_dev(const KArgs& a, int r0, int rstep, int lane) {
    float4 gs0[3], k1r[3], gs2[3], k3r[3];
#pragma unroll
    for (int k = 0; k < 3; ++k) {
        int d = (lane << 2) + k * 256;
        float4 ga = *(const float4*)(a.gw + d);
        float4 gbv = *(const float4*)(a.gw + 768 + d);
        gs0[k] = make_float4(ga.x+gbv.x, ga.y+gbv.y, ga.z+gbv.z, ga.w+gbv.w);
        k1r[k] = *(const float4*)(a.kvecs + 768 + d);
        float4 g2a = *(const float4*)(a.gw + 3072 + d);
        float4 g2b = *(const float4*)(a.gw + 3840 + d);
        gs2[k] = make_float4(g2a.x+g2b.x, g2a.y+g2b.y, g2a.z+g2b.z, g2a.w+g2b.w);
        k3r[k] = *(const float4*)(a.kvecs + 2304 + d);
    }
    for (int r = r0; r < Bb * Ls; r += rstep) {
        const float* xr = a.x0 + (size_t)r * Dd;
        float s0 = 0.f, s1 = 0.f, s2 = 0.f, s3 = 0.f;
#pragma unroll
        for (int k = 0; k < 3; ++k) {
            float4 xv = *(const float4*)(xr + (lane << 2) + k * 256);
            s0 += xv.x*gs0[k].x + xv.y*gs0[k].y + xv.z*gs0[k].z + xv.w*gs0[k].w;
            s1 += xv.x*k1r[k].x + xv.y*k1r[k].y + xv.z*k1r[k].z + xv.w*k1r[k].w;
            s2 += xv.x*gs2[k].x + xv.y*gs2[k].y + xv.z*gs2[k].z + xv.w*gs2[k].w;
            s3 += xv.x*k3r[k].x + xv.y*k3r[k].y + xv.z*k3r[k].z + xv.w*k3r[k].w;
        }
        s0 = wred(s0); s1 = wred(s1); s2 = wred(s2); s3 = wred(s3);
        if (lane == 0) {
            float4 o4 = make_float4(s0, s1, s2, s3);
            *(float4*)(a.xd + (size_t)r * 4) = o4;
        }
    }
}

// ---- pdots body
__device__ void pdots_dev(const KArgs& a, int g2, int lane) {
    for (int k = 0; k < 4; ++k) {
        int j = g2 + k * 128;
        if (k == 3) { if (g2 >= 4) break; j = 384 + g2; }
        if (j >= 388) continue;
        int vv = j / Cc, r = j - vv * Cc;
        const float* va; const float* vb2 = nullptr;
        if (vv == 0) va = a.kvecs;
        else if (vv == 1) va = a.kvecs + 2 * Dd;
        else if (vv == 2) { va = a.gw + 1536; vb2 = a.gw + 2304; }
        else { va = a.gw + 4608; vb2 = a.gw + 5376; }
        const float* row = a.p0b + (size_t)r * Dd;
        float sA = 0.f;
        for (int jj = lane; jj < Dd; jj += 64)
            sA += row[jj] * (va[jj] + (vb2 ? vb2[jj] : 0.f));
        sA = wred(sA);
        if (lane == 0) a.pdots[j] = sA;
    }
}

// ---- logits body
__device__ void logits_dev(const KArgs& a, int r, float* shr) {
    int t = threadIdx.x;
    int b = r / Cc, c = r - b * Cc;
    float g1 = a.g1buf[r];
    float g2 = sigm(2.f * a.pdots[291 + c] + g1 * a.sc[192 + b] + a.sc[288 + b] + a.gb[3]);
    float ssum = 0.f;
#pragma unroll
    for (int sseg = 0; sseg < 3; ++sseg) {
        int d = t + sseg * 256;
        float h = tanhf(4.f * a.pp[(size_t)c * Dd + d]
                      + 2.f * g1 * a.aw1[(size_t)b * Dd + d]
                      + g2 * a.aw2[(size_t)b * Dd + d]
                      + a.geb[(size_t)b * Dd + d]);
        ssum += h * a.fc2w[d];
    }
    float tt = blk_sum4(ssum, shr);
    if (t == 0) a.out[r] = sigm(tt + a.fc2b[0]);
}

// ================= single fused cooperative kernel =================
__global__ __launch_bounds__(NTHR, 2) void kfused(KArgs a) {
    __shared__ float As[1024], Ws[1024];
    __shared__ float xs[96], xs2[96], lw[128], shr[16];
    cg::grid_group grid = cg::this_grid();
    const int blk = blockIdx.x, t = threadIdx.x;
    const int wv_ = t >> 6, lane = t & 63;

    // ---- P0: zero workspace + kvecs dots
    for (size_t i = (size_t)blk * NTHR + t; i < (size_t)a.zcount; i += (size_t)GRID * NTHR)
        a.zbase[i] = 0.f;
    for (int dot = blk * 4 + wv_; dot < 3072; dot += GRID * 4)
        kvec_dot(a, dot, lane);
    grid.sync();

    // ---- P1: gemm1 (192 works) || xdots (remaining blocks)
    if (blk < 192) {
        sgemm_dev(a.emb, a.rel_w, a.rel_b, a.p0b, Cc, Dd, Dd, 96,
                  blk % 12, (blk / 12) % 2, blk / 24, As, Ws);
    } else {
        xdots_dev(a, (blk - 192) * 4 + wv_, (GRID - 192) * 4, lane);
    }
    grid.sync();

    // ---- P2: pp GEMM (96 works) || pdots (32 works)
    if (blk < 96) {
        sgemm_dev(a.p0b, a.fc1w, nullptr, a.pp, Cc, Dd, Dd, 192,
                  blk % 12, (blk / 12) % 2, blk / 24, As, Ws);
    } else if (blk < 128) {
        pdots_dev(a, (blk - 96) * 4 + wv_, lane);
    }
    grid.sync();

    // ---- P3: attn phase 0 (768 works)
    for (int j = blk; j < 768; j += GRID) attn_gemv(a, 0, j, xs, lw, shr);
    grid.sync();

    // ---- P4: softgate phase 0 (32 works)
    if (blk < 32) softgate_dev(a, 0, blk, shr);
    grid.sync();

    // ---- P5: passX0 -> S0, xp1, xp2 (512 works)
    for (int j = blk; j < 512; j += GRID) passX_dev(a, j, a.S0, true);
    grid.sync();

    // ---- P6: mm0 -> av1 (768 works)
    for (int j = blk; j < 768; j += GRID)
        mm_dev(a, j, a.S0, 2.f, a.avx1, a.sc + 320, 1.f, nullptr, nullptr, 0.f,
               a.vw + (size_t)1 * Dd * Dd, a.vb + Dd, a.av1,
               3, a.gw + 1536, nullptr, a.kvecs + 2 * Dd, a.gw + 4608, a.gw + 5376,
               a.sc + 128, xs, shr);
    grid.sync();

    // ---- P7: attn phase 1 (768 works)
    for (int j = blk; j < 768; j += GRID) attn_gemv(a, 1, j, xs, lw, shr);
    grid.sync();

    // ---- P8: softgate phase 1 (32 works)
    if (blk < 32) softgate_dev(a, 1, blk, shr);
    grid.sync();

    // ---- P9: passX1 (512 works) || ge bank (768 works) = 1280 works
    for (int w = blk; w < 1280; w += GRID) {
        if (w < 512) passX_dev(a, w, a.S1, false);
        else ge_dev(a, w - 512, xs, xs2);
    }
    grid.sync();

    // ---- P10: mm1 -> av2 (768 works)
    for (int j = blk; j < 768; j += GRID)
        mm_dev(a, j, a.S1, 4.f, a.avx1, a.sc + 352, 2.f, a.avx2, a.sc + 384, 1.f,
               a.vw + (size_t)3 * Dd * Dd, a.vb + 3 * Dd, a.av2,
               1, a.gw + 4608, nullptr, nullptr, nullptr, nullptr,
               a.sc + 288, xs, shr);
    grid.sync();

    // ---- P11: aw dual bank (768 works)
    for (int j = blk; j < 768; j += GRID) aw_dual_dev(a, j, xs, xs2);
    grid.sync();

    // ---- P12: logits (Bb*Cc works)
    for (int r = blk; r < Bb * Cc; r += GRID) logits_dev(a, r, shr);
    grid.sync();

    // ---- P13: argmax
    if (blk == 0 && t < Bb) {
        const float* row = a.out + (size_t)t * Cc;
        float best = row[0];
        int bi = 0;
        for (int c = 1; c < Cc; ++c) {
            float v = row[c];
            if (v > best) { best = v; bi = c; }
        }
        a.out[Bb * Cc + t] = (float)bi;
    }
}

// ================= fallback kernels (known-good 15-kernel pipeline) =================
__global__ __launch_bounds__(NTHR) void k_zero_kvec(KArgs a) {
    int blk = blockIdx.x, t = threadIdx.x;
    int wv_ = t >> 6, lane = t & 63;
    for (size_t i = (size_t)blk * NTHR + t; i < (size_t)a.zcount; i += (size_t)NBLK * NTHR)
        a.zbase[i] = 0.f;
    for (int dot = blk * 4 + wv_; dot < 3072; dot += NBLK * 4)
        kvec_dot(a, dot, lane);
}

__global__ __launch_bounds__(NTHR) void k_gemm1(KArgs a) {
    __shared__ float As[1024], Ws[1024];
    int blk = blockIdx.x;
    sgemm_dev(a.emb, a.rel_w, a.rel_b, a.p0b, Cc, Dd, Dd, 96,
              blk % 12, (blk / 12) % 2, blk / 24, As, Ws);
}

__global__ __launch_bounds__(NTHR) void k_prep2(KArgs a) {
    __shared__ float As[1024], Ws[1024];
    int blk = blockIdx.x, t = threadIdx.x;
    int wv_ = t >> 6, lane = t & 63;
    if (blk < 96) {
        sgemm_dev(a.p0b, a.fc1w, nullptr, a.pp, Cc, Dd, Dd, 192,
                  blk % 12, (blk / 12) % 2, blk / 24, As, Ws);
    } else if (blk < 128) {
        pdots_dev(a, (blk - 96) * 4 + wv_, lane);
    } else {
        xdots_dev(a, (blk - 128) * 4 + wv_, (NBLK - 128) * 4, lane);
    }
}

__global__ __launch_bounds__(NTHR) void k_attn(KArgs a, int phase) {
    __shared__ float xs[96], lw[128], shr[16];
    attn_gemv(a, phase, blockIdx.x, xs, lw, shr);
}

__global__ __launch_bounds__(NTHR) void k_softgate(KArgs a, int phase) {
    __shared__ float shr[16];
    softgate_dev(a, phase, blockIdx.x, shr);
}

__global__ __launch_bounds__(NTHR) void k_passX0(KArgs a) {
    passX_dev(a, blockIdx.x, a.S0, true);
}

__global__ __launch_bounds__(NTHR) void k_mm0(KArgs a) {
    __shared__ float xs[96], shr[16];
    mm_dev(a, blockIdx.x, a.S0, 2.f, a.avx1, a.sc + 320, 1.f, nullptr, nullptr, 0.f,
           a.vw + (size_t)1 * Dd * Dd, a.vb + Dd, a.av1,
           3, a.gw + 1536, nullptr, a.kvecs + 2 * Dd, a.gw + 4608, a.gw + 5376,
           a.sc + 128, xs, shr);
}

__global__ __launch_bounds__(NTHR) void k_passX1ge(KArgs a) {
    __shared__ float xs[96], xs2[96];
    int blk = blockIdx.x;
    if (blk < 512) passX_dev(a, blk, a.S1, false);
    else ge_dev(a, blk - 512, xs, xs2);
}

__global__ __launch_bounds__(NTHR) void k_mm1(KArgs a) {
    __shared__ float xs[96], shr[16];
    mm_dev(a, blockIdx.x, a.S1, 4.f, a.avx1, a.sc + 352, 2.f, a.avx2, a.sc + 384, 1.f,
           a.vw + (size_t)3 * Dd * Dd, a.vb + 3 * Dd, a.av2,
           1, a.gw + 4608, nullptr, nullptr, nullptr, nullptr,
           a.sc + 288, xs, shr);
}

__global__ __launch_bounds__(NTHR) void k_awdual(KArgs a) {
    __shared__ float xs[96], xs2[96];
    aw_dual_dev(a, blockIdx.x, xs, xs2);
}

__global__ __launch_bounds__(NTHR) void k_logits(KArgs a) {
    __shared__ float shr[16];
    for (int r = blockIdx.x; r < Bb * Cc; r += NBLK) logits_dev(a, r, shr);
}

__global__ void k_argmax(KArgs a) {
    int t = threadIdx.x;
    if (t < Bb) {
        const float* row = a.out + (size_t)t * Cc;
        float best = row[0];
        int bi = 0;
        for (int c = 1; c < Cc; ++c) {
            float v = row[c];
            if (v > best) { best = v; bi = c; }
        }
        a.out[Bb * Cc + t] = (float)bi;
    }
}

extern "C" void kernel_launch(void* const* d_in, const int* in_sizes, int n_in,
                              void* d_out, int out_size, void* d_ws, size_t ws_size,
                              hipStream_t stream) {
    KArgs ka;
    ka.x0    = (const float*)d_in[0];
    ka.pos1  = (const float*)d_in[1];
    ka.pos2  = (const float*)d_in[2];
    ka.mask  = (const int*)d_in[3];
    ka.emb   = (const float*)d_in[4];
    ka.rel_w = (const float*)d_in[5];
    ka.rel_b = (const float*)d_in[6];
    // qw(7), qb(8) dead (softmax shift-invariance); kb(10), sb(14) dead (row-constant)
    ka.kw    = (const float*)d_in[9];
    ka.vw    = (const float*)d_in[11];
    ka.vb    = (const float*)d_in[12];
    ka.sw    = (const float*)d_in[13];
    ka.gw    = (const float*)d_in[15];
    ka.gb    = (const float*)d_in[16];
    ka.fc1w  = (const float*)d_in[17];
    ka.fc1b  = (const float*)d_in[18];
    ka.fc2w  = (const float*)d_in[19];
    ka.fc2b  = (const float*)d_in[20];
    ka.out   = (float*)d_out;

    float* ws = (float*)d_ws;
    size_t off = 0;
    const size_t PD = (size_t)Cc * Dd;
    const size_t BD = (size_t)Bb * Dd;
    ka.p0b  = ws + off; off += PD;
    ka.pp   = ws + off; off += PD;
    ka.sc   = ws + off; off += 640;
    ka.avx1 = ws + off; off += BD;
    ka.avx2 = ws + off; off += BD;
    ka.av1  = ws + off; off += BD;
    ka.av2  = ws + off; off += BD;
    ka.aw1  = ws + off; off += BD;
    ka.aw2  = ws + off; off += BD;
    ka.S0   = ws + off; off += BD;
    ka.S1   = ws + off; off += BD;
    ka.xp1  = ws + off; off += BD;
    ka.xp2  = ws + off; off += BD;
    ka.geb  = ws + off; off += BD;
    ka.zbase = ws;
    ka.zcount = (int)off;
    ka.kvecs = ws + off; off += (size_t)4 * Dd;
    ka.pdots = ws + off; off += 388;
    ka.g1buf = ws + off; off += (size_t)Bb * Cc;
    ka.xd    = ws + off; off += (size_t)Bb * Ls * 4;
    ka.gx1   = ws + off; off += (size_t)Bb * Ls;
    ka.gx2   = ws + off; off += (size_t)Bb * Ls;
    ka.awb   = ws + off; off += (size_t)Bb * Ls;

    void* params[] = { (void*)&ka };
    hipError_t err = hipLaunchCooperativeKernel((void*)kfused, dim3(GRID), dim3(NTHR),
                                                params, 0, stream);
    if (err != hipSuccess) {
        // fallback: known-good 15-kernel pipeline
        k_zero_kvec<<<NBLK, NTHR, 0, stream>>>(ka);
        k_gemm1<<<192, NTHR, 0, stream>>>(ka);
        k_prep2<<<NBLK, NTHR, 0, stream>>>(ka);
        k_attn<<<768, NTHR, 0, stream>>>(ka, 0);
        k_softgate<<<32, NTHR, 0, stream>>>(ka, 0);
        k_passX0<<<NBLK, NTHR, 0, stream>>>(ka);
        k_mm0<<<768, NTHR, 0, stream>>>(ka);
        k_attn<<<768, NTHR, 0, stream>>>(ka, 1);
        k_softgate<<<32, NTHR, 0, stream>>>(ka, 1);
        k_passX1ge<<<1280, NTHR, 0, stream>>>(ka);
        k_mm1<<<768, NTHR, 0, stream>>>(ka);
        k_awdual<<<768, NTHR, 0, stream>>>(ka);
        k_logits<<<NBLK, NTHR, 0, stream>>>(ka);
        k_argmax<<<1, 64, 0, stream>>>(ka);
    }
}

// Round 3
// 1018.989 us; speedup vs baseline: 1.0091x; 1.0091x over previous
//
#include <hip/hip_runtime.h>
#include <math.h>

#define GRID 512
#define NBLK 512
#define NTHR 256
static const int Bb = 32, Ls = 512, Dd = 768, Cc = 97;

struct KArgs {
    const float *x0, *pos1, *pos2;
    const int* mask;
    const float *emb, *rel_w, *rel_b, *kw, *vw, *vb, *sw, *gw, *gb;
    const float *fc1w, *fc1b, *fc2w, *fc2b;
    float* out;
    float *p0b, *pp, *sc, *avx1, *avx2, *av1, *av2, *aw1, *aw2, *S0, *S1, *xp1, *xp2, *geb;
    float *kvecs, *pdots, *g1buf, *xd, *gx1, *gx2, *awb;
    float* zbase;
    int zcount;
    unsigned long long* amax;   // [32] packed (logit_bits<<32 | ~c)
    int* bctl;                  // [0..15] grp cnt, [16] root, [17] gen, [19] done
};

__device__ __forceinline__ float sigm(float x) { return 1.f / (1.f + expf(-x)); }

__device__ __forceinline__ float wred(float v) {
#pragma unroll
    for (int o = 32; o > 0; o >>= 1) v += __shfl_down(v, o, 64);
    return v;
}

__device__ __forceinline__ float blk_sum4(float v, float* shr) {
    v = wred(v);
    int t = threadIdx.x;
    if ((t & 63) == 0) shr[t >> 6] = v;
    __syncthreads();
    float r = shr[0] + shr[1] + shr[2] + shr[3];
    __syncthreads();
    return r;
}

// ---- hierarchical grid barrier: 16 groups x 32 blocks, generation-based.
// Release: __syncthreads() drains all waves' stores to L2 (compiler waitcnt);
// thread0's __threadfence() writes L2 back to coherence point. Acquire: thread0
// __threadfence() invalidates L1/L2 before the exit __syncthreads().
__device__ __forceinline__ void gbar(int* bctl) {
    __syncthreads();
    if (threadIdx.x == 0) {
        __threadfence();
        int gen = __hip_atomic_load(bctl + 17, __ATOMIC_RELAXED, __HIP_MEMORY_SCOPE_AGENT);
        int grp = blockIdx.x >> 5;
        if (atomicAdd(bctl + grp, 1) == 31) {
            if (atomicAdd(bctl + 16, 1) == 15) {
                // last arrival grid-wide: reset counters, then flip generation
                for (int i = 0; i < 17; ++i)
                    __hip_atomic_store(bctl + i, 0, __ATOMIC_RELAXED, __HIP_MEMORY_SCOPE_AGENT);
                __threadfence();
                __hip_atomic_fetch_add(bctl + 17, 1, __ATOMIC_RELAXED, __HIP_MEMORY_SCOPE_AGENT);
            }
        }
        while (__hip_atomic_load(bctl + 17, __ATOMIC_RELAXED, __HIP_MEMORY_SCOPE_AGENT) == gen)
            __builtin_amdgcn_s_sleep(1);
        __threadfence();
    }
    __syncthreads();
}

// ---- direct-store full-K SGEMM tile: C[bm:+64, bn:+64] = A@W (+bias)
__device__ void sgemm_direct(const float* __restrict__ A, const float* __restrict__ W,
                             const float* __restrict__ bias, float* __restrict__ C,
                             int M, int N, int K, int bx, int by,
                             float* As, float* Ws) {
    int tid = threadIdx.x;
    int tx = tid & 15, ty = tid >> 4;
    int bn = bx * 64, bm = by * 64;
    int arow = tid >> 2, akq = (tid & 3) << 2;
    int wrow = tid >> 4, wcol = (tid & 15) << 2;
    int gar = bm + arow;
    bool aval = gar < M;
    const float* Ap = A + (size_t)gar * K + akq;
    const float* Wp = W + (size_t)wrow * N + bn + wcol;
    float acc[4][4] = {{0.f}};
    float4 a4 = make_float4(0.f, 0.f, 0.f, 0.f);
    if (aval) a4 = *(const float4*)Ap;
    float4 w4 = *(const float4*)Wp;
    for (int k0 = 0; k0 < K; k0 += 16) {
        __syncthreads();
        As[(akq + 0) * 64 + arow] = a4.x; As[(akq + 1) * 64 + arow] = a4.y;
        As[(akq + 2) * 64 + arow] = a4.z; As[(akq + 3) * 64 + arow] = a4.w;
        *(float4*)&Ws[wrow * 64 + wcol] = w4;
        __syncthreads();
        if (k0 + 16 < K) {
            if (aval) a4 = *(const float4*)(Ap + k0 + 16);
            w4 = *(const float4*)(Wp + (size_t)(k0 + 16) * N);
        }
#pragma unroll
        for (int kk = 0; kk < 16; ++kk) {
            float4 a = *(const float4*)&As[kk * 64 + (ty << 2)];
            float4 b = *(const float4*)&Ws[kk * 64 + (tx << 2)];
            acc[0][0]+=a.x*b.x; acc[0][1]+=a.x*b.y; acc[0][2]+=a.x*b.z; acc[0][3]+=a.x*b.w;
            acc[1][0]+=a.y*b.x; acc[1][1]+=a.y*b.y; acc[1][2]+=a.y*b.z; acc[1][3]+=a.y*b.w;
            acc[2][0]+=a.z*b.x; acc[2][1]+=a.z*b.y; acc[2][2]+=a.z*b.z; acc[2][3]+=a.z*b.w;
            acc[3][0]+=a.w*b.x; acc[3][1]+=a.w*b.y; acc[3][2]+=a.w*b.z; acc[3][3]+=a.w*b.w;
        }
    }
    int gc = bn + (tx << 2);
    float4 bz4 = make_float4(0.f, 0.f, 0.f, 0.f);
    if (bias) bz4 = *(const float4*)(bias + gc);
#pragma unroll
    for (int i = 0; i < 4; ++i) {
        int gr = bm + (ty << 2) + i;
        if (gr < M) {
            float4 o = make_float4(acc[i][0] + bz4.x, acc[i][1] + bz4.y,
                                   acc[i][2] + bz4.z, acc[i][3] + bz4.w);
            *(float4*)(C + (size_t)gr * N + gc) = o;
        }
    }
}

// ---- fused relation-attention + V-GEMV bank; jlin in [0,768): jt%3, b, kseg/96
__device__ void attn_gemv(const KArgs& a, int phase, int jlin,
                          float* xs, float* lw, float* shr) {
    int t = threadIdx.x;
    int jt = jlin % 3, b = (jlin / 3) % 32, kseg = jlin / 96;
    float v = -3.0e38f, g1 = 0.f;
    if (t < Cc) {
        if (phase == 0) v = a.pdots[t];
        else {
            g1 = sigm(a.pdots[194 + t] + a.sc[128 + b] + a.gb[1]);
            v = 2.f * a.pdots[97 + t] + g1 * a.sc[160 + b];
        }
    }
    if (phase == 1 && jt == 0 && kseg == 0 && t < Cc) a.g1buf[(size_t)b * Cc + t] = g1;
    float m = v;
#pragma unroll
    for (int o = 32; o > 0; o >>= 1) m = fmaxf(m, __shfl_down(m, o, 64));
    if ((t & 63) == 0) shr[t >> 6] = m;
    __syncthreads();
    m = fmaxf(fmaxf(shr[0], shr[1]), fmaxf(shr[2], shr[3]));
    __syncthreads();
    float e = (t < Cc) ? expf(v - m) : 0.f;
    float s = blk_sum4(e, shr);
    float wc = e / s;
    if (t < Cc) lw[t] = wc;
    float cg1 = blk_sum4(wc * g1, shr);   // publishes lw
    float alpha = (phase == 0) ? 1.f : 2.f;
    if (t < 96) {
        int d = kseg * 96 + t;
        const float* pc = a.p0b + d;
        float acc2 = 0.f;
#pragma unroll 4
        for (int c = 0; c < Cc; ++c) acc2 += lw[c] * pc[(size_t)c * Dd];
        float val = alpha * acc2;
        if (phase == 1) val += cg1 * a.av1[(size_t)b * Dd + d];
        xs[t] = val;
    }
    __syncthreads();
    const float* W = a.vw + (size_t)(phase == 0 ? 0 : 2) * Dd * Dd;
    const float* bias = a.vb + (phase == 0 ? 0 : 2) * Dd;
    float* outp = (phase == 0) ? a.avx1 : a.avx2;
    int j = jt * 256 + t;
    float acc = (kseg == 0) ? bias[j] : 0.f;
    const float* wp = W + (size_t)(kseg * 96) * Dd + j;
#pragma unroll 8
    for (int dd = 0; dd < 96; ++dd) acc += xs[dd] * wp[(size_t)dd * Dd];
    atomicAdd(&outp[(size_t)b * Dd + j], acc);
    const float* da[4]; const float* db[4]; int nd; float* dout;
    if (phase == 0) {
        da[0]=a.gw;          db[0]=nullptr;
        da[1]=a.kvecs+Dd;    db[1]=nullptr;
        da[2]=a.gw+3072;     db[2]=a.gw+3840;
        da[3]=a.kvecs+3*Dd;  db[3]=nullptr;
        nd = 4; dout = a.sc;
    } else {
        da[0]=a.gw+3072;     db[0]=nullptr;
        da[1]=a.kvecs+3*Dd;  db[1]=nullptr;
        nd = 2; dout = a.sc + 224;
    }
    for (int vv = 0; vv < nd; ++vv) {
        float wv = da[vv][j] + (db[vv] ? db[vv][j] : 0.f);
        float p = blk_sum4(acc * wv, shr);
        if (t == 0) atomicAdd(&dout[vv * 32 + b], p);
    }
    __syncthreads();
}

// ---- GEMV bank: out[b,:] += xs@Wseg; xs = gamma*S + multA*coefA[b]*avA + multB*coefB[b]*avB
__device__ void mm_dev(const KArgs& a, int jlin, const float* S, float gamma,
                       const float* avA, const float* coefA, float multA,
                       const float* avB, const float* coefB, float multB,
                       const float* W, const float* bias, float* outp,
                       int ndots, const float* d0a, const float* d0b,
                       const float* d1a, const float* d2a, const float* d2b,
                       float* dout, float* xs, float* shr) {
    int t = threadIdx.x;
    int jt = jlin % 3, b = (jlin / 3) % 32, kseg = jlin / 96;
    if (t < 96) {
        int d = kseg * 96 + t;
        float v = gamma * S[(size_t)b * Dd + d];
        if (avA) v += multA * coefA[b] * avA[(size_t)b * Dd + d];
        if (avB) v += multB * coefB[b] * avB[(size_t)b * Dd + d];
        xs[t] = v;
    }
    __syncthreads();
    int j = jt * 256 + t;
    float acc = (kseg == 0 && bias) ? bias[j] : 0.f;
    const float* wp = W + (size_t)(kseg * 96) * Dd + j;
#pragma unroll 8
    for (int dd = 0; dd < 96; ++dd) acc += xs[dd] * wp[(size_t)dd * Dd];
    atomicAdd(&outp[(size_t)b * Dd + j], acc);
    if (ndots > 0) {
        float wv = d0a[j] + (d0b ? d0b[j] : 0.f);
        float p = blk_sum4(acc * wv, shr);
        if (t == 0) atomicAdd(&dout[b], p);
    }
    if (ndots > 1) {
        float p = blk_sum4(acc * d1a[j], shr);
        if (t == 0) atomicAdd(&dout[32 + b], p);
    }
    if (ndots > 2) {
        float wv = d2a[j] + (d2b ? d2b[j] : 0.f);
        float p = blk_sum4(acc * wv, shr);
        if (t == 0) atomicAdd(&dout[64 + b], p);
    }
    __syncthreads();
}

// ---- ge bank: geb[b,:] += e1@W1seg + e2@W2seg (+fc1b at kseg 0)
__device__ void ge_dev(const KArgs& a, int jlin, float* xs, float* xs2) {
    int t = threadIdx.x;
    int jt = jlin % 3, b = (jlin / 3) % 32, kseg = jlin / 96;
    __syncthreads();
    if (t < 96) {
        int d = kseg * 96 + t;
        float a1 = a.avx1[(size_t)b * Dd + d], a2 = a.avx2[(size_t)b * Dd + d];
        xs[t]  = (4.f * a.xp1[(size_t)b * Dd + d] + 2.f * a.sc[448 + b] * a1 + a.sc[480 + b] * a2) * a.sc[576 + b];
        xs2[t] = (4.f * a.xp2[(size_t)b * Dd + d] + 2.f * a.sc[512 + b] * a1 + a.sc[544 + b] * a2) * a.sc[608 + b];
    }
    __syncthreads();
    int j = jt * 256 + t;
    float a1 = 0.f, a2 = 0.f;
    const float* w1 = a.fc1w + (size_t)(Dd + kseg * 96) * Dd + j;
    const float* w2 = a.fc1w + (size_t)(2 * Dd + kseg * 96) * Dd + j;
#pragma unroll 8
    for (int dd = 0; dd < 96; ++dd) {
        a1 += xs[dd] * w1[(size_t)dd * Dd];
        a2 += xs2[dd] * w2[(size_t)dd * Dd];
    }
    float res = a1 + a2 + (kseg == 0 ? a.fc1b[j] : 0.f);
    atomicAdd(&a.geb[(size_t)b * Dd + j], res);
}

// ---- dual bank sharing fc1w0: aw1 += av1@W, aw2 += av2@W (one W read)
__device__ void aw_dual_dev(const KArgs& a, int jlin, float* xs, float* xs2) {
    int t = threadIdx.x;
    int jt = jlin % 3, b = (jlin / 3) % 32, kseg = jlin / 96;
    __syncthreads();
    if (t < 96) {
        int d = kseg * 96 + t;
        xs[t]  = a.av1[(size_t)b * Dd + d];
        xs2[t] = a.av2[(size_t)b * Dd + d];
    }
    __syncthreads();
    int j = jt * 256 + t;
    float a1 = 0.f, a2 = 0.f;
    const float* wp = a.fc1w + (size_t)(kseg * 96) * Dd + j;
#pragma unroll 8
    for (int dd = 0; dd < 96; ++dd) {
        float w = wp[(size_t)dd * Dd];
        a1 += xs[dd] * w;
        a2 += xs2[dd] * w;
    }
    atomicAdd(&a.aw1[(size_t)b * Dd + j], a1);
    atomicAdd(&a.aw2[(size_t)b * Dd + j], a2);
}

// ---- softgate: gate coeffs + masked softmax over L (+ pool coeffs at phase 1)
__device__ void softgate_dev(const KArgs& a, int phase, int b, float* shr) {
    int t = threadIdx.x;
    float ks[2], ga[2] = {0.f, 0.f}, gb2[2] = {0.f, 0.f};
#pragma unroll
    for (int i = 0; i < 2; ++i) {
        int l = t + (i << 8);
        size_t r = (size_t)b * Ls + l;
        float4 x = *(const float4*)(a.xd + r * 4);
        if (phase == 0) {
            float g = sigm(x.x + a.sc[b] + a.gb[0]);
            a.gx1[r] = g;
            ga[i] = g;
            ks[i] = 2.f * x.y + g * a.sc[32 + b];
        } else {
            float gp = a.gx1[r];
            float g = sigm(2.f * x.z + gp * a.sc[64 + b] + a.sc[224 + b] + a.gb[2]);
            a.gx2[r] = g;
            ga[i] = gp; gb2[i] = g;
            ks[i] = 4.f * x.w + 2.f * gp * a.sc[96 + b] + g * a.sc[256 + b];
        }
        if (a.mask[r] == 0) ks[i] = -1e9f;
    }
    float mx = fmaxf(ks[0], ks[1]);
#pragma unroll
    for (int o = 32; o > 0; o >>= 1) mx = fmaxf(mx, __shfl_down(mx, o, 64));
    if ((t & 63) == 0) shr[t >> 6] = mx;
    __syncthreads();
    mx = fmaxf(fmaxf(shr[0], shr[1]), fmaxf(shr[2], shr[3]));
    __syncthreads();
    float e0 = expf(ks[0] - mx), e1 = expf(ks[1] - mx);
    float s = blk_sum4(e0 + e1, shr);
    float inv = 1.f / s;
    float w0 = e0 * inv, w1 = e1 * inv;
    a.awb[(size_t)b * Ls + t] = w0;
    a.awb[(size_t)b * Ls + t + 256] = w1;
    float ca = blk_sum4(w0 * ga[0] + w1 * ga[1], shr);
    if (phase == 0) {
        if (t == 0) a.sc[320 + b] = ca;
    } else {
        if (t == 0) a.sc[352 + b] = ca;
        float cb = blk_sum4(w0 * gb2[0] + w1 * gb2[1], shr);
        if (t == 0) a.sc[384 + b] = cb;
        float q1a = a.pos1[(size_t)b * Ls + t], q1b = a.pos1[(size_t)b * Ls + t + 256];
        float q2a = a.pos2[(size_t)b * Ls + t], q2b = a.pos2[(size_t)b * Ls + t + 256];
        float s1 = blk_sum4(q1a + q1b, shr);
        float s2 = blk_sum4(q2a + q2b, shr);
        float c11 = blk_sum4(q1a * ga[0] + q1b * ga[1], shr);
        float c12 = blk_sum4(q1a * gb2[0] + q1b * gb2[1], shr);
        float c21 = blk_sum4(q2a * ga[0] + q2b * ga[1], shr);
        float c22 = blk_sum4(q2a * gb2[0] + q2b * gb2[1], shr);
        if (t == 0) {
            a.sc[448 + b] = c11; a.sc[480 + b] = c12;
            a.sc[512 + b] = c21; a.sc[544 + b] = c22;
            a.sc[576 + b] = 1.f / s1; a.sc[608 + b] = 1.f / s2;
        }
    }
}

// ---- passX: weighted sums of x0 rows (float4 lanes, t<192)
__device__ void passX_dev(const KArgs& a, int blk, float* S, bool dopos) {
    int t = threadIdx.x;
    if (t >= 192) return;
    int b = blk >> 4, seg = blk & 15, l0 = seg * 32;
    int d4 = t << 2;
    const float* xb = a.x0 + ((size_t)b * Ls + l0) * Dd + d4;
    const float* wb = a.awb + (size_t)b * Ls + l0;
    float4 as = make_float4(0.f,0.f,0.f,0.f);
    float4 a1 = make_float4(0.f,0.f,0.f,0.f);
    float4 a2 = make_float4(0.f,0.f,0.f,0.f);
    for (int l = 0; l < 32; ++l) {
        float4 xv = *(const float4*)(xb + (size_t)l * Dd);
        float wv = wb[l];
        as.x += wv*xv.x; as.y += wv*xv.y; as.z += wv*xv.z; as.w += wv*xv.w;
        if (dopos) {
            float q1 = a.pos1[(size_t)b * Ls + l0 + l], q2 = a.pos2[(size_t)b * Ls + l0 + l];
            a1.x += q1*xv.x; a1.y += q1*xv.y; a1.z += q1*xv.z; a1.w += q1*xv.w;
            a2.x += q2*xv.x; a2.y += q2*xv.y; a2.z += q2*xv.z; a2.w += q2*xv.w;
        }
    }
    float* ds = S + (size_t)b * Dd + d4;
    atomicAdd(ds+0, as.x); atomicAdd(ds+1, as.y); atomicAdd(ds+2, as.z); atomicAdd(ds+3, as.w);
    if (dopos) {
        float* d1 = a.xp1 + (size_t)b * Dd + d4;
        float* d2 = a.xp2 + (size_t)b * Dd + d4;
        atomicAdd(d1+0, a1.x); atomicAdd(d1+1, a1.y); atomicAdd(d1+2, a1.z); atomicAdd(d1+3, a1.w);
        atomicAdd(d2+0, a2.x); atomicAdd(d2+1, a2.y); atomicAdd(d2+2, a2.z); atomicAdd(d2+3, a2.w);
    }
}

// ---- kvec dots body
__device__ void kvec_dot(const KArgs& a, int dot, int lane) {
    int idx = dot / Dd, d = dot - idx * Dd;
    const float* row = a.kw + ((size_t)idx * Dd + d) * Dd;
    const float* swk = a.sw + (size_t)idx * 2 * Dd + Dd;
    float sA = 0.f;
    for (int j = lane; j < Dd; j += 64) sA += row[j] * swk[j];
    sA = wred(sA);
    if (lane == 0) a.kvecs[dot] = sA;
}

// ---- xdots body: wave-per-row over rows [r0, Bb*Ls) step rstep
__device__ void xdots_dev(const KArgs& a, int r0, int rstep, int lane) {
    float4 gs0[3], k1r[3], gs2[3], k3r[3];
#pragma unroll
    for (int k = 0; k < 3; ++k) {
        int d = (lane << 2) + k * 256;
        float4 ga = *(const float4*)(a.gw + d);
        float4 gbv = *(const float4*)(a.gw + 768 + d);
        gs0[k] = make_float4(ga.x+gbv.x, ga.y+gbv.y, ga.z+gbv.z, ga.w+gbv.w);
        k1r[k] = *(const float4*)(a.kvecs + 768 + d);
        float4 g2a = *(const float4*)(a.gw + 3072 + d);
        float4 g2b = *(const float4*)(a.gw + 3840 + d);
        gs2[k] = make_float4(g2a.x+g2b.x, g2a.y+g2b.y, g2a.z+g2b.z, g2a.w+g2b.w);
        k3r[k] = *(const float4*)(a.kvecs + 2304 + d);
    }
    for (int r = r0; r < Bb * Ls; r += rstep) {
        const float* xr = a.x0 + (size_t)r * Dd;
        float s0 = 0.f, s1 = 0.f, s2 = 0.f, s3 = 0.f;
#pragma unroll
        for (int k = 0; k < 3; ++k) {
            float4 xv = *(const float4*)(xr + (lane << 2) + k * 256);
            s0 += xv.x*gs0[k].x + xv.y*gs0[k].y + xv.z*gs0[k].z + xv.w*gs0[k].w;
            s1 += xv.x*k1r[k].x + xv.y*k1r[k].y + xv.z*k1r[k].z + xv.w*k1r[k].w;
            s2 += xv.x*gs2[k].x + xv.y*gs2[k].y + xv.z*gs2[k].z + xv.w*gs2[k].w;
            s3 += xv.x*k3r[k].x + xv.y*k3r[k].y + xv.z*k3r[k].z + xv.w*k3r[k].w;
        }
        s0 = wred(s0); s1 = wred(s1); s2 = wred(s2); s3 = wred(s3);
        if (lane == 0) {
            float4 o4 = make_float4(s0, s1, s2, s3);
            *(float4*)(a.xd + (size_t)r * 4) = o4;
        }
    }
}

// ---- pdots body
__device__ void pdots_dev(const KArgs& a, int g2, int lane) {
    for (int k = 0; k < 4; ++k) {
        int j = g2 + k * 128;
        if (k == 3) { if (g2 >= 4) break; j = 384 + g2; }
        if (j >= 388) continue;
        int vv = j / Cc, r = j - vv * Cc;
        const float* va; const float* vb2 = nullptr;
        if (vv == 0) va = a.kvecs;
        else if (vv == 1) va = a.kvecs + 2 * Dd;
        else if (vv == 2) { va = a.gw + 1536; vb2 = a.gw + 2304; }
        else { va = a.gw + 4608; vb2 = a.gw + 5376; }
        const float* row = a.p0b + (size_t)r * Dd;
        float sA = 0.f;
        for (int jj = lane; jj < Dd; jj += 64)
            sA += row[jj] * (va[jj] + (vb2 ? vb2[jj] : 0.f));
        sA = wred(sA);
        if (lane == 0) a.pdots[j] = sA;
    }
}

// ---- logits body; doMax: also feed packed argmax atomics
__device__ void logits_dev(const KArgs& a, int r, float* shr, bool doMax) {
    int t = threadIdx.x;
    int b = r / Cc, c = r - b * Cc;
    float g1 = a.g1buf[r];
    float g2 = sigm(2.f * a.pdots[291 + c] + g1 * a.sc[192 + b] + a.sc[288 + b] + a.gb[3]);
    float ssum = 0.f;
#pragma unroll
    for (int sseg = 0; sseg < 3; ++sseg) {
        int d = t + sseg * 256;
        float h = tanhf(4.f * a.pp[(size_t)c * Dd + d]
                      + 2.f * g1 * a.aw1[(size_t)b * Dd + d]
                      + g2 * a.aw2[(size_t)b * Dd + d]
                      + a.geb[(size_t)b * Dd + d]);
        ssum += h * a.fc2w[d];
    }
    float tt = blk_sum4(ssum, shr);
    if (t == 0) {
        float lg = sigm(tt + a.fc2b[0]);
        a.out[r] = lg;
        if (doMax) {
            // sigmoid > 0: float bits monotonic; ~c gives first-index tie-break
            unsigned long long key = ((unsigned long long)__float_as_uint(lg) << 32)
                                   | (unsigned)(0xFFFFFFFFu - (unsigned)c);
            atomicMax(&a.amax[b], key);
        }
    }
}

// ================= single fused cooperative kernel =================
__global__ __launch_bounds__(NTHR, 2) void kfused(KArgs a) {
    __shared__ float As[1024], Ws[1024];
    __shared__ float xs[96], xs2[96], lw[128], shr[16];
    const int blk = blockIdx.x, t = threadIdx.x;
    const int wv_ = t >> 6, lane = t & 63;

    // ---- P0: gemm1-direct (24 blocks) || zero workspace + kvecs dots (rest)
    if (blk < 24) {
        sgemm_direct(a.emb, a.rel_w, a.rel_b, a.p0b, Cc, Dd, Dd,
                     blk % 12, blk / 12, As, Ws);
    } else {
        for (size_t i = (size_t)(blk - 24) * NTHR + t; i < (size_t)a.zcount;
             i += (size_t)(GRID - 24) * NTHR)
            a.zbase[i] = 0.f;
        for (int dot = (blk - 24) * 4 + wv_; dot < 3072; dot += (GRID - 24) * 4)
            kvec_dot(a, dot, lane);
    }
    gbar(a.bctl);

    // ---- P1: ppGEMM-direct (24) || pdots (32) || xdots (456)
    if (blk < 24) {
        sgemm_direct(a.p0b, a.fc1w, nullptr, a.pp, Cc, Dd, Dd,
                     blk % 12, blk / 12, As, Ws);
    } else if (blk < 56) {
        pdots_dev(a, (blk - 24) * 4 + wv_, lane);
    } else {
        xdots_dev(a, (blk - 56) * 4 + wv_, (GRID - 56) * 4, lane);
    }
    gbar(a.bctl);

    // ---- P2: attn phase 0 (768 works)
    for (int j = blk; j < 768; j += GRID) attn_gemv(a, 0, j, xs, lw, shr);
    gbar(a.bctl);

    // ---- P3: softgate phase 0 (32 works)
    if (blk < 32) softgate_dev(a, 0, blk, shr);
    gbar(a.bctl);

    // ---- P4: passX0 -> S0, xp1, xp2 (512 works)
    for (int j = blk; j < 512; j += GRID) passX_dev(a, j, a.S0, true);
    gbar(a.bctl);

    // ---- P5: mm0 -> av1 (768 works)
    for (int j = blk; j < 768; j += GRID)
        mm_dev(a, j, a.S0, 2.f, a.avx1, a.sc + 320, 1.f, nullptr, nullptr, 0.f,
               a.vw + (size_t)1 * Dd * Dd, a.vb + Dd, a.av1,
               3, a.gw + 1536, nullptr, a.kvecs + 2 * Dd, a.gw + 4608, a.gw + 5376,
               a.sc + 128, xs, shr);
    gbar(a.bctl);

    // ---- P6: attn phase 1 (768 works)
    for (int j = blk; j < 768; j += GRID) attn_gemv(a, 1, j, xs, lw, shr);
    gbar(a.bctl);

    // ---- P7: softgate phase 1 (32 works)
    if (blk < 32) softgate_dev(a, 1, blk, shr);
    gbar(a.bctl);

    // ---- P8: passX1 (512) || ge bank (768) = 1280 works
    for (int w = blk; w < 1280; w += GRID) {
        if (w < 512) passX_dev(a, w, a.S1, false);
        else ge_dev(a, w - 512, xs, xs2);
    }
    gbar(a.bctl);

    // ---- P9: mm1 -> av2 (768 works)
    for (int j = blk; j < 768; j += GRID)
        mm_dev(a, j, a.S1, 4.f, a.avx1, a.sc + 352, 2.f, a.avx2, a.sc + 384, 1.f,
               a.vw + (size_t)3 * Dd * Dd, a.vb + 3 * Dd, a.av2,
               1, a.gw + 4608, nullptr, nullptr, nullptr, nullptr,
               a.sc + 288, xs, shr);
    gbar(a.bctl);

    // ---- P10: aw dual bank (768 works)
    for (int j = blk; j < 768; j += GRID) aw_dual_dev(a, j, xs, xs2);
    gbar(a.bctl);

    // ---- P11: logits (3104 works) + packed-atomic argmax, last block writes pred
    for (int r = blk; r < Bb * Cc; r += GRID) logits_dev(a, r, shr, true);
    if (t == 0) {
        __threadfence();
        if (atomicAdd(a.bctl + 19, 1) == GRID - 1) {
            __threadfence();
            for (int b = 0; b < Bb; ++b) {
                unsigned long long k =
                    __hip_atomic_load(&a.amax[b], __ATOMIC_RELAXED, __HIP_MEMORY_SCOPE_AGENT);
                a.out[Bb * Cc + b] = (float)(0xFFFFFFFFu - (unsigned)(k & 0xFFFFFFFFu));
            }
        }
    }
}

// ================= fallback kernels (non-cooperative pipeline) =================
__global__ __launch_bounds__(NTHR) void k_zero_kvec(KArgs a) {
    int blk = blockIdx.x, t = threadIdx.x;
    int wv_ = t >> 6, lane = t & 63;
    for (size_t i = (size_t)blk * NTHR + t; i < (size_t)a.zcount; i += (size_t)NBLK * NTHR)
        a.zbase[i] = 0.f;
    for (int dot = blk * 4 + wv_; dot < 3072; dot += NBLK * 4)
        kvec_dot(a, dot, lane);
}

__global__ __launch_bounds__(NTHR) void k_gemm1(KArgs a) {
    __shared__ float As[1024], Ws[1024];
    int blk = blockIdx.x;
    sgemm_direct(a.emb, a.rel_w, a.rel_b, a.p0b, Cc, Dd, Dd, blk % 12, blk / 12, As, Ws);
}

__global__ __launch_bounds__(NTHR) void k_prep2(KArgs a) {
    __shared__ float As[1024], Ws[1024];
    int blk = blockIdx.x, t = threadIdx.x;
    int wv_ = t >> 6, lane = t & 63;
    if (blk < 24) {
        sgemm_direct(a.p0b, a.fc1w, nullptr, a.pp, Cc, Dd, Dd, blk % 12, blk / 12, As, Ws);
    } else if (blk < 56) {
        pdots_dev(a, (blk - 24) * 4 + wv_, lane);
    } else {
        xdots_dev(a, (blk - 56) * 4 + wv_, (NBLK - 56) * 4, lane);
    }
}

__global__ __launch_bounds__(NTHR) void k_attn(KArgs a, int phase) {
    __shared__ float xs[96], lw[128], shr[16];
    attn_gemv(a, phase, blockIdx.x, xs, lw, shr);
}

__global__ __launch_bounds__(NTHR) void k_softgate(KArgs a, int phase) {
    __shared__ float shr[16];
    softgate_dev(a, phase, blockIdx.x, shr);
}

__global__ __launch_bounds__(NTHR) void k_passX0(KArgs a) {
    passX_dev(a, blockIdx.x, a.S0, true);
}

__global__ __launch_bounds__(NTHR) void k_mm0(KArgs a) {
    __shared__ float xs[96], shr[16];
    mm_dev(a, blockIdx.x, a.S0, 2.f, a.avx1, a.sc + 320, 1.f, nullptr, nullptr, 0.f,
           a.vw + (size_t)1 * Dd * Dd, a.vb + Dd, a.av1,
           3, a.gw + 1536, nullptr, a.kvecs + 2 * Dd, a.gw + 4608, a.gw + 5376,
           a.sc + 128, xs, shr);
}

__global__ __launch_bounds__(NTHR) void k_passX1ge(KArgs a) {
    __shared__ float xs[96], xs2[96];
    int blk = blockIdx.x;
    if (blk < 512) passX_dev(a, blk, a.S1, false);
    else ge_dev(a, blk - 512, xs, xs2);
}

__global__ __launch_bounds__(NTHR) void k_mm1(KArgs a) {
    __shared__ float xs[96], shr[16];
    mm_dev(a, blockIdx.x, a.S1, 4.f, a.avx1, a.sc + 352, 2.f, a.avx2, a.sc + 384, 1.f,
           a.vw + (size_t)3 * Dd * Dd, a.vb + 3 * Dd, a.av2,
           1, a.gw + 4608, nullptr, nullptr, nullptr, nullptr,
           a.sc + 288, xs, shr);
}

__global__ __launch_bounds__(NTHR) void k_awdual(KArgs a) {
    __shared__ float xs[96], xs2[96];
    aw_dual_dev(a, blockIdx.x, xs, xs2);
}

__global__ __launch_bounds__(NTHR) void k_logits(KArgs a) {
    __shared__ float shr[16];
    for (int r = blockIdx.x; r < Bb * Cc; r += NBLK) logits_dev(a, r, shr, false);
}

__global__ void k_argmax(KArgs a) {
    int t = threadIdx.x;
    if (t < Bb) {
        const float* row = a.out + (size_t)t * Cc;
        float best = row[0];
        int bi = 0;
        for (int c = 1; c < Cc; ++c) {
            float v = row[c];
            if (v > best) { best = v; bi = c; }
        }
        a.out[Bb * Cc + t] = (float)bi;
    }
}

extern "C" void kernel_launch(void* const* d_in, const int* in_sizes, int n_in,
                              void* d_out, int out_size, void* d_ws, size_t ws_size,
                              hipStream_t stream) {
    KArgs ka;
    ka.x0    = (const float*)d_in[0];
    ka.pos1  = (const float*)d_in[1];
    ka.pos2  = (const float*)d_in[2];
    ka.mask  = (const int*)d_in[3];
    ka.emb   = (const float*)d_in[4];
    ka.rel_w = (const float*)d_in[5];
    ka.rel_b = (const float*)d_in[6];
    // qw(7), qb(8) dead (softmax shift-invariance); kb(10), sb(14) dead (row-constant)
    ka.kw    = (const float*)d_in[9];
    ka.vw    = (const float*)d_in[11];
    ka.vb    = (const float*)d_in[12];
    ka.sw    = (const float*)d_in[13];
    ka.gw    = (const float*)d_in[15];
    ka.gb    = (const float*)d_in[16];
    ka.fc1w  = (const float*)d_in[17];
    ka.fc1b  = (const float*)d_in[18];
    ka.fc2w  = (const float*)d_in[19];
    ka.fc2b  = (const float*)d_in[20];
    ka.out   = (float*)d_out;

    float* ws = (float*)d_ws;
    size_t off = 0;
    const size_t PD = (size_t)Cc * Dd;
    const size_t BD = (size_t)Bb * Dd;
    // direct-write buffers (NOT zeroed): p0b, pp
    ka.p0b  = ws + off; off += PD;
    ka.pp   = ws + off; off += PD;
    // atomically-accumulated buffers (zeroed in-kernel): sc .. geb
    size_t zstart = off;
    ka.sc   = ws + off; off += 640;
    ka.avx1 = ws + off; off += BD;
    ka.avx2 = ws + off; off += BD;
    ka.av1  = ws + off; off += BD;
    ka.av2  = ws + off; off += BD;
    ka.aw1  = ws + off; off += BD;
    ka.aw2  = ws + off; off += BD;
    ka.S0   = ws + off; off += BD;
    ka.S1   = ws + off; off += BD;
    ka.xp1  = ws + off; off += BD;
    ka.xp2  = ws + off; off += BD;
    ka.geb  = ws + off; off += BD;
    ka.zbase = ws + zstart;
    ka.zcount = (int)(off - zstart);
    // plain-store buffers
    ka.kvecs = ws + off; off += (size_t)4 * Dd;
    ka.pdots = ws + off; off += 388;
    ka.g1buf = ws + off; off += (size_t)Bb * Cc;
    ka.xd    = ws + off; off += (size_t)Bb * Ls * 4;
    ka.gx1   = ws + off; off += (size_t)Bb * Ls;
    ka.gx2   = ws + off; off += (size_t)Bb * Ls;
    ka.awb   = ws + off; off += (size_t)Bb * Ls;
    // control region: amax[32] (8B-aligned) + bctl[64]
    off = (off + 1) & ~(size_t)1;
    ka.amax = (unsigned long long*)(ws + off); off += 64;   // 32 * 8B
    ka.bctl = (int*)(ws + off); off += 64;                  // 64 * 4B

    // zero the control region (barrier counters, generation, done, amax)
    hipMemsetAsync((void*)ka.amax, 0, 512, stream);

    void* params[] = { (void*)&ka };
    hipError_t err = hipLaunchCooperativeKernel((void*)kfused, dim3(GRID), dim3(NTHR),
                                                params, 0, stream);
    if (err != hipSuccess) {
        // fallback: known-good non-cooperative pipeline
        k_zero_kvec<<<NBLK, NTHR, 0, stream>>>(ka);
        k_gemm1<<<24, NTHR, 0, stream>>>(ka);
        k_prep2<<<NBLK, NTHR, 0, stream>>>(ka);
        k_attn<<<768, NTHR, 0, stream>>>(ka, 0);
        k_softgate<<<32, NTHR, 0, stream>>>(ka, 0);
        k_passX0<<<NBLK, NTHR, 0, stream>>>(ka);
        k_mm0<<<768, NTHR, 0, stream>>>(ka);
        k_attn<<<768, NTHR, 0, stream>>>(ka, 1);
        k_softgate<<<32, NTHR, 0, stream>>>(ka, 1);
        k_passX1ge<<<1280, NTHR, 0, stream>>>(ka);
        k_mm1<<<768, NTHR, 0, stream>>>(ka);
        k_awdual<<<768, NTHR, 0, stream>>>(ka);
        k_logits<<<NBLK, NTHR, 0, stream>>>(ka);
        k_argmax<<<1, 64, 0, stream>>>(ka);
    }
}

// Round 4
// 499.592 us; speedup vs baseline: 2.0581x; 2.0396x over previous
//
#include <hip/hip_runtime.h>
#include <math.h>

#define GRID 512
#define NBLK 512
#define NTHR 256
static const int Bb = 32, Ls = 512, Dd = 768, Cc = 97;

struct KArgs {
    const float *x0, *pos1, *pos2;
    const int* mask;
    const float *emb, *rel_w, *rel_b, *kw, *vw, *vb, *sw, *gw, *gb;
    const float *fc1w, *fc1b, *fc2w, *fc2b;
    float* out;
    float *p0b, *pp, *sc, *avx1, *avx2, *av1, *av2, *aw1, *aw2, *S0, *S1, *xp1, *xp2, *geb;
    float *kvecs, *pdots, *g1buf, *xd, *gx1, *gx2, *awb;
    float* zbase;
    int zcount;
    unsigned long long* amax;   // [32] packed (logit_bits<<32 | ~c)
    int* bctl;                  // padded barrier control, see layout in kernel_launch
};

__device__ __forceinline__ float sigm(float x) { return 1.f / (1.f + expf(-x)); }

// ---- agent-scope coherent scalar access (LLC-resident, no fence needed)
__device__ __forceinline__ float ldc(const float* p) {
    return __hip_atomic_load((float*)p, __ATOMIC_RELAXED, __HIP_MEMORY_SCOPE_AGENT);
}
__device__ __forceinline__ void stc(float* p, float v) {
    __hip_atomic_store(p, v, __ATOMIC_RELAXED, __HIP_MEMORY_SCOPE_AGENT);
}

__device__ __forceinline__ float wred(float v) {
#pragma unroll
    for (int o = 32; o > 0; o >>= 1) v += __shfl_down(v, o, 64);
    return v;
}

__device__ __forceinline__ float blk_sum4(float v, float* shr) {
    v = wred(v);
    int t = threadIdx.x;
    if ((t & 63) == 0) shr[t >> 6] = v;
    __syncthreads();
    float r = shr[0] + shr[1] + shr[2] + shr[3];
    __syncthreads();
    return r;
}

// ---- fence-free hierarchical grid barrier.
// All cross-phase data moves via agent-scope (LLC-coherent) ops, so no wbl2/inv
// is needed. __syncthreads() drains vmcnt (stores acked at LLC) before arrival.
// Monotonic counters: no resets, no reset races. Every counter/flag on its own
// 64B line: grp cnt @ g*16, root @ 256, gen @ 272, grp flag @ 288+g*16, done @ 560.
__device__ __forceinline__ void gbar(int* c, int& mygen) {
    __syncthreads();
    if (threadIdx.x == 0) {
        const int grp = blockIdx.x >> 5;
        int old = __hip_atomic_fetch_add(c + grp * 16, 1, __ATOMIC_RELAXED, __HIP_MEMORY_SCOPE_AGENT);
        if ((old & 31) == 31) {                      // last arrival of this group
            int rold = __hip_atomic_fetch_add(c + 256, 1, __ATOMIC_RELAXED, __HIP_MEMORY_SCOPE_AGENT);
            if ((rold & 15) == 15)                   // last group grid-wide
                __hip_atomic_store(c + 272, mygen + 1, __ATOMIC_RELAXED, __HIP_MEMORY_SCOPE_AGENT);
        }
        if ((blockIdx.x & 31) == 0) {                // group leader: poll gen, fan out
            while (__hip_atomic_load(c + 272, __ATOMIC_RELAXED, __HIP_MEMORY_SCOPE_AGENT) <= mygen)
                __builtin_amdgcn_s_sleep(4);
            __hip_atomic_store(c + 288 + grp * 16, mygen + 1, __ATOMIC_RELAXED, __HIP_MEMORY_SCOPE_AGENT);
        } else {                                     // member: poll group flag (<=32 pollers/line)
            while (__hip_atomic_load(c + 288 + grp * 16, __ATOMIC_RELAXED, __HIP_MEMORY_SCOPE_AGENT) <= mygen)
                __builtin_amdgcn_s_sleep(4);
        }
    }
    mygen += 1;
    __syncthreads();
}

// ---- direct-store full-K SGEMM tile: C[bm:+64, bn:+64] = A@W (+bias)
// cohA: A is an LLC-coherent intermediate. C always stored coherent.
__device__ void sgemm_direct(const float* __restrict__ A, const float* __restrict__ W,
                             const float* __restrict__ bias, float* __restrict__ C,
                             int M, int N, int K, int bx, int by, bool cohA,
                             float* As, float* Ws) {
    int tid = threadIdx.x;
    int tx = tid & 15, ty = tid >> 4;
    int bn = bx * 64, bm = by * 64;
    int arow = tid >> 2, akq = (tid & 3) << 2;
    int wrow = tid >> 4, wcol = (tid & 15) << 2;
    int gar = bm + arow;
    bool aval = gar < M;
    const float* Ap = A + (size_t)gar * K + akq;
    const float* Wp = W + (size_t)wrow * N + bn + wcol;
    float acc[4][4] = {{0.f}};
    float4 a4 = make_float4(0.f, 0.f, 0.f, 0.f);
    if (aval) {
        if (cohA) a4 = make_float4(ldc(Ap + 0), ldc(Ap + 1), ldc(Ap + 2), ldc(Ap + 3));
        else a4 = *(const float4*)Ap;
    }
    float4 w4 = *(const float4*)Wp;
    for (int k0 = 0; k0 < K; k0 += 16) {
        __syncthreads();
        As[(akq + 0) * 64 + arow] = a4.x; As[(akq + 1) * 64 + arow] = a4.y;
        As[(akq + 2) * 64 + arow] = a4.z; As[(akq + 3) * 64 + arow] = a4.w;
        *(float4*)&Ws[wrow * 64 + wcol] = w4;
        __syncthreads();
        if (k0 + 16 < K) {
            if (aval) {
                const float* Ap2 = Ap + k0 + 16;
                if (cohA) a4 = make_float4(ldc(Ap2 + 0), ldc(Ap2 + 1), ldc(Ap2 + 2), ldc(Ap2 + 3));
                else a4 = *(const float4*)Ap2;
            }
            w4 = *(const float4*)(Wp + (size_t)(k0 + 16) * N);
        }
#pragma unroll
        for (int kk = 0; kk < 16; ++kk) {
            float4 a = *(const float4*)&As[kk * 64 + (ty << 2)];
            float4 b = *(const float4*)&Ws[kk * 64 + (tx << 2)];
            acc[0][0]+=a.x*b.x; acc[0][1]+=a.x*b.y; acc[0][2]+=a.x*b.z; acc[0][3]+=a.x*b.w;
            acc[1][0]+=a.y*b.x; acc[1][1]+=a.y*b.y; acc[1][2]+=a.y*b.z; acc[1][3]+=a.y*b.w;
            acc[2][0]+=a.z*b.x; acc[2][1]+=a.z*b.y; acc[2][2]+=a.z*b.z; acc[2][3]+=a.z*b.w;
            acc[3][0]+=a.w*b.x; acc[3][1]+=a.w*b.y; acc[3][2]+=a.w*b.z; acc[3][3]+=a.w*b.w;
        }
    }
    int gc = bn + (tx << 2);
    float4 bz4 = make_float4(0.f, 0.f, 0.f, 0.f);
    if (bias) bz4 = *(const float4*)(bias + gc);
#pragma unroll
    for (int i = 0; i < 4; ++i) {
        int gr = bm + (ty << 2) + i;
        if (gr < M) {
            float* cp = C + (size_t)gr * N + gc;
            stc(cp + 0, acc[i][0] + bz4.x); stc(cp + 1, acc[i][1] + bz4.y);
            stc(cp + 2, acc[i][2] + bz4.z); stc(cp + 3, acc[i][3] + bz4.w);
        }
    }
}

// ---- fused relation-attention + V-GEMV bank; jlin in [0,768): jt%3, b, kseg/96
__device__ void attn_gemv(const KArgs& a, int phase, int jlin,
                          float* xs, float* lw, float* shr) {
    int t = threadIdx.x;
    int jt = jlin % 3, b = (jlin / 3) % 32, kseg = jlin / 96;
    float v = -3.0e38f, g1 = 0.f;
    if (t < Cc) {
        if (phase == 0) v = ldc(&a.pdots[t]);
        else {
            g1 = sigm(ldc(&a.pdots[194 + t]) + ldc(&a.sc[128 + b]) + a.gb[1]);
            v = 2.f * ldc(&a.pdots[97 + t]) + g1 * ldc(&a.sc[160 + b]);
        }
    }
    if (phase == 1 && jt == 0 && kseg == 0 && t < Cc) stc(&a.g1buf[(size_t)b * Cc + t], g1);
    float m = v;
#pragma unroll
    for (int o = 32; o > 0; o >>= 1) m = fmaxf(m, __shfl_down(m, o, 64));
    if ((t & 63) == 0) shr[t >> 6] = m;
    __syncthreads();
    m = fmaxf(fmaxf(shr[0], shr[1]), fmaxf(shr[2], shr[3]));
    __syncthreads();
    float e = (t < Cc) ? expf(v - m) : 0.f;
    float s = blk_sum4(e, shr);
    float wc = e / s;
    if (t < Cc) lw[t] = wc;
    float cg1 = blk_sum4(wc * g1, shr);   // publishes lw
    float alpha = (phase == 0) ? 1.f : 2.f;
    if (t < 96) {
        int d = kseg * 96 + t;
        const float* pc = a.p0b + d;
        float acc2 = 0.f;
#pragma unroll 4
        for (int c = 0; c < Cc; ++c) acc2 += lw[c] * ldc(&pc[(size_t)c * Dd]);
        float val = alpha * acc2;
        if (phase == 1) val += cg1 * ldc(&a.av1[(size_t)b * Dd + d]);
        xs[t] = val;
    }
    __syncthreads();
    const float* W = a.vw + (size_t)(phase == 0 ? 0 : 2) * Dd * Dd;
    const float* bias = a.vb + (phase == 0 ? 0 : 2) * Dd;
    float* outp = (phase == 0) ? a.avx1 : a.avx2;
    int j = jt * 256 + t;
    float acc = (kseg == 0) ? bias[j] : 0.f;
    const float* wp = W + (size_t)(kseg * 96) * Dd + j;
#pragma unroll 8
    for (int dd = 0; dd < 96; ++dd) acc += xs[dd] * wp[(size_t)dd * Dd];
    atomicAdd(&outp[(size_t)b * Dd + j], acc);
    const float* da[4]; const float* db[4]; int nd; float* dout;
    if (phase == 0) {
        da[0]=a.gw;          db[0]=nullptr;
        da[1]=a.kvecs+Dd;    db[1]=nullptr;
        da[2]=a.gw+3072;     db[2]=a.gw+3840;
        da[3]=a.kvecs+3*Dd;  db[3]=nullptr;
        nd = 4; dout = a.sc;
    } else {
        da[0]=a.gw+3072;     db[0]=nullptr;
        da[1]=a.kvecs+3*Dd;  db[1]=nullptr;
        nd = 2; dout = a.sc + 224;
    }
    for (int vv = 0; vv < nd; ++vv) {
        float wv = ldc(&da[vv][j]) + (db[vv] ? ldc(&db[vv][j]) : 0.f);
        float p = blk_sum4(acc * wv, shr);
        if (t == 0) atomicAdd(&dout[vv * 32 + b], p);
    }
    __syncthreads();
}

// ---- GEMV bank: out[b,:] += xs@Wseg; xs = gamma*S + multA*coefA[b]*avA + multB*coefB[b]*avB
__device__ void mm_dev(const KArgs& a, int jlin, const float* S, float gamma,
                       const float* avA, const float* coefA, float multA,
                       const float* avB, const float* coefB, float multB,
                       const float* W, const float* bias, float* outp,
                       int ndots, const float* d0a, const float* d0b,
                       const float* d1a, const float* d2a, const float* d2b,
                       float* dout, float* xs, float* shr) {
    int t = threadIdx.x;
    int jt = jlin % 3, b = (jlin / 3) % 32, kseg = jlin / 96;
    if (t < 96) {
        int d = kseg * 96 + t;
        float v = gamma * ldc(&S[(size_t)b * Dd + d]);
        if (avA) v += multA * ldc(&coefA[b]) * ldc(&avA[(size_t)b * Dd + d]);
        if (avB) v += multB * ldc(&coefB[b]) * ldc(&avB[(size_t)b * Dd + d]);
        xs[t] = v;
    }
    __syncthreads();
    int j = jt * 256 + t;
    float acc = (kseg == 0 && bias) ? bias[j] : 0.f;
    const float* wp = W + (size_t)(kseg * 96) * Dd + j;
#pragma unroll 8
    for (int dd = 0; dd < 96; ++dd) acc += xs[dd] * wp[(size_t)dd * Dd];
    atomicAdd(&outp[(size_t)b * Dd + j], acc);
    if (ndots > 0) {
        float wv = ldc(&d0a[j]) + (d0b ? ldc(&d0b[j]) : 0.f);
        float p = blk_sum4(acc * wv, shr);
        if (t == 0) atomicAdd(&dout[b], p);
    }
    if (ndots > 1) {
        float p = blk_sum4(acc * ldc(&d1a[j]), shr);
        if (t == 0) atomicAdd(&dout[32 + b], p);
    }
    if (ndots > 2) {
        float wv = ldc(&d2a[j]) + (d2b ? ldc(&d2b[j]) : 0.f);
        float p = blk_sum4(acc * wv, shr);
        if (t == 0) atomicAdd(&dout[64 + b], p);
    }
    __syncthreads();
}

// ---- ge bank: geb[b,:] += e1@W1seg + e2@W2seg (+fc1b at kseg 0)
__device__ void ge_dev(const KArgs& a, int jlin, float* xs, float* xs2) {
    int t = threadIdx.x;
    int jt = jlin % 3, b = (jlin / 3) % 32, kseg = jlin / 96;
    __syncthreads();
    if (t < 96) {
        int d = kseg * 96 + t;
        float a1 = ldc(&a.avx1[(size_t)b * Dd + d]), a2 = ldc(&a.avx2[(size_t)b * Dd + d]);
        xs[t]  = (4.f * ldc(&a.xp1[(size_t)b * Dd + d]) + 2.f * ldc(&a.sc[448 + b]) * a1
                  + ldc(&a.sc[480 + b]) * a2) * ldc(&a.sc[576 + b]);
        xs2[t] = (4.f * ldc(&a.xp2[(size_t)b * Dd + d]) + 2.f * ldc(&a.sc[512 + b]) * a1
                  + ldc(&a.sc[544 + b]) * a2) * ldc(&a.sc[608 + b]);
    }
    __syncthreads();
    int j = jt * 256 + t;
    float a1 = 0.f, a2 = 0.f;
    const float* w1 = a.fc1w + (size_t)(Dd + kseg * 96) * Dd + j;
    const float* w2 = a.fc1w + (size_t)(2 * Dd + kseg * 96) * Dd + j;
#pragma unroll 8
    for (int dd = 0; dd < 96; ++dd) {
        a1 += xs[dd] * w1[(size_t)dd * Dd];
        a2 += xs2[dd] * w2[(size_t)dd * Dd];
    }
    float res = a1 + a2 + (kseg == 0 ? a.fc1b[j] : 0.f);
    atomicAdd(&a.geb[(size_t)b * Dd + j], res);
}

// ---- dual bank sharing fc1w0: aw1 += av1@W, aw2 += av2@W (one W read)
__device__ void aw_dual_dev(const KArgs& a, int jlin, float* xs, float* xs2) {
    int t = threadIdx.x;
    int jt = jlin % 3, b = (jlin / 3) % 32, kseg = jlin / 96;
    __syncthreads();
    if (t < 96) {
        int d = kseg * 96 + t;
        xs[t]  = ldc(&a.av1[(size_t)b * Dd + d]);
        xs2[t] = ldc(&a.av2[(size_t)b * Dd + d]);
    }
    __syncthreads();
    int j = jt * 256 + t;
    float a1 = 0.f, a2 = 0.f;
    const float* wp = a.fc1w + (size_t)(kseg * 96) * Dd + j;
#pragma unroll 8
    for (int dd = 0; dd < 96; ++dd) {
        float w = wp[(size_t)dd * Dd];
        a1 += xs[dd] * w;
        a2 += xs2[dd] * w;
    }
    atomicAdd(&a.aw1[(size_t)b * Dd + j], a1);
    atomicAdd(&a.aw2[(size_t)b * Dd + j], a2);
}

// ---- softgate: gate coeffs + masked softmax over L (+ pool coeffs at phase 1)
__device__ void softgate_dev(const KArgs& a, int phase, int b, float* shr) {
    int t = threadIdx.x;
    float ks[2], ga[2] = {0.f, 0.f}, gb2[2] = {0.f, 0.f};
#pragma unroll
    for (int i = 0; i < 2; ++i) {
        int l = t + (i << 8);
        size_t r = (size_t)b * Ls + l;
        const float* px = a.xd + r * 4;
        if (phase == 0) {
            float g = sigm(ldc(px + 0) + ldc(&a.sc[b]) + a.gb[0]);
            stc(&a.gx1[r], g);
            ga[i] = g;
            ks[i] = 2.f * ldc(px + 1) + g * ldc(&a.sc[32 + b]);
        } else {
            float gp = ldc(&a.gx1[r]);
            float g = sigm(2.f * ldc(px + 2) + gp * ldc(&a.sc[64 + b]) + ldc(&a.sc[224 + b]) + a.gb[2]);
            stc(&a.gx2[r], g);
            ga[i] = gp; gb2[i] = g;
            ks[i] = 4.f * ldc(px + 3) + 2.f * gp * ldc(&a.sc[96 + b]) + g * ldc(&a.sc[256 + b]);
        }
        if (a.mask[r] == 0) ks[i] = -1e9f;
    }
    float mx = fmaxf(ks[0], ks[1]);
#pragma unroll
    for (int o = 32; o > 0; o >>= 1) mx = fmaxf(mx, __shfl_down(mx, o, 64));
    if ((t & 63) == 0) shr[t >> 6] = mx;
    __syncthreads();
    mx = fmaxf(fmaxf(shr[0], shr[1]), fmaxf(shr[2], shr[3]));
    __syncthreads();
    float e0 = expf(ks[0] - mx), e1 = expf(ks[1] - mx);
    float s = blk_sum4(e0 + e1, shr);
    float inv = 1.f / s;
    float w0 = e0 * inv, w1 = e1 * inv;
    stc(&a.awb[(size_t)b * Ls + t], w0);
    stc(&a.awb[(size_t)b * Ls + t + 256], w1);
    float ca = blk_sum4(w0 * ga[0] + w1 * ga[1], shr);
    if (phase == 0) {
        if (t == 0) stc(&a.sc[320 + b], ca);
    } else {
        if (t == 0) stc(&a.sc[352 + b], ca);
        float cb = blk_sum4(w0 * gb2[0] + w1 * gb2[1], shr);
        if (t == 0) stc(&a.sc[384 + b], cb);
        float q1a = a.pos1[(size_t)b * Ls + t], q1b = a.pos1[(size_t)b * Ls + t + 256];
        float q2a = a.pos2[(size_t)b * Ls + t], q2b = a.pos2[(size_t)b * Ls + t + 256];
        float s1 = blk_sum4(q1a + q1b, shr);
        float s2 = blk_sum4(q2a + q2b, shr);
        float c11 = blk_sum4(q1a * ga[0] + q1b * ga[1], shr);
        float c12 = blk_sum4(q1a * gb2[0] + q1b * gb2[1], shr);
        float c21 = blk_sum4(q2a * ga[0] + q2b * ga[1], shr);
        float c22 = blk_sum4(q2a * gb2[0] + q2b * gb2[1], shr);
        if (t == 0) {
            stc(&a.sc[448 + b], c11); stc(&a.sc[480 + b], c12);
            stc(&a.sc[512 + b], c21); stc(&a.sc[544 + b], c22);
            stc(&a.sc[576 + b], 1.f / s1); stc(&a.sc[608 + b], 1.f / s2);
        }
    }
}

// ---- passX: weighted sums of x0 rows (float4 lanes, t<192)
__device__ void passX_dev(const KArgs& a, int blk, float* S, bool dopos) {
    int t = threadIdx.x;
    if (t >= 192) return;
    int b = blk >> 4, seg = blk & 15, l0 = seg * 32;
    int d4 = t << 2;
    const float* xb = a.x0 + ((size_t)b * Ls + l0) * Dd + d4;
    const float* wb = a.awb + (size_t)b * Ls + l0;
    float4 as = make_float4(0.f,0.f,0.f,0.f);
    float4 a1 = make_float4(0.f,0.f,0.f,0.f);
    float4 a2 = make_float4(0.f,0.f,0.f,0.f);
    for (int l = 0; l < 32; ++l) {
        float4 xv = *(const float4*)(xb + (size_t)l * Dd);
        float wv = ldc(&wb[l]);
        as.x += wv*xv.x; as.y += wv*xv.y; as.z += wv*xv.z; as.w += wv*xv.w;
        if (dopos) {
            float q1 = a.pos1[(size_t)b * Ls + l0 + l], q2 = a.pos2[(size_t)b * Ls + l0 + l];
            a1.x += q1*xv.x; a1.y += q1*xv.y; a1.z += q1*xv.z; a1.w += q1*xv.w;
            a2.x += q2*xv.x; a2.y += q2*xv.y; a2.z += q2*xv.z; a2.w += q2*xv.w;
        }
    }
    float* ds = S + (size_t)b * Dd + d4;
    atomicAdd(ds+0, as.x); atomicAdd(ds+1, as.y); atomicAdd(ds+2, as.z); atomicAdd(ds+3, as.w);
    if (dopos) {
        float* d1 = a.xp1 + (size_t)b * Dd + d4;
        float* d2 = a.xp2 + (size_t)b * Dd + d4;
        atomicAdd(d1+0, a1.x); atomicAdd(d1+1, a1.y); atomicAdd(d1+2, a1.z); atomicAdd(d1+3, a1.w);
        atomicAdd(d2+0, a2.x); atomicAdd(d2+1, a2.y); atomicAdd(d2+2, a2.z); atomicAdd(d2+3, a2.w);
    }
}

// ---- kvec dots body
__device__ void kvec_dot(const KArgs& a, int dot, int lane) {
    int idx = dot / Dd, d = dot - idx * Dd;
    const float* row = a.kw + ((size_t)idx * Dd + d) * Dd;
    const float* swk = a.sw + (size_t)idx * 2 * Dd + Dd;
    float sA = 0.f;
    for (int j = lane; j < Dd; j += 64) sA += row[j] * swk[j];
    sA = wred(sA);
    if (lane == 0) stc(&a.kvecs[dot], sA);
}

// ---- xdots body: wave-per-row over rows [r0, Bb*Ls) step rstep
__device__ void xdots_dev(const KArgs& a, int r0, int rstep, int lane) {
    float4 gs0[3], k1r[3], gs2[3], k3r[3];
#pragma unroll
    for (int k = 0; k < 3; ++k) {
        int d = (lane << 2) + k * 256;
        float4 ga = *(const float4*)(a.gw + d);
        float4 gbv = *(const float4*)(a.gw + 768 + d);
        gs0[k] = make_float4(ga.x+gbv.x, ga.y+gbv.y, ga.z+gbv.z, ga.w+gbv.w);
        const float* k1p = a.kvecs + 768 + d;
        k1r[k] = make_float4(ldc(k1p+0), ldc(k1p+1), ldc(k1p+2), ldc(k1p+3));
        float4 g2a = *(const float4*)(a.gw + 3072 + d);
        float4 g2b = *(const float4*)(a.gw + 3840 + d);
        gs2[k] = make_float4(g2a.x+g2b.x, g2a.y+g2b.y, g2a.z+g2b.z, g2a.w+g2b.w);
        const float* k3p = a.kvecs + 2304 + d;
        k3r[k] = make_float4(ldc(k3p+0), ldc(k3p+1), ldc(k3p+2), ldc(k3p+3));
    }
    for (int r = r0; r < Bb * Ls; r += rstep) {
        const float* xr = a.x0 + (size_t)r * Dd;
        float s0 = 0.f, s1 = 0.f, s2 = 0.f, s3 = 0.f;
#pragma unroll
        for (int k = 0; k < 3; ++k) {
            float4 xv = *(const float4*)(xr + (lane << 2) + k * 256);
            s0 += xv.x*gs0[k].x + xv.y*gs0[k].y + xv.z*gs0[k].z + xv.w*gs0[k].w;
            s1 += xv.x*k1r[k].x + xv.y*k1r[k].y + xv.z*k1r[k].z + xv.w*k1r[k].w;
            s2 += xv.x*gs2[k].x + xv.y*gs2[k].y + xv.z*gs2[k].z + xv.w*gs2[k].w;
            s3 += xv.x*k3r[k].x + xv.y*k3r[k].y + xv.z*k3r[k].z + xv.w*k3r[k].w;
        }
        s0 = wred(s0); s1 = wred(s1); s2 = wred(s2); s3 = wred(s3);
        if (lane == 0) {
            float* op = a.xd + (size_t)r * 4;
            stc(op + 0, s0); stc(op + 1, s1); stc(op + 2, s2); stc(op + 3, s3);
        }
    }
}

// ---- pdots body
__device__ void pdots_dev(const KArgs& a, int g2, int lane) {
    for (int k = 0; k < 4; ++k) {
        int j = g2 + k * 128;
        if (k == 3) { if (g2 >= 4) break; j = 384 + g2; }
        if (j >= 388) continue;
        int vv = j / Cc, r = j - vv * Cc;
        const float* va; const float* vb2 = nullptr;
        if (vv == 0) va = a.kvecs;
        else if (vv == 1) va = a.kvecs + 2 * Dd;
        else if (vv == 2) { va = a.gw + 1536; vb2 = a.gw + 2304; }
        else { va = a.gw + 4608; vb2 = a.gw + 5376; }
        const float* row = a.p0b + (size_t)r * Dd;
        float sA = 0.f;
        for (int jj = lane; jj < Dd; jj += 64)
            sA += ldc(&row[jj]) * (ldc(&va[jj]) + (vb2 ? ldc(&vb2[jj]) : 0.f));
        sA = wred(sA);
        if (lane == 0) stc(&a.pdots[j], sA);
    }
}

// ---- logits body; doMax: also feed packed argmax atomics
__device__ void logits_dev(const KArgs& a, int r, float* shr, bool doMax) {
    int t = threadIdx.x;
    int b = r / Cc, c = r - b * Cc;
    float g1 = ldc(&a.g1buf[r]);
    float g2 = sigm(2.f * ldc(&a.pdots[291 + c]) + g1 * ldc(&a.sc[192 + b])
                    + ldc(&a.sc[288 + b]) + a.gb[3]);
    float ssum = 0.f;
#pragma unroll
    for (int sseg = 0; sseg < 3; ++sseg) {
        int d = t + sseg * 256;
        float h = tanhf(4.f * ldc(&a.pp[(size_t)c * Dd + d])
                      + 2.f * g1 * ldc(&a.aw1[(size_t)b * Dd + d])
                      + g2 * ldc(&a.aw2[(size_t)b * Dd + d])
                      + ldc(&a.geb[(size_t)b * Dd + d]));
        ssum += h * a.fc2w[d];
    }
    float tt = blk_sum4(ssum, shr);
    if (t == 0) {
        float lg = sigm(tt + a.fc2b[0]);
        a.out[r] = lg;
        if (doMax) {
            // sigmoid > 0: float bits monotonic; ~c gives first-index tie-break
            unsigned long long key = ((unsigned long long)__float_as_uint(lg) << 32)
                                   | (unsigned)(0xFFFFFFFFu - (unsigned)c);
            atomicMax(&a.amax[b], key);
        }
    }
}

// ================= single fused cooperative-style kernel =================
__global__ __launch_bounds__(NTHR, 2) void kfused(KArgs a) {
    __shared__ float As[1024], Ws[1024];
    __shared__ float xs[96], xs2[96], lw[128], shr[16];
    const int blk = blockIdx.x, t = threadIdx.x;
    const int wv_ = t >> 6, lane = t & 63;
    int mygen = 0;

    // ---- P0: gemm1-direct (24 blocks) || zero workspace + kvecs dots (rest)
    if (blk < 24) {
        sgemm_direct(a.emb, a.rel_w, a.rel_b, a.p0b, Cc, Dd, Dd,
                     blk % 12, blk / 12, false, As, Ws);
    } else {
        for (size_t i = (size_t)(blk - 24) * NTHR + t; i < (size_t)a.zcount;
             i += (size_t)(GRID - 24) * NTHR)
            stc(&a.zbase[i], 0.f);
        for (int dot = (blk - 24) * 4 + wv_; dot < 3072; dot += (GRID - 24) * 4)
            kvec_dot(a, dot, lane);
    }
    gbar(a.bctl, mygen);

    // ---- P1: ppGEMM-direct (24) || pdots (32) || xdots (456)
    if (blk < 24) {
        sgemm_direct(a.p0b, a.fc1w, nullptr, a.pp, Cc, Dd, Dd,
                     blk % 12, blk / 12, true, As, Ws);
    } else if (blk < 56) {
        pdots_dev(a, (blk - 24) * 4 + wv_, lane);
    } else {
        xdots_dev(a, (blk - 56) * 4 + wv_, (GRID - 56) * 4, lane);
    }
    gbar(a.bctl, mygen);

    // ---- P2: attn phase 0 (768 works)
    for (int j = blk; j < 768; j += GRID) attn_gemv(a, 0, j, xs, lw, shr);
    gbar(a.bctl, mygen);

    // ---- P3: softgate phase 0 (32 works)
    if (blk < 32) softgate_dev(a, 0, blk, shr);
    gbar(a.bctl, mygen);

    // ---- P4: passX0 -> S0, xp1, xp2 (512 works)
    for (int j = blk; j < 512; j += GRID) passX_dev(a, j, a.S0, true);
    gbar(a.bctl, mygen);

    // ---- P5: mm0 -> av1 (768 works)
    for (int j = blk; j < 768; j += GRID)
        mm_dev(a, j, a.S0, 2.f, a.avx1, a.sc + 320, 1.f, nullptr, nullptr, 0.f,
               a.vw + (size_t)1 * Dd * Dd, a.vb + Dd, a.av1,
               3, a.gw + 1536, nullptr, a.kvecs + 2 * Dd, a.gw + 4608, a.gw + 5376,
               a.sc + 128, xs, shr);
    gbar(a.bctl, mygen);

    // ---- P6: attn phase 1 (768 works)
    for (int j = blk; j < 768; j += GRID) attn_gemv(a, 1, j, xs, lw, shr);
    gbar(a.bctl, mygen);

    // ---- P7: softgate phase 1 (32 works)
    if (blk < 32) softgate_dev(a, 1, blk, shr);
    gbar(a.bctl, mygen);

    // ---- P8: passX1 (512) || ge bank (768) = 1280 works
    for (int w = blk; w < 1280; w += GRID) {
        if (w < 512) passX_dev(a, w, a.S1, false);
        else ge_dev(a, w - 512, xs, xs2);
    }
    gbar(a.bctl, mygen);

    // ---- P9: mm1 -> av2 (768 works)
    for (int j = blk; j < 768; j += GRID)
        mm_dev(a, j, a.S1, 4.f, a.avx1, a.sc + 352, 2.f, a.avx2, a.sc + 384, 1.f,
               a.vw + (size_t)3 * Dd * Dd, a.vb + 3 * Dd, a.av2,
               1, a.gw + 4608, nullptr, nullptr, nullptr, nullptr,
               a.sc + 288, xs, shr);
    gbar(a.bctl, mygen);

    // ---- P10: aw dual bank (768 works)
    for (int j = blk; j < 768; j += GRID) aw_dual_dev(a, j, xs, xs2);
    gbar(a.bctl, mygen);

    // ---- P11: logits (3104 works) + packed-atomic argmax, last block writes pred
    for (int r = blk; r < Bb * Cc; r += GRID) logits_dev(a, r, shr, true);
    __syncthreads();
    if (t == 0) {
        int old = __hip_atomic_fetch_add(a.bctl + 560, 1, __ATOMIC_RELAXED, __HIP_MEMORY_SCOPE_AGENT);
        if (old == GRID - 1) {
            for (int b = 0; b < Bb; ++b) {
                unsigned long long k =
                    __hip_atomic_load(&a.amax[b], __ATOMIC_RELAXED, __HIP_MEMORY_SCOPE_AGENT);
                a.out[Bb * Cc + b] = (float)(0xFFFFFFFFu - (unsigned)(k & 0xFFFFFFFFu));
            }
        }
    }
}

// ================= fallback kernels (non-cooperative pipeline) =================
__global__ __launch_bounds__(NTHR) void k_zero_kvec(KArgs a) {
    int blk = blockIdx.x, t = threadIdx.x;
    int wv_ = t >> 6, lane = t & 63;
    for (size_t i = (size_t)blk * NTHR + t; i < (size_t)a.zcount; i += (size_t)NBLK * NTHR)
        stc(&a.zbase[i], 0.f);
    for (int dot = blk * 4 + wv_; dot < 3072; dot += NBLK * 4)
        kvec_dot(a, dot, lane);
}

__global__ __launch_bounds__(NTHR) void k_gemm1(KArgs a) {
    __shared__ float As[1024], Ws[1024];
    int blk = blockIdx.x;
    sgemm_direct(a.emb, a.rel_w, a.rel_b, a.p0b, Cc, Dd, Dd, blk % 12, blk / 12, false, As, Ws);
}

__global__ __launch_bounds__(NTHR) void k_prep2(KArgs a) {
    __shared__ float As[1024], Ws[1024];
    int blk = blockIdx.x, t = threadIdx.x;
    int wv_ = t >> 6, lane = t & 63;
    if (blk < 24) {
        sgemm_direct(a.p0b, a.fc1w, nullptr, a.pp, Cc, Dd, Dd, blk % 12, blk / 12, true, As, Ws);
    } else if (blk < 56) {
        pdots_dev(a, (blk - 24) * 4 + wv_, lane);
    } else {
        xdots_dev(a, (blk - 56) * 4 + wv_, (NBLK - 56) * 4, lane);
    }
}

__global__ __launch_bounds__(NTHR) void k_attn(KArgs a, int phase) {
    __shared__ float xs[96], lw[128], shr[16];
    attn_gemv(a, phase, blockIdx.x, xs, lw, shr);
}

__global__ __launch_bounds__(NTHR) void k_softgate(KArgs a, int phase) {
    __shared__ float shr[16];
    softgate_dev(a, phase, blockIdx.x, shr);
}

__global__ __launch_bounds__(NTHR) void k_passX0(KArgs a) {
    passX_dev(a, blockIdx.x, a.S0, true);
}

__global__ __launch_bounds__(NTHR) void k_mm0(KArgs a) {
    __shared__ float xs[96], shr[16];
    mm_dev(a, blockIdx.x, a.S0, 2.f, a.avx1, a.sc + 320, 1.f, nullptr, nullptr, 0.f,
           a.vw + (size_t)1 * Dd * Dd, a.vb + Dd, a.av1,
           3, a.gw + 1536, nullptr, a.kvecs + 2 * Dd, a.gw + 4608, a.gw + 5376,
           a.sc + 128, xs, shr);
}

__global__ __launch_bounds__(NTHR) void k_passX1ge(KArgs a) {
    __shared__ float xs[96], xs2[96];
    int blk = blockIdx.x;
    if (blk < 512) passX_dev(a, blk, a.S1, false);
    else ge_dev(a, blk - 512, xs, xs2);
}

__global__ __launch_bounds__(NTHR) void k_mm1(KArgs a) {
    __shared__ float xs[96], shr[16];
    mm_dev(a, blockIdx.x, a.S1, 4.f, a.avx1, a.sc + 352, 2.f, a.avx2, a.sc + 384, 1.f,
           a.vw + (size_t)3 * Dd * Dd, a.vb + 3 * Dd, a.av2,
           1, a.gw + 4608, nullptr, nullptr, nullptr, nullptr,
           a.sc + 288, xs, shr);
}

__global__ __launch_bounds__(NTHR) void k_awdual(KArgs a) {
    __shared__ float xs[96], xs2[96];
    aw_dual_dev(a, blockIdx.x, xs, xs2);
}

__global__ __launch_bounds__(NTHR) void k_logits(KArgs a) {
    __shared__ float shr[16];
    for (int r = blockIdx.x; r < Bb * Cc; r += NBLK) logits_dev(a, r, shr, false);
}

__global__ void k_argmax(KArgs a) {
    int t = threadIdx.x;
    if (t < Bb) {
        const float* row = a.out + (size_t)t * Cc;
        float best = row[0];
        int bi = 0;
        for (int c = 1; c < Cc; ++c) {
            float v = row[c];
            if (v > best) { best = v; bi = c; }
        }
        a.out[Bb * Cc + t] = (float)bi;
    }
}

extern "C" void kernel_launch(void* const* d_in, const int* in_sizes, int n_in,
                              void* d_out, int out_size, void* d_ws, size_t ws_size,
                              hipStream_t stream) {
    KArgs ka;
    ka.x0    = (const float*)d_in[0];
    ka.pos1  = (const float*)d_in[1];
    ka.pos2  = (const float*)d_in[2];
    ka.mask  = (const int*)d_in[3];
    ka.emb   = (const float*)d_in[4];
    ka.rel_w = (const float*)d_in[5];
    ka.rel_b = (const float*)d_in[6];
    // qw(7), qb(8) dead (softmax shift-invariance); kb(10), sb(14) dead (row-constant)
    ka.kw    = (const float*)d_in[9];
    ka.vw    = (const float*)d_in[11];
    ka.vb    = (const float*)d_in[12];
    ka.sw    = (const float*)d_in[13];
    ka.gw    = (const float*)d_in[15];
    ka.gb    = (const float*)d_in[16];
    ka.fc1w  = (const float*)d_in[17];
    ka.fc1b  = (const float*)d_in[18];
    ka.fc2w  = (const float*)d_in[19];
    ka.fc2b  = (const float*)d_in[20];
    ka.out   = (float*)d_out;

    float* ws = (float*)d_ws;
    size_t off = 0;
    const size_t PD = (size_t)Cc * Dd;
    const size_t BD = (size_t)Bb * Dd;
    // direct-write buffers (NOT zeroed): p0b, pp
    ka.p0b  = ws + off; off += PD;
    ka.pp   = ws + off; off += PD;
    // atomically-accumulated buffers (zeroed in-kernel): sc .. geb
    size_t zstart = off;
    ka.sc   = ws + off; off += 640;
    ka.avx1 = ws + off; off += BD;
    ka.avx2 = ws + off; off += BD;
    ka.av1  = ws + off; off += BD;
    ka.av2  = ws + off; off += BD;
    ka.aw1  = ws + off; off += BD;
    ka.aw2  = ws + off; off += BD;
    ka.S0   = ws + off; off += BD;
    ka.S1   = ws + off; off += BD;
    ka.xp1  = ws + off; off += BD;
    ka.xp2  = ws + off; off += BD;
    ka.geb  = ws + off; off += BD;
    ka.zbase = ws + zstart;
    ka.zcount = (int)(off - zstart);
    // plain-store buffers
    ka.kvecs = ws + off; off += (size_t)4 * Dd;
    ka.pdots = ws + off; off += 388;
    ka.g1buf = ws + off; off += (size_t)Bb * Cc;
    ka.xd    = ws + off; off += (size_t)Bb * Ls * 4;
    ka.gx1   = ws + off; off += (size_t)Bb * Ls;
    ka.gx2   = ws + off; off += (size_t)Bb * Ls;
    ka.awb   = ws + off; off += (size_t)Bb * Ls;
    // control region: amax[32] (8B-aligned, 256B) + padded bctl (576 ints, one line
    // per counter: grp cnt @ g*16, root @ 256, gen @ 272, grp flag @ 288+g*16, done @ 560)
    off = (off + 1) & ~(size_t)1;
    ka.amax = (unsigned long long*)(ws + off); off += 64;   // 32 * 8B
    ka.bctl = (int*)(ws + off); off += 576;

    // zero the control region (amax 256B + bctl 2304B)
    hipMemsetAsync((void*)ka.amax, 0, 2560, stream);

    void* params[] = { (void*)&ka };
    hipError_t err = hipLaunchCooperativeKernel((void*)kfused, dim3(GRID), dim3(NTHR),
                                                params, 0, stream);
    if (err != hipSuccess) {
        // fallback: known-good non-cooperative pipeline
        k_zero_kvec<<<NBLK, NTHR, 0, stream>>>(ka);
        k_gemm1<<<24, NTHR, 0, stream>>>(ka);
        k_prep2<<<NBLK, NTHR, 0, stream>>>(ka);
        k_attn<<<768, NTHR, 0, stream>>>(ka, 0);
        k_softgate<<<32, NTHR, 0, stream>>>(ka, 0);
        k_passX0<<<NBLK, NTHR, 0, stream>>>(ka);
        k_mm0<<<768, NTHR, 0, stream>>>(ka);
        k_attn<<<768, NTHR, 0, stream>>>(ka, 1);
        k_softgate<<<32, NTHR, 0, stream>>>(ka, 1);
        k_passX1ge<<<1280, NTHR, 0, stream>>>(ka);
        k_mm1<<<768, NTHR, 0, stream>>>(ka);
        k_awdual<<<768, NTHR, 0, stream>>>(ka);
        k_logits<<<NBLK, NTHR, 0, stream>>>(ka);
        k_argmax<<<1, 64, 0, stream>>>(ka);
    }
}

// Round 8
// 366.484 us; speedup vs baseline: 2.8056x; 1.3632x over previous
//
#include <hip/hip_runtime.h>
#include <math.h>

#define NBLK 512
#define NTHR 256
static const int Bb = 32, Ls = 512, Dd = 768, Cc = 97;

struct KArgs {
    const float *x0, *pos1, *pos2;
    const int* mask;
    const float *emb, *rel_w, *rel_b, *kw, *vw, *vb, *sw, *gw, *gb;
    const float *fc1w, *fc1b, *fc2w, *fc2b;
    float* out;
    float *p0b, *pp, *sc, *avx1, *avx2, *av1, *av2, *aw1, *aw2, *S0, *S1, *xp1, *xp2, *geb;
    float *kvecs, *pdots, *g1buf, *xd;
    float* zbase;
    int zcount;
};

__device__ __forceinline__ float sigm(float x) { return 1.f / (1.f + expf(-x)); }

__device__ __forceinline__ float wred(float v) {
#pragma unroll
    for (int o = 32; o > 0; o >>= 1) v += __shfl_down(v, o, 64);
    return v;
}

__device__ __forceinline__ float blk_sum4(float v, float* shr) {
    v = wred(v);
    int t = threadIdx.x;
    if ((t & 63) == 0) shr[t >> 6] = v;
    __syncthreads();
    float r = shr[0] + shr[1] + shr[2] + shr[3];
    __syncthreads();
    return r;
}

// ---- direct-store full-K SGEMM tile: C[bm:+64, bn:+64] = A@W (+bias)
__device__ void sgemm_direct(const float* __restrict__ A, const float* __restrict__ W,
                             const float* __restrict__ bias, float* __restrict__ C,
                             int M, int N, int K, int bx, int by,
                             float* As, float* Ws) {
    int tid = threadIdx.x;
    int tx = tid & 15, ty = tid >> 4;
    int bn = bx * 64, bm = by * 64;
    int arow = tid >> 2, akq = (tid & 3) << 2;
    int wrow = tid >> 4, wcol = (tid & 15) << 2;
    int gar = bm + arow;
    bool aval = gar < M;
    const float* Ap = A + (size_t)gar * K + akq;
    const float* Wp = W + (size_t)wrow * N + bn + wcol;
    float acc[4][4] = {{0.f}};
    float4 a4 = make_float4(0.f, 0.f, 0.f, 0.f);
    if (aval) a4 = *(const float4*)Ap;
    float4 w4 = *(const float4*)Wp;
    for (int k0 = 0; k0 < K; k0 += 16) {
        __syncthreads();
        As[(akq + 0) * 64 + arow] = a4.x; As[(akq + 1) * 64 + arow] = a4.y;
        As[(akq + 2) * 64 + arow] = a4.z; As[(akq + 3) * 64 + arow] = a4.w;
        *(float4*)&Ws[wrow * 64 + wcol] = w4;
        __syncthreads();
        if (k0 + 16 < K) {
            if (aval) a4 = *(const float4*)(Ap + k0 + 16);
            w4 = *(const float4*)(Wp + (size_t)(k0 + 16) * N);
        }
#pragma unroll
        for (int kk = 0; kk < 16; ++kk) {
            float4 a = *(const float4*)&As[kk * 64 + (ty << 2)];
            float4 b = *(const float4*)&Ws[kk * 64 + (tx << 2)];
            acc[0][0]+=a.x*b.x; acc[0][1]+=a.x*b.y; acc[0][2]+=a.x*b.z; acc[0][3]+=a.x*b.w;
            acc[1][0]+=a.y*b.x; acc[1][1]+=a.y*b.y; acc[1][2]+=a.y*b.z; acc[1][3]+=a.y*b.w;
            acc[2][0]+=a.z*b.x; acc[2][1]+=a.z*b.y; acc[2][2]+=a.z*b.z; acc[2][3]+=a.z*b.w;
            acc[3][0]+=a.w*b.x; acc[3][1]+=a.w*b.y; acc[3][2]+=a.w*b.z; acc[3][3]+=a.w*b.w;
        }
    }
    int gc = bn + (tx << 2);
    float4 bz4 = make_float4(0.f, 0.f, 0.f, 0.f);
    if (bias) bz4 = *(const float4*)(bias + gc);
#pragma unroll
    for (int i = 0; i < 4; ++i) {
        int gr = bm + (ty << 2) + i;
        if (gr < M) {
            float4 o = make_float4(acc[i][0] + bz4.x, acc[i][1] + bz4.y,
                                   acc[i][2] + bz4.z, acc[i][3] + bz4.w);
            *(float4*)(C + (size_t)gr * N + gc) = o;
        }
    }
}

// ---- recompute masked softmax-over-L weights for batch b (deterministic;
// identical math to the verified softgate kernel, re-derived per block).
__device__ void sm_w(const KArgs& a, int phase, int b, float* shr,
                     float& w0o, float& w1o, float& ga0, float& ga1,
                     float& gb0o, float& gb1o) {
    int t = threadIdx.x;
    float ks[2], ga[2], gb2[2] = {0.f, 0.f};
#pragma unroll
    for (int i = 0; i < 2; ++i) {
        int l = t + (i << 8);
        size_t r = (size_t)b * Ls + l;
        const float* px = a.xd + r * 4;
        float gp = sigm(px[0] + a.sc[b] + a.gb[0]);
        if (phase == 0) {
            ga[i] = gp;
            ks[i] = 2.f * px[1] + gp * a.sc[32 + b];
        } else {
            float g = sigm(2.f * px[2] + gp * a.sc[64 + b] + a.sc[224 + b] + a.gb[2]);
            ga[i] = gp; gb2[i] = g;
            ks[i] = 4.f * px[3] + 2.f * gp * a.sc[96 + b] + g * a.sc[256 + b];
        }
        if (a.mask[r] == 0) ks[i] = -1e9f;
    }
    float mx = fmaxf(ks[0], ks[1]);
#pragma unroll
    for (int o = 32; o > 0; o >>= 1) mx = fmaxf(mx, __shfl_down(mx, o, 64));
    if ((t & 63) == 0) shr[t >> 6] = mx;
    __syncthreads();
    mx = fmaxf(fmaxf(shr[0], shr[1]), fmaxf(shr[2], shr[3]));
    __syncthreads();
    float e0 = expf(ks[0] - mx), e1 = expf(ks[1] - mx);
    float s = blk_sum4(e0 + e1, shr);
    float inv = 1.f / s;
    w0o = e0 * inv; w1o = e1 * inv;
    ga0 = ga[0]; ga1 = ga[1];
    gb0o = gb2[0]; gb1o = gb2[1];
}

// ---- coeff0: ca0 = sum(w*g) -> sc[320+b]  (mm0 coefA)
__device__ void coeff0_dev(const KArgs& a, int b, float* shr) {
    float w0, w1, ga0, ga1, u0, u1;
    sm_w(a, 0, b, shr, w0, w1, ga0, ga1, u0, u1);
    float ca = blk_sum4(w0 * ga0 + w1 * ga1, shr);
    if (threadIdx.x == 0) a.sc[320 + b] = ca;
}

// ---- coeff1: ca1/cb1 (mm1 coefs) + pool coeffs c11..c22, 1/s1, 1/s2 (ge)
__device__ void coeff1_dev(const KArgs& a, int b, float* shr) {
    int t = threadIdx.x;
    float w0, w1, ga0, ga1, g0, g1;
    sm_w(a, 1, b, shr, w0, w1, ga0, ga1, g0, g1);
    float ca = blk_sum4(w0 * ga0 + w1 * ga1, shr);
    if (t == 0) a.sc[352 + b] = ca;
    float cb = blk_sum4(w0 * g0 + w1 * g1, shr);
    if (t == 0) a.sc[384 + b] = cb;
    float q1a = a.pos1[(size_t)b * Ls + t], q1b = a.pos1[(size_t)b * Ls + t + 256];
    float q2a = a.pos2[(size_t)b * Ls + t], q2b = a.pos2[(size_t)b * Ls + t + 256];
    float s1 = blk_sum4(q1a + q1b, shr);
    float s2 = blk_sum4(q2a + q2b, shr);
    float c11 = blk_sum4(q1a * ga0 + q1b * ga1, shr);
    float c12 = blk_sum4(q1a * g0 + q1b * g1, shr);
    float c21 = blk_sum4(q2a * ga0 + q2b * ga1, shr);
    float c22 = blk_sum4(q2a * g0 + q2b * g1, shr);
    if (t == 0) {
        a.sc[448 + b] = c11; a.sc[480 + b] = c12;
        a.sc[512 + b] = c21; a.sc[544 + b] = c22;
        a.sc[576 + b] = 1.f / s1; a.sc[608 + b] = 1.f / s2;
    }
}

// ---- fused relation-attention + V-GEMV bank; jlin in [0,768): jt%3, b, kseg/96
__device__ void attn_gemv(const KArgs& a, int phase, int jlin,
                          float* xs, float* lw, float* shr) {
    int t = threadIdx.x;
    int jt = jlin % 3, b = (jlin / 3) % 32, kseg = jlin / 96;
    float v = -3.0e38f, g1 = 0.f;
    if (t < Cc) {
        if (phase == 0) v = a.pdots[t];
        else {
            g1 = sigm(a.pdots[194 + t] + a.sc[128 + b] + a.gb[1]);
            v = 2.f * a.pdots[97 + t] + g1 * a.sc[160 + b];
        }
    }
    if (phase == 1 && jt == 0 && kseg == 0 && t < Cc) a.g1buf[(size_t)b * Cc + t] = g1;
    float m = v;
#pragma unroll
    for (int o = 32; o > 0; o >>= 1) m = fmaxf(m, __shfl_down(m, o, 64));
    if ((t & 63) == 0) shr[t >> 6] = m;
    __syncthreads();
    m = fmaxf(fmaxf(shr[0], shr[1]), fmaxf(shr[2], shr[3]));
    __syncthreads();
    float e = (t < Cc) ? expf(v - m) : 0.f;
    float s = blk_sum4(e, shr);
    float wc = e / s;
    if (t < Cc) lw[t] = wc;
    float cg1 = blk_sum4(wc * g1, shr);   // publishes lw
    float alpha = (phase == 0) ? 1.f : 2.f;
    if (t < 96) {
        int d = kseg * 96 + t;
        const float* pc = a.p0b + d;
        float acc2 = 0.f;
#pragma unroll 4
        for (int c = 0; c < Cc; ++c) acc2 += lw[c] * pc[(size_t)c * Dd];
        float val = alpha * acc2;
        if (phase == 1) val += cg1 * a.av1[(size_t)b * Dd + d];
        xs[t] = val;
    }
    __syncthreads();
    const float* W = a.vw + (size_t)(phase == 0 ? 0 : 2) * Dd * Dd;
    const float* bias = a.vb + (phase == 0 ? 0 : 2) * Dd;
    float* outp = (phase == 0) ? a.avx1 : a.avx2;
    int j = jt * 256 + t;
    float acc = (kseg == 0) ? bias[j] : 0.f;
    const float* wp = W + (size_t)(kseg * 96) * Dd + j;
#pragma unroll 8
    for (int dd = 0; dd < 96; ++dd) acc += xs[dd] * wp[(size_t)dd * Dd];
    atomicAdd(&outp[(size_t)b * Dd + j], acc);
    const float* da[4]; const float* db[4]; int nd; float* dout;
    if (phase == 0) {
        da[0]=a.gw;          db[0]=nullptr;
        da[1]=a.kvecs+Dd;    db[1]=nullptr;
        da[2]=a.gw+3072;     db[2]=a.gw+3840;
        da[3]=a.kvecs+3*Dd;  db[3]=nullptr;
        nd = 4; dout = a.sc;
    } else {
        da[0]=a.gw+3072;     db[0]=nullptr;
        da[1]=a.kvecs+3*Dd;  db[1]=nullptr;
        nd = 2; dout = a.sc + 224;
    }
    for (int vv = 0; vv < nd; ++vv) {
        float wv = da[vv][j] + (db[vv] ? db[vv][j] : 0.f);
        float p = blk_sum4(acc * wv, shr);
        if (t == 0) atomicAdd(&dout[vv * 32 + b], p);
    }
    __syncthreads();
}

// ---- GEMV bank: out[b,:] += xs@Wseg
__device__ void mm_dev(const KArgs& a, int jlin, const float* S, float gamma,
                       const float* avA, const float* coefA, float multA,
                       const float* avB, const float* coefB, float multB,
                       const float* W, const float* bias, float* outp,
                       int ndots, const float* d0a, const float* d0b,
                       const float* d1a, const float* d2a, const float* d2b,
                       float* dout, float* xs, float* shr) {
    int t = threadIdx.x;
    int jt = jlin % 3, b = (jlin / 3) % 32, kseg = jlin / 96;
    if (t < 96) {
        int d = kseg * 96 + t;
        float v = gamma * S[(size_t)b * Dd + d];
        if (avA) v += multA * coefA[b] * avA[(size_t)b * Dd + d];
        if (avB) v += multB * coefB[b] * avB[(size_t)b * Dd + d];
        xs[t] = v;
    }
    __syncthreads();
    int j = jt * 256 + t;
    float acc = (kseg == 0 && bias) ? bias[j] : 0.f;
    const float* wp = W + (size_t)(kseg * 96) * Dd + j;
#pragma unroll 8
    for (int dd = 0; dd < 96; ++dd) acc += xs[dd] * wp[(size_t)dd * Dd];
    atomicAdd(&outp[(size_t)b * Dd + j], acc);
    if (ndots > 0) {
        float wv = d0a[j] + (d0b ? d0b[j] : 0.f);
        float p = blk_sum4(acc * wv, shr);
        if (t == 0) atomicAdd(&dout[b], p);
    }
    if (ndots > 1) {
        float p = blk_sum4(acc * d1a[j], shr);
        if (t == 0) atomicAdd(&dout[32 + b], p);
    }
    if (ndots > 2) {
        float wv = d2a[j] + (d2b ? d2b[j] : 0.f);
        float p = blk_sum4(acc * wv, shr);
        if (t == 0) atomicAdd(&dout[64 + b], p);
    }
}

// ---- ge bank: geb[b,:] += e1@W1seg + e2@W2seg (+fc1b at kseg 0)
__device__ void ge_dev(const KArgs& a, int jlin, float* xs, float* xs2) {
    int t = threadIdx.x;
    int jt = jlin % 3, b = (jlin / 3) % 32, kseg = jlin / 96;
    if (t < 96) {
        int d = kseg * 96 + t;
        float a1 = a.avx1[(size_t)b * Dd + d], a2 = a.avx2[(size_t)b * Dd + d];
        xs[t]  = (4.f * a.xp1[(size_t)b * Dd + d] + 2.f * a.sc[448 + b] * a1
                  + a.sc[480 + b] * a2) * a.sc[576 + b];
        xs2[t] = (4.f * a.xp2[(size_t)b * Dd + d] + 2.f * a.sc[512 + b] * a1
                  + a.sc[544 + b] * a2) * a.sc[608 + b];
    }
    __syncthreads();
    int j = jt * 256 + t;
    float a1 = 0.f, a2 = 0.f;
    const float* w1 = a.fc1w + (size_t)(Dd + kseg * 96) * Dd + j;
    const float* w2 = a.fc1w + (size_t)(2 * Dd + kseg * 96) * Dd + j;
#pragma unroll 8
    for (int dd = 0; dd < 96; ++dd) {
        a1 += xs[dd] * w1[(size_t)dd * Dd];
        a2 += xs2[dd] * w2[(size_t)dd * Dd];
    }
    float res = a1 + a2 + (kseg == 0 ? a.fc1b[j] : 0.f);
    atomicAdd(&a.geb[(size_t)b * Dd + j], res);
}

// ---- single bank: outp[b,:] += av[b,:]@fc1w0seg
__device__ void aw_one(const KArgs& a, int jlin, const float* av, float* outp, float* xs) {
    int t = threadIdx.x;
    int jt = jlin % 3, b = (jlin / 3) % 32, kseg = jlin / 96;
    if (t < 96) xs[t] = av[(size_t)b * Dd + kseg * 96 + t];
    __syncthreads();
    int j = jt * 256 + t;
    float acc = 0.f;
    const float* wp = a.fc1w + (size_t)(kseg * 96) * Dd + j;
#pragma unroll 8
    for (int dd = 0; dd < 96; ++dd) acc += xs[dd] * wp[(size_t)dd * Dd];
    atomicAdd(&outp[(size_t)b * Dd + j], acc);
}

// ---- passX: recompute softmax weights in-block, then weighted x0 sums
__device__ void passX_dev(const KArgs& a, int phase, int blk, float* S, bool dopos,
                          float* smw, float* shr) {
    int t = threadIdx.x;
    int b = blk >> 4, seg = blk & 15, l0 = seg * 32;
    {
        float w0, w1, u0, u1, u2, u3;
        sm_w(a, phase, b, shr, w0, w1, u0, u1, u2, u3);
        smw[t] = w0; smw[t + 256] = w1;
    }
    __syncthreads();
    if (t < 192) {
        int d4 = t << 2;
        const float* xb = a.x0 + ((size_t)b * Ls + l0) * Dd + d4;
        float4 as = make_float4(0.f,0.f,0.f,0.f);
        float4 a1 = make_float4(0.f,0.f,0.f,0.f);
        float4 a2 = make_float4(0.f,0.f,0.f,0.f);
        for (int l = 0; l < 32; ++l) {
            float4 xv = *(const float4*)(xb + (size_t)l * Dd);
            float wv = smw[l0 + l];
            as.x += wv*xv.x; as.y += wv*xv.y; as.z += wv*xv.z; as.w += wv*xv.w;
            if (dopos) {
                float q1 = a.pos1[(size_t)b * Ls + l0 + l], q2 = a.pos2[(size_t)b * Ls + l0 + l];
                a1.x += q1*xv.x; a1.y += q1*xv.y; a1.z += q1*xv.z; a1.w += q1*xv.w;
                a2.x += q2*xv.x; a2.y += q2*xv.y; a2.z += q2*xv.z; a2.w += q2*xv.w;
            }
        }
        float* ds = S + (size_t)b * Dd + d4;
        atomicAdd(ds+0, as.x); atomicAdd(ds+1, as.y); atomicAdd(ds+2, as.z); atomicAdd(ds+3, as.w);
        if (dopos) {
            float* d1 = a.xp1 + (size_t)b * Dd + d4;
            float* d2 = a.xp2 + (size_t)b * Dd + d4;
            atomicAdd(d1+0, a1.x); atomicAdd(d1+1, a1.y); atomicAdd(d1+2, a1.z); atomicAdd(d1+3, a1.w);
            atomicAdd(d2+0, a2.x); atomicAdd(d2+1, a2.y); atomicAdd(d2+2, a2.z); atomicAdd(d2+3, a2.w);
        }
    }
}

// ---- kvec dots body
__device__ void kvec_dot(const KArgs& a, int dot, int lane) {
    int idx = dot / Dd, d = dot - idx * Dd;
    const float* row = a.kw + ((size_t)idx * Dd + d) * Dd;
    const float* swk = a.sw + (size_t)idx * 2 * Dd + Dd;
    float sA = 0.f;
    for (int j = lane; j < Dd; j += 64) sA += row[j] * swk[j];
    sA = wred(sA);
    if (lane == 0) a.kvecs[dot] = sA;
}

// ---- xdots body: wave-per-row over rows [r0, Bb*Ls) step rstep
__device__ void xdots_dev(const KArgs& a, int r0, int rstep, int lane) {
    float4 gs0[3], k1r[3], gs2[3], k3r[3];
#pragma unroll
    for (int k = 0; k < 3; ++k) {
        int d = (lane << 2) + k * 256;
        float4 ga = *(const float4*)(a.gw + d);
        float4 gbv = *(const float4*)(a.gw + 768 + d);
        gs0[k] = make_float4(ga.x+gbv.x, ga.y+gbv.y, ga.z+gbv.z, ga.w+gbv.w);
        k1r[k] = *(const float4*)(a.kvecs + 768 + d);
        float4 g2a = *(const float4*)(a.gw + 3072 + d);
        float4 g2b = *(const float4*)(a.gw + 3840 + d);
        gs2[k] = make_float4(g2a.x+g2b.x, g2a.y+g2b.y, g2a.z+g2b.z, g2a.w+g2b.w);
        k3r[k] = *(const float4*)(a.kvecs + 2304 + d);
    }
    for (int r = r0; r < Bb * Ls; r += rstep) {
        const float* xr = a.x0 + (size_t)r * Dd;
        float s0 = 0.f, s1 = 0.f, s2 = 0.f, s3 = 0.f;
#pragma unroll
        for (int k = 0; k < 3; ++k) {
            float4 xv = *(const float4*)(xr + (lane << 2) + k * 256);
            s0 += xv.x*gs0[k].x + xv.y*gs0[k].y + xv.z*gs0[k].z + xv.w*gs0[k].w;
            s1 += xv.x*k1r[k].x + xv.y*k1r[k].y + xv.z*k1r[k].z + xv.w*k1r[k].w;
            s2 += xv.x*gs2[k].x + xv.y*gs2[k].y + xv.z*gs2[k].z + xv.w*gs2[k].w;
            s3 += xv.x*k3r[k].x + xv.y*k3r[k].y + xv.z*k3r[k].z + xv.w*k3r[k].w;
        }
        s0 = wred(s0); s1 = wred(s1); s2 = wred(s2); s3 = wred(s3);
        if (lane == 0) {
            float4 o4 = make_float4(s0, s1, s2, s3);
            *(float4*)(a.xd + (size_t)r * 4) = o4;
        }
    }
}

// ---- pdots body
__device__ void pdots_dev(const KArgs& a, int g2, int lane) {
    for (int k = 0; k < 4; ++k) {
        int j = g2 + k * 128;
        if (k == 3) { if (g2 >= 4) break; j = 384 + g2; }
        if (j >= 388) continue;
        int vv = j / Cc, r = j - vv * Cc;
        const float* va; const float* vb2 = nullptr;
        if (vv == 0) va = a.kvecs;
        else if (vv == 1) va = a.kvecs + 2 * Dd;
        else if (vv == 2) { va = a.gw + 1536; vb2 = a.gw + 2304; }
        else { va = a.gw + 4608; vb2 = a.gw + 5376; }
        const float* row = a.p0b + (size_t)r * Dd;
        float sA = 0.f;
        for (int jj = lane; jj < Dd; jj += 64)
            sA += row[jj] * (va[jj] + (vb2 ? vb2[jj] : 0.f));
        sA = wred(sA);
        if (lane == 0) a.pdots[j] = sA;
    }
}

// ---- logits body
__device__ void logits_dev(const KArgs& a, int r, float* shr) {
    int t = threadIdx.x;
    int b = r / Cc, c = r - b * Cc;
    float g1 = a.g1buf[r];
    float g2 = sigm(2.f * a.pdots[291 + c] + g1 * a.sc[192 + b] + a.sc[288 + b] + a.gb[3]);
    float ssum = 0.f;
#pragma unroll
    for (int sseg = 0; sseg < 3; ++sseg) {
        int d = t + sseg * 256;
        float h = tanhf(4.f * a.pp[(size_t)c * Dd + d]
                      + 2.f * g1 * a.aw1[(size_t)b * Dd + d]
                      + g2 * a.aw2[(size_t)b * Dd + d]
                      + a.geb[(size_t)b * Dd + d]);
        ssum += h * a.fc2w[d];
    }
    float tt = blk_sum4(ssum, shr);
    if (t == 0) a.out[r] = sigm(tt + a.fc2b[0]);
}

// ================= kernels (11-launch pipeline) =================
// K1: gemm1-direct (24) || zero accumulators + kvec dots (rest)
__global__ __launch_bounds__(NTHR) void k_zg(KArgs a) {
    __shared__ float As[1024], Ws[1024];
    int blk = blockIdx.x, t = threadIdx.x;
    int wv_ = t >> 6, lane = t & 63;
    if (blk < 24) {
        sgemm_direct(a.emb, a.rel_w, a.rel_b, a.p0b, Cc, Dd, Dd, blk % 12, blk / 12, As, Ws);
    } else {
        for (size_t i = (size_t)(blk - 24) * NTHR + t; i < (size_t)a.zcount;
             i += (size_t)(NBLK - 24) * NTHR)
            a.zbase[i] = 0.f;
        for (int dot = (blk - 24) * 4 + wv_; dot < 3072; dot += (NBLK - 24) * 4)
            kvec_dot(a, dot, lane);
    }
}

// K2: ppGEMM-direct (24) || pdots (32) || xdots (rest)
__global__ __launch_bounds__(NTHR) void k_prep2(KArgs a) {
    __shared__ float As[1024], Ws[1024];
    int blk = blockIdx.x, t = threadIdx.x;
    int wv_ = t >> 6, lane = t & 63;
    if (blk < 24) {
        sgemm_direct(a.p0b, a.fc1w, nullptr, a.pp, Cc, Dd, Dd, blk % 12, blk / 12, As, Ws);
    } else if (blk < 56) {
        pdots_dev(a, (blk - 24) * 4 + wv_, lane);
    } else {
        xdots_dev(a, (blk - 56) * 4 + wv_, (NBLK - 56) * 4, lane);
    }
}

// K3: attn phase 0
__global__ __launch_bounds__(NTHR) void k_attn0(KArgs a) {
    __shared__ float xs[96], lw[128], shr[16];
    attn_gemv(a, 0, blockIdx.x, xs, lw, shr);
}

// K4: passX0 (512) || coeff0 (32)
__global__ __launch_bounds__(NTHR) void k_p3(KArgs a) {
    __shared__ float smw[512], shr[16];
    int blk = blockIdx.x;
    if (blk < 512) passX_dev(a, 0, blk, a.S0, true, smw, shr);
    else coeff0_dev(a, blk - 512, shr);
}

// K5: mm0 -> av1
__global__ __launch_bounds__(NTHR) void k_mm0(KArgs a) {
    __shared__ float xs[96], shr[16];
    mm_dev(a, blockIdx.x, a.S0, 2.f, a.avx1, a.sc + 320, 1.f, nullptr, nullptr, 0.f,
           a.vw + (size_t)1 * Dd * Dd, a.vb + Dd, a.av1,
           3, a.gw + 1536, nullptr, a.kvecs + 2 * Dd, a.gw + 4608, a.gw + 5376,
           a.sc + 128, xs, shr);
}

// K6: attn phase 1 (768) || aw1 (768)
__global__ __launch_bounds__(NTHR) void k_p5(KArgs a) {
    __shared__ float xs[96], lw[128], shr[16];
    int blk = blockIdx.x;
    if (blk < 768) attn_gemv(a, 1, blk, xs, lw, shr);
    else aw_one(a, blk - 768, a.av1, a.aw1, xs);
}

// K7: passX1 (512) || coeff1 (32)
__global__ __launch_bounds__(NTHR) void k_p6(KArgs a) {
    __shared__ float smw[512], shr[16];
    int blk = blockIdx.x;
    if (blk < 512) passX_dev(a, 1, blk, a.S1, false, smw, shr);
    else coeff1_dev(a, blk - 512, shr);
}

// K8: mm1 (768) || ge (768)
__global__ __launch_bounds__(NTHR) void k_p7(KArgs a) {
    __shared__ float xs[96], xs2[96], shr[16];
    int blk = blockIdx.x;
    if (blk < 768)
        mm_dev(a, blk, a.S1, 4.f, a.avx1, a.sc + 352, 2.f, a.avx2, a.sc + 384, 1.f,
               a.vw + (size_t)3 * Dd * Dd, a.vb + 3 * Dd, a.av2,
               1, a.gw + 4608, nullptr, nullptr, nullptr, nullptr,
               a.sc + 288, xs, shr);
    else ge_dev(a, blk - 768, xs, xs2);
}

// K9: aw2
__global__ __launch_bounds__(NTHR) void k_aw2(KArgs a) {
    __shared__ float xs[96];
    aw_one(a, blockIdx.x, a.av2, a.aw2, xs);
}

// K10: logits
__global__ __launch_bounds__(NTHR) void k_logits(KArgs a) {
    __shared__ float shr[16];
    for (int r = blockIdx.x; r < Bb * Cc; r += NBLK) logits_dev(a, r, shr);
}

// K11: argmax
__global__ void k_argmax(KArgs a) {
    int t = threadIdx.x;
    if (t < Bb) {
        const float* row = a.out + (size_t)t * Cc;
        float best = row[0];
        int bi = 0;
        for (int c = 1; c < Cc; ++c) {
            float v = row[c];
            if (v > best) { best = v; bi = c; }
        }
        a.out[Bb * Cc + t] = (float)bi;
    }
}

extern "C" void kernel_launch(void* const* d_in, const int* in_sizes, int n_in,
                              void* d_out, int out_size, void* d_ws, size_t ws_size,
                              hipStream_t stream) {
    KArgs ka;
    ka.x0    = (const float*)d_in[0];
    ka.pos1  = (const float*)d_in[1];
    ka.pos2  = (const float*)d_in[2];
    ka.mask  = (const int*)d_in[3];
    ka.emb   = (const float*)d_in[4];
    ka.rel_w = (const float*)d_in[5];
    ka.rel_b = (const float*)d_in[6];
    // qw(7), qb(8) dead (softmax shift-invariance); kb(10), sb(14) dead (row-constant)
    ka.kw    = (const float*)d_in[9];
    ka.vw    = (const float*)d_in[11];
    ka.vb    = (const float*)d_in[12];
    ka.sw    = (const float*)d_in[13];
    ka.gw    = (const float*)d_in[15];
    ka.gb    = (const float*)d_in[16];
    ka.fc1w  = (const float*)d_in[17];
    ka.fc1b  = (const float*)d_in[18];
    ka.fc2w  = (const float*)d_in[19];
    ka.fc2b  = (const float*)d_in[20];
    ka.out   = (float*)d_out;

    float* ws = (float*)d_ws;
    size_t off = 0;
    const size_t PD = (size_t)Cc * Dd;
    const size_t BD = (size_t)Bb * Dd;
    // direct-write buffers (NOT zeroed): p0b, pp
    ka.p0b  = ws + off; off += PD;
    ka.pp   = ws + off; off += PD;
    // atomically-accumulated buffers (zeroed by K1): sc .. geb
    size_t zstart = off;
    ka.sc   = ws + off; off += 640;
    ka.avx1 = ws + off; off += BD;
    ka.avx2 = ws + off; off += BD;
    ka.av1  = ws + off; off += BD;
    ka.av2  = ws + off; off += BD;
    ka.aw1  = ws + off; off += BD;
    ka.aw2  = ws + off; off += BD;
    ka.S0   = ws + off; off += BD;
    ka.S1   = ws + off; off += BD;
    ka.xp1  = ws + off; off += BD;
    ka.xp2  = ws + off; off += BD;
    ka.geb  = ws + off; off += BD;
    ka.zbase = ws + zstart;
    ka.zcount = (int)(off - zstart);
    // plain-store buffers
    ka.kvecs = ws + off; off += (size_t)4 * Dd;
    ka.pdots = ws + off; off += 388;
    ka.g1buf = ws + off; off += (size_t)Bb * Cc;
    ka.xd    = ws + off; off += (size_t)Bb * Ls * 4;

    k_zg<<<NBLK, NTHR, 0, stream>>>(ka);
    k_prep2<<<NBLK, NTHR, 0, stream>>>(ka);
    k_attn0<<<768, NTHR, 0, stream>>>(ka);
    k_p3<<<544, NTHR, 0, stream>>>(ka);
    k_mm0<<<768, NTHR, 0, stream>>>(ka);
    k_p5<<<1536, NTHR, 0, stream>>>(ka);
    k_p6<<<544, NTHR, 0, stream>>>(ka);
    k_p7<<<1536, NTHR, 0, stream>>>(ka);
    k_aw2<<<768, NTHR, 0, stream>>>(ka);
    k_logits<<<NBLK, NTHR, 0, stream>>>(ka);
    k_argmax<<<1, 64, 0, stream>>>(ka);
}

// Round 9
// 329.647 us; speedup vs baseline: 3.1192x; 1.1117x over previous
//
#include <hip/hip_runtime.h>
#include <math.h>

#define NBLK 512
#define NTHR 256
static const int Bb = 32, Ls = 512, Dd = 768, Cc = 97;

struct KArgs {
    const float *x0, *pos1, *pos2;
    const int* mask;
    const float *emb, *rel_w, *rel_b, *kw, *vw, *vb, *sw, *gw, *gb;
    const float *fc1w, *fc1b, *fc2w, *fc2b;
    float* out;
    float *p0b, *pp, *sc, *avx1, *avx2, *av1, *av2, *aw1, *aw2, *S0, *S1, *xp1, *xp2, *geb;
    float *kvecs, *pdots, *g1buf, *xd;
};

__device__ __forceinline__ float sigm(float x) { return 1.f / (1.f + expf(-x)); }

__device__ __forceinline__ float wred(float v) {
#pragma unroll
    for (int o = 32; o > 0; o >>= 1) v += __shfl_down(v, o, 64);
    return v;
}

__device__ __forceinline__ float blk_sum4(float v, float* shr) {
    v = wred(v);
    int t = threadIdx.x;
    if ((t & 63) == 0) shr[t >> 6] = v;
    __syncthreads();
    float r = shr[0] + shr[1] + shr[2] + shr[3];
    __syncthreads();
    return r;
}

// ---- split-K SGEMM tile: C += A[:,kb:kb+KC]@W[kb:kb+KC,:] (+bias at bz==0); C pre-zeroed
__device__ void sgemm_dev(const float* __restrict__ A, const float* __restrict__ W,
                          const float* __restrict__ bias, float* __restrict__ C,
                          int M, int N, int K, int KC, int bx, int by, int bz,
                          float* As, float* Ws) {
    int tid = threadIdx.x;
    int tx = tid & 15, ty = tid >> 4;
    int bn = bx * 64, bm = by * 64;
    int kb = bz * KC;
    int arow = tid >> 2, akq = (tid & 3) << 2;
    int wrow = tid >> 4, wcol = (tid & 15) << 2;
    int gar = bm + arow;
    bool aval = gar < M;
    const float* Ap = A + (size_t)gar * K + kb + akq;
    const float* Wp = W + (size_t)(kb + wrow) * N + bn + wcol;
    float acc[4][4] = {{0.f}};
    float4 a4 = make_float4(0.f, 0.f, 0.f, 0.f);
    if (aval) a4 = *(const float4*)Ap;
    float4 w4 = *(const float4*)Wp;
    for (int k0 = 0; k0 < KC; k0 += 16) {
        __syncthreads();
        As[(akq + 0) * 64 + arow] = a4.x; As[(akq + 1) * 64 + arow] = a4.y;
        As[(akq + 2) * 64 + arow] = a4.z; As[(akq + 3) * 64 + arow] = a4.w;
        *(float4*)&Ws[wrow * 64 + wcol] = w4;
        __syncthreads();
        if (k0 + 16 < KC) {
            if (aval) a4 = *(const float4*)(Ap + k0 + 16);
            w4 = *(const float4*)(Wp + (size_t)(k0 + 16) * N);
        }
#pragma unroll
        for (int kk = 0; kk < 16; ++kk) {
            float4 a = *(const float4*)&As[kk * 64 + (ty << 2)];
            float4 b = *(const float4*)&Ws[kk * 64 + (tx << 2)];
            acc[0][0]+=a.x*b.x; acc[0][1]+=a.x*b.y; acc[0][2]+=a.x*b.z; acc[0][3]+=a.x*b.w;
            acc[1][0]+=a.y*b.x; acc[1][1]+=a.y*b.y; acc[1][2]+=a.y*b.z; acc[1][3]+=a.y*b.w;
            acc[2][0]+=a.z*b.x; acc[2][1]+=a.z*b.y; acc[2][2]+=a.z*b.z; acc[2][3]+=a.z*b.w;
            acc[3][0]+=a.w*b.x; acc[3][1]+=a.w*b.y; acc[3][2]+=a.w*b.z; acc[3][3]+=a.w*b.w;
        }
    }
    int gc = bn + (tx << 2);
    float4 bz4 = make_float4(0.f, 0.f, 0.f, 0.f);
    if (bz == 0 && bias) bz4 = *(const float4*)(bias + gc);
#pragma unroll
    for (int i = 0; i < 4; ++i) {
        int gr = bm + (ty << 2) + i;
        if (gr < M) {
            float* cp = C + (size_t)gr * N + gc;
            atomicAdd(cp + 0, acc[i][0] + bz4.x); atomicAdd(cp + 1, acc[i][1] + bz4.y);
            atomicAdd(cp + 2, acc[i][2] + bz4.z); atomicAdd(cp + 3, acc[i][3] + bz4.w);
        }
    }
}

// ---- recompute masked softmax-over-L weights for batch b (deterministic;
// identical math to the verified softgate kernel, re-derived per block).
__device__ void sm_w(const KArgs& a, int phase, int b, float* shr,
                     float& w0o, float& w1o, float& ga0, float& ga1,
                     float& gb0o, float& gb1o) {
    int t = threadIdx.x;
    float ks[2], ga[2], gb2[2] = {0.f, 0.f};
#pragma unroll
    for (int i = 0; i < 2; ++i) {
        int l = t + (i << 8);
        size_t r = (size_t)b * Ls + l;
        const float* px = a.xd + r * 4;
        float gp = sigm(px[0] + a.sc[b] + a.gb[0]);
        if (phase == 0) {
            ga[i] = gp;
            ks[i] = 2.f * px[1] + gp * a.sc[32 + b];
        } else {
            float g = sigm(2.f * px[2] + gp * a.sc[64 + b] + a.sc[224 + b] + a.gb[2]);
            ga[i] = gp; gb2[i] = g;
            ks[i] = 4.f * px[3] + 2.f * gp * a.sc[96 + b] + g * a.sc[256 + b];
        }
        if (a.mask[r] == 0) ks[i] = -1e9f;
    }
    float mx = fmaxf(ks[0], ks[1]);
#pragma unroll
    for (int o = 32; o > 0; o >>= 1) mx = fmaxf(mx, __shfl_down(mx, o, 64));
    if ((t & 63) == 0) shr[t >> 6] = mx;
    __syncthreads();
    mx = fmaxf(fmaxf(shr[0], shr[1]), fmaxf(shr[2], shr[3]));
    __syncthreads();
    float e0 = expf(ks[0] - mx), e1 = expf(ks[1] - mx);
    float s = blk_sum4(e0 + e1, shr);
    float inv = 1.f / s;
    w0o = e0 * inv; w1o = e1 * inv;
    ga0 = ga[0]; ga1 = ga[1];
    gb0o = gb2[0]; gb1o = gb2[1];
}

// ---- coeff0: ca0 = sum(w*g) -> sc[320+b]  (mm0 coefA)
__device__ void coeff0_dev(const KArgs& a, int b, float* shr) {
    float w0, w1, ga0, ga1, u0, u1;
    sm_w(a, 0, b, shr, w0, w1, ga0, ga1, u0, u1);
    float ca = blk_sum4(w0 * ga0 + w1 * ga1, shr);
    if (threadIdx.x == 0) a.sc[320 + b] = ca;
}

// ---- coeff1: ca1/cb1 (mm1 coefs) + pool coeffs c11..c22, 1/s1, 1/s2 (ge)
__device__ void coeff1_dev(const KArgs& a, int b, float* shr) {
    int t = threadIdx.x;
    float w0, w1, ga0, ga1, g0, g1;
    sm_w(a, 1, b, shr, w0, w1, ga0, ga1, g0, g1);
    float ca = blk_sum4(w0 * ga0 + w1 * ga1, shr);
    if (t == 0) a.sc[352 + b] = ca;
    float cb = blk_sum4(w0 * g0 + w1 * g1, shr);
    if (t == 0) a.sc[384 + b] = cb;
    float q1a = a.pos1[(size_t)b * Ls + t], q1b = a.pos1[(size_t)b * Ls + t + 256];
    float q2a = a.pos2[(size_t)b * Ls + t], q2b = a.pos2[(size_t)b * Ls + t + 256];
    float s1 = blk_sum4(q1a + q1b, shr);
    float s2 = blk_sum4(q2a + q2b, shr);
    float c11 = blk_sum4(q1a * ga0 + q1b * ga1, shr);
    float c12 = blk_sum4(q1a * g0 + q1b * g1, shr);
    float c21 = blk_sum4(q2a * ga0 + q2b * ga1, shr);
    float c22 = blk_sum4(q2a * g0 + q2b * g1, shr);
    if (t == 0) {
        a.sc[448 + b] = c11; a.sc[480 + b] = c12;
        a.sc[512 + b] = c21; a.sc[544 + b] = c22;
        a.sc[576 + b] = 1.f / s1; a.sc[608 + b] = 1.f / s2;
    }
}

// ---- fused relation-attention + V-GEMV bank; jlin in [0,768): jt%3, b, kseg/96
__device__ void attn_gemv(const KArgs& a, int phase, int jlin,
                          float* xs, float* lw, float* shr) {
    int t = threadIdx.x;
    int jt = jlin % 3, b = (jlin / 3) % 32, kseg = jlin / 96;
    float v = -3.0e38f, g1 = 0.f;
    if (t < Cc) {
        if (phase == 0) v = a.pdots[t];
        else {
            g1 = sigm(a.pdots[194 + t] + a.sc[128 + b] + a.gb[1]);
            v = 2.f * a.pdots[97 + t] + g1 * a.sc[160 + b];
        }
    }
    if (phase == 1 && jt == 0 && kseg == 0 && t < Cc) a.g1buf[(size_t)b * Cc + t] = g1;
    float m = v;
#pragma unroll
    for (int o = 32; o > 0; o >>= 1) m = fmaxf(m, __shfl_down(m, o, 64));
    if ((t & 63) == 0) shr[t >> 6] = m;
    __syncthreads();
    m = fmaxf(fmaxf(shr[0], shr[1]), fmaxf(shr[2], shr[3]));
    __syncthreads();
    float e = (t < Cc) ? expf(v - m) : 0.f;
    float s = blk_sum4(e, shr);
    float wc = e / s;
    if (t < Cc) lw[t] = wc;
    float cg1 = blk_sum4(wc * g1, shr);   // publishes lw
    float alpha = (phase == 0) ? 1.f : 2.f;
    if (t < 96) {
        int d = kseg * 96 + t;
        const float* pc = a.p0b + d;
        float acc2 = 0.f;
#pragma unroll 4
        for (int c = 0; c < Cc; ++c) acc2 += lw[c] * pc[(size_t)c * Dd];
        float val = alpha * acc2;
        if (phase == 1) val += cg1 * a.av1[(size_t)b * Dd + d];
        xs[t] = val;
    }
    __syncthreads();
    const float* W = a.vw + (size_t)(phase == 0 ? 0 : 2) * Dd * Dd;
    const float* bias = a.vb + (phase == 0 ? 0 : 2) * Dd;
    float* outp = (phase == 0) ? a.avx1 : a.avx2;
    int j = jt * 256 + t;
    float acc = (kseg == 0) ? bias[j] : 0.f;
    const float* wp = W + (size_t)(kseg * 96) * Dd + j;
#pragma unroll 8
    for (int dd = 0; dd < 96; ++dd) acc += xs[dd] * wp[(size_t)dd * Dd];
    atomicAdd(&outp[(size_t)b * Dd + j], acc);
    const float* da[4]; const float* db[4]; int nd; float* dout;
    if (phase == 0) {
        da[0]=a.gw;          db[0]=nullptr;
        da[1]=a.kvecs+Dd;    db[1]=nullptr;
        da[2]=a.gw+3072;     db[2]=a.gw+3840;
        da[3]=a.kvecs+3*Dd;  db[3]=nullptr;
        nd = 4; dout = a.sc;
    } else {
        da[0]=a.gw+3072;     db[0]=nullptr;
        da[1]=a.kvecs+3*Dd;  db[1]=nullptr;
        nd = 2; dout = a.sc + 224;
    }
    for (int vv = 0; vv < nd; ++vv) {
        float wv = da[vv][j] + (db[vv] ? db[vv][j] : 0.f);
        float p = blk_sum4(acc * wv, shr);
        if (t == 0) atomicAdd(&dout[vv * 32 + b], p);
    }
    __syncthreads();
}

// ---- GEMV bank: out[b,:] += xs@Wseg
__device__ void mm_dev(const KArgs& a, int jlin, const float* S, float gamma,
                       const float* avA, const float* coefA, float multA,
                       const float* avB, const float* coefB, float multB,
                       const float* W, const float* bias, float* outp,
                       int ndots, const float* d0a, const float* d0b,
                       const float* d1a, const float* d2a, const float* d2b,
                       float* dout, float* xs, float* shr) {
    int t = threadIdx.x;
    int jt = jlin % 3, b = (jlin / 3) % 32, kseg = jlin / 96;
    if (t < 96) {
        int d = kseg * 96 + t;
        float v = gamma * S[(size_t)b * Dd + d];
        if (avA) v += multA * coefA[b] * avA[(size_t)b * Dd + d];
        if (avB) v += multB * coefB[b] * avB[(size_t)b * Dd + d];
        xs[t] = v;
    }
    __syncthreads();
    int j = jt * 256 + t;
    float acc = (kseg == 0 && bias) ? bias[j] : 0.f;
    const float* wp = W + (size_t)(kseg * 96) * Dd + j;
#pragma unroll 8
    for (int dd = 0; dd < 96; ++dd) acc += xs[dd] * wp[(size_t)dd * Dd];
    atomicAdd(&outp[(size_t)b * Dd + j], acc);
    if (ndots > 0) {
        float wv = d0a[j] + (d0b ? d0b[j] : 0.f);
        float p = blk_sum4(acc * wv, shr);
        if (t == 0) atomicAdd(&dout[b], p);
    }
    if (ndots > 1) {
        float p = blk_sum4(acc * d1a[j], shr);
        if (t == 0) atomicAdd(&dout[32 + b], p);
    }
    if (ndots > 2) {
        float wv = d2a[j] + (d2b ? d2b[j] : 0.f);
        float p = blk_sum4(acc * wv, shr);
        if (t == 0) atomicAdd(&dout[64 + b], p);
    }
}

// ---- ge bank: geb[b,:] += e1@W1seg + e2@W2seg (+fc1b at kseg 0)
__device__ void ge_dev(const KArgs& a, int jlin, float* xs, float* xs2) {
    int t = threadIdx.x;
    int jt = jlin % 3, b = (jlin / 3) % 32, kseg = jlin / 96;
    if (t < 96) {
        int d = kseg * 96 + t;
        float a1 = a.avx1[(size_t)b * Dd + d], a2 = a.avx2[(size_t)b * Dd + d];
        xs[t]  = (4.f * a.xp1[(size_t)b * Dd + d] + 2.f * a.sc[448 + b] * a1
                  + a.sc[480 + b] * a2) * a.sc[576 + b];
        xs2[t] = (4.f * a.xp2[(size_t)b * Dd + d] + 2.f * a.sc[512 + b] * a1
                  + a.sc[544 + b] * a2) * a.sc[608 + b];
    }
    __syncthreads();
    int j = jt * 256 + t;
    float a1 = 0.f, a2 = 0.f;
    const float* w1 = a.fc1w + (size_t)(Dd + kseg * 96) * Dd + j;
    const float* w2 = a.fc1w + (size_t)(2 * Dd + kseg * 96) * Dd + j;
#pragma unroll 8
    for (int dd = 0; dd < 96; ++dd) {
        a1 += xs[dd] * w1[(size_t)dd * Dd];
        a2 += xs2[dd] * w2[(size_t)dd * Dd];
    }
    float res = a1 + a2 + (kseg == 0 ? a.fc1b[j] : 0.f);
    atomicAdd(&a.geb[(size_t)b * Dd + j], res);
}

// ---- single bank: outp[b,:] += av[b,:]@fc1w0seg
__device__ void aw_one(const KArgs& a, int jlin, const float* av, float* outp, float* xs) {
    int t = threadIdx.x;
    int jt = jlin % 3, b = (jlin / 3) % 32, kseg = jlin / 96;
    if (t < 96) xs[t] = av[(size_t)b * Dd + kseg * 96 + t];
    __syncthreads();
    int j = jt * 256 + t;
    float acc = 0.f;
    const float* wp = a.fc1w + (size_t)(kseg * 96) * Dd + j;
#pragma unroll 8
    for (int dd = 0; dd < 96; ++dd) acc += xs[dd] * wp[(size_t)dd * Dd];
    atomicAdd(&outp[(size_t)b * Dd + j], acc);
}

// ---- passX: recompute softmax weights in-block, then weighted x0 sums
__device__ void passX_dev(const KArgs& a, int phase, int blk, float* S, bool dopos,
                          float* smw, float* shr) {
    int t = threadIdx.x;
    int b = blk >> 4, seg = blk & 15, l0 = seg * 32;
    {
        float w0, w1, u0, u1, u2, u3;
        sm_w(a, phase, b, shr, w0, w1, u0, u1, u2, u3);
        smw[t] = w0; smw[t + 256] = w1;
    }
    __syncthreads();
    if (t < 192) {
        int d4 = t << 2;
        const float* xb = a.x0 + ((size_t)b * Ls + l0) * Dd + d4;
        float4 as = make_float4(0.f,0.f,0.f,0.f);
        float4 a1 = make_float4(0.f,0.f,0.f,0.f);
        float4 a2 = make_float4(0.f,0.f,0.f,0.f);
        for (int l = 0; l < 32; ++l) {
            float4 xv = *(const float4*)(xb + (size_t)l * Dd);
            float wv = smw[l0 + l];
            as.x += wv*xv.x; as.y += wv*xv.y; as.z += wv*xv.z; as.w += wv*xv.w;
            if (dopos) {
                float q1 = a.pos1[(size_t)b * Ls + l0 + l], q2 = a.pos2[(size_t)b * Ls + l0 + l];
                a1.x += q1*xv.x; a1.y += q1*xv.y; a1.z += q1*xv.z; a1.w += q1*xv.w;
                a2.x += q2*xv.x; a2.y += q2*xv.y; a2.z += q2*xv.z; a2.w += q2*xv.w;
            }
        }
        float* ds = S + (size_t)b * Dd + d4;
        atomicAdd(ds+0, as.x); atomicAdd(ds+1, as.y); atomicAdd(ds+2, as.z); atomicAdd(ds+3, as.w);
        if (dopos) {
            float* d1 = a.xp1 + (size_t)b * Dd + d4;
            float* d2 = a.xp2 + (size_t)b * Dd + d4;
            atomicAdd(d1+0, a1.x); atomicAdd(d1+1, a1.y); atomicAdd(d1+2, a1.z); atomicAdd(d1+3, a1.w);
            atomicAdd(d2+0, a2.x); atomicAdd(d2+1, a2.y); atomicAdd(d2+2, a2.z); atomicAdd(d2+3, a2.w);
        }
    }
}

// ---- kvec dots body
__device__ void kvec_dot(const KArgs& a, int dot, int lane) {
    int idx = dot / Dd, d = dot - idx * Dd;
    const float* row = a.kw + ((size_t)idx * Dd + d) * Dd;
    const float* swk = a.sw + (size_t)idx * 2 * Dd + Dd;
    float sA = 0.f;
    for (int j = lane; j < Dd; j += 64) sA += row[j] * swk[j];
    sA = wred(sA);
    if (lane == 0) a.kvecs[dot] = sA;
}

// ---- xdots body: wave-per-row over rows [r0, Bb*Ls) step rstep
__device__ void xdots_dev(const KArgs& a, int r0, int rstep, int lane) {
    float4 gs0[3], k1r[3], gs2[3], k3r[3];
#pragma unroll
    for (int k = 0; k < 3; ++k) {
        int d = (lane << 2) + k * 256;
        float4 ga = *(const float4*)(a.gw + d);
        float4 gbv = *(const float4*)(a.gw + 768 + d);
        gs0[k] = make_float4(ga.x+gbv.x, ga.y+gbv.y, ga.z+gbv.z, ga.w+gbv.w);
        k1r[k] = *(const float4*)(a.kvecs + 768 + d);
        float4 g2a = *(const float4*)(a.gw + 3072 + d);
        float4 g2b = *(const float4*)(a.gw + 3840 + d);
        gs2[k] = make_float4(g2a.x+g2b.x, g2a.y+g2b.y, g2a.z+g2b.z, g2a.w+g2b.w);
        k3r[k] = *(const float4*)(a.kvecs + 2304 + d);
    }
    for (int r = r0; r < Bb * Ls; r += rstep) {
        const float* xr = a.x0 + (size_t)r * Dd;
        float s0 = 0.f, s1 = 0.f, s2 = 0.f, s3 = 0.f;
#pragma unroll
        for (int k = 0; k < 3; ++k) {
            float4 xv = *(const float4*)(xr + (lane << 2) + k * 256);
            s0 += xv.x*gs0[k].x + xv.y*gs0[k].y + xv.z*gs0[k].z + xv.w*gs0[k].w;
            s1 += xv.x*k1r[k].x + xv.y*k1r[k].y + xv.z*k1r[k].z + xv.w*k1r[k].w;
            s2 += xv.x*gs2[k].x + xv.y*gs2[k].y + xv.z*gs2[k].z + xv.w*gs2[k].w;
            s3 += xv.x*k3r[k].x + xv.y*k3r[k].y + xv.z*k3r[k].z + xv.w*k3r[k].w;
        }
        s0 = wred(s0); s1 = wred(s1); s2 = wred(s2); s3 = wred(s3);
        if (lane == 0) {
            float4 o4 = make_float4(s0, s1, s2, s3);
            *(float4*)(a.xd + (size_t)r * 4) = o4;
        }
    }
}

// ---- pdots body
__device__ void pdots_dev(const KArgs& a, int g2, int lane) {
    for (int k = 0; k < 4; ++k) {
        int j = g2 + k * 128;
        if (k == 3) { if (g2 >= 4) break; j = 384 + g2; }
        if (j >= 388) continue;
        int vv = j / Cc, r = j - vv * Cc;
        const float* va; const float* vb2 = nullptr;
        if (vv == 0) va = a.kvecs;
        else if (vv == 1) va = a.kvecs + 2 * Dd;
        else if (vv == 2) { va = a.gw + 1536; vb2 = a.gw + 2304; }
        else { va = a.gw + 4608; vb2 = a.gw + 5376; }
        const float* row = a.p0b + (size_t)r * Dd;
        float sA = 0.f;
        for (int jj = lane; jj < Dd; jj += 64)
            sA += row[jj] * (va[jj] + (vb2 ? vb2[jj] : 0.f));
        sA = wred(sA);
        if (lane == 0) a.pdots[j] = sA;
    }
}

// ---- logits body
__device__ void logits_dev(const KArgs& a, int r, float* shr) {
    int t = threadIdx.x;
    int b = r / Cc, c = r - b * Cc;
    float g1 = a.g1buf[r];
    float g2 = sigm(2.f * a.pdots[291 + c] + g1 * a.sc[192 + b] + a.sc[288 + b] + a.gb[3]);
    float ssum = 0.f;
#pragma unroll
    for (int sseg = 0; sseg < 3; ++sseg) {
        int d = t + sseg * 256;
        float h = tanhf(4.f * a.pp[(size_t)c * Dd + d]
                      + 2.f * g1 * a.aw1[(size_t)b * Dd + d]
                      + g2 * a.aw2[(size_t)b * Dd + d]
                      + a.geb[(size_t)b * Dd + d]);
        ssum += h * a.fc2w[d];
    }
    float tt = blk_sum4(ssum, shr);
    if (t == 0) a.out[r] = sigm(tt + a.fc2b[0]);
}

// ================= kernels (11-launch pipeline + memset) =================
// K1: gemm1 split-K (192 blocks) || kvec dots (320 blocks)
__global__ __launch_bounds__(NTHR) void k_g1kv(KArgs a) {
    __shared__ float As[1024], Ws[1024];
    int blk = blockIdx.x, t = threadIdx.x;
    int wv_ = t >> 6, lane = t & 63;
    if (blk < 192) {
        sgemm_dev(a.emb, a.rel_w, a.rel_b, a.p0b, Cc, Dd, Dd, 96,
                  blk % 12, (blk / 12) % 2, blk / 24, As, Ws);
    } else {
        for (int dot = (blk - 192) * 4 + wv_; dot < 3072; dot += (NBLK - 192) * 4)
            kvec_dot(a, dot, lane);
    }
}

// K2: ppGEMM split-K (96) || pdots (32) || xdots (384)
__global__ __launch_bounds__(NTHR) void k_prep2(KArgs a) {
    __shared__ float As[1024], Ws[1024];
    int blk = blockIdx.x, t = threadIdx.x;
    int wv_ = t >> 6, lane = t & 63;
    if (blk < 96) {
        sgemm_dev(a.p0b, a.fc1w, nullptr, a.pp, Cc, Dd, Dd, 192,
                  blk % 12, (blk / 12) % 2, blk / 24, As, Ws);
    } else if (blk < 128) {
        pdots_dev(a, (blk - 96) * 4 + wv_, lane);
    } else {
        xdots_dev(a, (blk - 128) * 4 + wv_, (NBLK - 128) * 4, lane);
    }
}

// K3: attn phase 0
__global__ __launch_bounds__(NTHR) void k_attn0(KArgs a) {
    __shared__ float xs[96], lw[128], shr[16];
    attn_gemv(a, 0, blockIdx.x, xs, lw, shr);
}

// K4: passX0 (512) || coeff0 (32)
__global__ __launch_bounds__(NTHR) void k_p3(KArgs a) {
    __shared__ float smw[512], shr[16];
    int blk = blockIdx.x;
    if (blk < 512) passX_dev(a, 0, blk, a.S0, true, smw, shr);
    else coeff0_dev(a, blk - 512, shr);
}

// K5: mm0 -> av1
__global__ __launch_bounds__(NTHR) void k_mm0(KArgs a) {
    __shared__ float xs[96], shr[16];
    mm_dev(a, blockIdx.x, a.S0, 2.f, a.avx1, a.sc + 320, 1.f, nullptr, nullptr, 0.f,
           a.vw + (size_t)1 * Dd * Dd, a.vb + Dd, a.av1,
           3, a.gw + 1536, nullptr, a.kvecs + 2 * Dd, a.gw + 4608, a.gw + 5376,
           a.sc + 128, xs, shr);
}

// K6: attn phase 1 (768) || aw1 (768)
__global__ __launch_bounds__(NTHR) void k_p5(KArgs a) {
    __shared__ float xs[96], lw[128], shr[16];
    int blk = blockIdx.x;
    if (blk < 768) attn_gemv(a, 1, blk, xs, lw, shr);
    else aw_one(a, blk - 768, a.av1, a.aw1, xs);
}

// K7: passX1 (512) || coeff1 (32)
__global__ __launch_bounds__(NTHR) void k_p6(KArgs a) {
    __shared__ float smw[512], shr[16];
    int blk = blockIdx.x;
    if (blk < 512) passX_dev(a, 1, blk, a.S1, false, smw, shr);
    else coeff1_dev(a, blk - 512, shr);
}

// K8: mm1 (768) || ge (768)
__global__ __launch_bounds__(NTHR) void k_p7(KArgs a) {
    __shared__ float xs[96], xs2[96], shr[16];
    int blk = blockIdx.x;
    if (blk < 768)
        mm_dev(a, blk, a.S1, 4.f, a.avx1, a.sc + 352, 2.f, a.avx2, a.sc + 384, 1.f,
               a.vw + (size_t)3 * Dd * Dd, a.vb + 3 * Dd, a.av2,
               1, a.gw + 4608, nullptr, nullptr, nullptr, nullptr,
               a.sc + 288, xs, shr);
    else ge_dev(a, blk - 768, xs, xs2);
}

// K9: aw2
__global__ __launch_bounds__(NTHR) void k_aw2(KArgs a) {
    __shared__ float xs[96];
    aw_one(a, blockIdx.x, a.av2, a.aw2, xs);
}

// K10: logits
__global__ __launch_bounds__(NTHR) void k_logits(KArgs a) {
    __shared__ float shr[16];
    for (int r = blockIdx.x; r < Bb * Cc; r += NBLK) logits_dev(a, r, shr);
}

// K11: argmax
__global__ void k_argmax(KArgs a) {
    int t = threadIdx.x;
    if (t < Bb) {
        const float* row = a.out + (size_t)t * Cc;
        float best = row[0];
        int bi = 0;
        for (int c = 1; c < Cc; ++c) {
            float v = row[c];
            if (v > best) { best = v; bi = c; }
        }
        a.out[Bb * Cc + t] = (float)bi;
    }
}

extern "C" void kernel_launch(void* const* d_in, const int* in_sizes, int n_in,
                              void* d_out, int out_size, void* d_ws, size_t ws_size,
                              hipStream_t stream) {
    KArgs ka;
    ka.x0    = (const float*)d_in[0];
    ka.pos1  = (const float*)d_in[1];
    ka.pos2  = (const float*)d_in[2];
    ka.mask  = (const int*)d_in[3];
    ka.emb   = (const float*)d_in[4];
    ka.rel_w = (const float*)d_in[5];
    ka.rel_b = (const float*)d_in[6];
    // qw(7), qb(8) dead (softmax shift-invariance); kb(10), sb(14) dead (row-constant)
    ka.kw    = (const float*)d_in[9];
    ka.vw    = (const float*)d_in[11];
    ka.vb    = (const float*)d_in[12];
    ka.sw    = (const float*)d_in[13];
    ka.gw    = (const float*)d_in[15];
    ka.gb    = (const float*)d_in[16];
    ka.fc1w  = (const float*)d_in[17];
    ka.fc1b  = (const float*)d_in[18];
    ka.fc2w  = (const float*)d_in[19];
    ka.fc2b  = (const float*)d_in[20];
    ka.out   = (float*)d_out;

    float* ws = (float*)d_ws;
    size_t off = 0;
    const size_t PD = (size_t)Cc * Dd;
    const size_t BD = (size_t)Bb * Dd;
    // zeroed region (one memset): p0b, pp (split-K atomic targets) + accumulators
    ka.p0b  = ws + off; off += PD;
    ka.pp   = ws + off; off += PD;
    ka.sc   = ws + off; off += 640;
    ka.avx1 = ws + off; off += BD;
    ka.avx2 = ws + off; off += BD;
    ka.av1  = ws + off; off += BD;
    ka.av2  = ws + off; off += BD;
    ka.aw1  = ws + off; off += BD;
    ka.aw2  = ws + off; off += BD;
    ka.S0   = ws + off; off += BD;
    ka.S1   = ws + off; off += BD;
    ka.xp1  = ws + off; off += BD;
    ka.xp2  = ws + off; off += BD;
    ka.geb  = ws + off; off += BD;
    size_t zbytes = off * sizeof(float);
    // plain-store buffers (no zeroing needed)
    ka.kvecs = ws + off; off += (size_t)4 * Dd;
    ka.pdots = ws + off; off += 388;
    ka.g1buf = ws + off; off += (size_t)Bb * Cc;
    ka.xd    = ws + off; off += (size_t)Bb * Ls * 4;

    hipMemsetAsync((void*)ws, 0, zbytes, stream);
    k_g1kv<<<NBLK, NTHR, 0, stream>>>(ka);
    k_prep2<<<NBLK, NTHR, 0, stream>>>(ka);
    k_attn0<<<768, NTHR, 0, stream>>>(ka);
    k_p3<<<544, NTHR, 0, stream>>>(ka);
    k_mm0<<<768, NTHR, 0, stream>>>(ka);
    k_p5<<<1536, NTHR, 0, stream>>>(ka);
    k_p6<<<544, NTHR, 0, stream>>>(ka);
    k_p7<<<1536, NTHR, 0, stream>>>(ka);
    k_aw2<<<768, NTHR, 0, stream>>>(ka);
    k_logits<<<NBLK, NTHR, 0, stream>>>(ka);
    k_argmax<<<1, 64, 0, stream>>>(ka);
}

// Round 10
// 320.683 us; speedup vs baseline: 3.2063x; 1.0280x over previous
//
#include <hip/hip_runtime.h>
#include <math.h>

#define NBLK 512
#define NTHR 256
static const int Bb = 32, Ls = 512, Dd = 768, Cc = 97;

struct KArgs {
    const float *x0, *pos1, *pos2;
    const int* mask;
    const float *emb, *rel_w, *rel_b, *kw, *vw, *vb, *sw, *gw, *gb;
    const float *fc1w, *fc1b, *fc2w, *fc2b;
    float* out;
    float *p0b, *pp, *sc, *avx1, *avx2, *av1, *av2, *aw1, *aw2, *S0, *S1, *xp1, *xp2, *geb;
    float *kvecs, *pdots, *g1buf, *xd;
    float* zbase;
    int zcount;
};

__device__ __forceinline__ float sigm(float x) { return 1.f / (1.f + expf(-x)); }

__device__ __forceinline__ float wred(float v) {
#pragma unroll
    for (int o = 32; o > 0; o >>= 1) v += __shfl_down(v, o, 64);
    return v;
}

__device__ __forceinline__ float blk_sum4(float v, float* shr) {
    v = wred(v);
    int t = threadIdx.x;
    if ((t & 63) == 0) shr[t >> 6] = v;
    __syncthreads();
    float r = shr[0] + shr[1] + shr[2] + shr[3];
    __syncthreads();
    return r;
}

// ---- split-K SGEMM tile: C += A[:,kb:kb+KC]@W[kb:kb+KC,:] (+bias at bz==0); C pre-zeroed
__device__ void sgemm_dev(const float* __restrict__ A, const float* __restrict__ W,
                          const float* __restrict__ bias, float* __restrict__ C,
                          int M, int N, int K, int KC, int bx, int by, int bz,
                          float* As, float* Ws) {
    int tid = threadIdx.x;
    int tx = tid & 15, ty = tid >> 4;
    int bn = bx * 64, bm = by * 64;
    int kb = bz * KC;
    int arow = tid >> 2, akq = (tid & 3) << 2;
    int wrow = tid >> 4, wcol = (tid & 15) << 2;
    int gar = bm + arow;
    bool aval = gar < M;
    const float* Ap = A + (size_t)gar * K + kb + akq;
    const float* Wp = W + (size_t)(kb + wrow) * N + bn + wcol;
    float acc[4][4] = {{0.f}};
    float4 a4 = make_float4(0.f, 0.f, 0.f, 0.f);
    if (aval) a4 = *(const float4*)Ap;
    float4 w4 = *(const float4*)Wp;
    for (int k0 = 0; k0 < KC; k0 += 16) {
        __syncthreads();
        As[(akq + 0) * 64 + arow] = a4.x; As[(akq + 1) * 64 + arow] = a4.y;
        As[(akq + 2) * 64 + arow] = a4.z; As[(akq + 3) * 64 + arow] = a4.w;
        *(float4*)&Ws[wrow * 64 + wcol] = w4;
        __syncthreads();
        if (k0 + 16 < KC) {
            if (aval) a4 = *(const float4*)(Ap + k0 + 16);
            w4 = *(const float4*)(Wp + (size_t)(k0 + 16) * N);
        }
#pragma unroll
        for (int kk = 0; kk < 16; ++kk) {
            float4 a = *(const float4*)&As[kk * 64 + (ty << 2)];
            float4 b = *(const float4*)&Ws[kk * 64 + (tx << 2)];
            acc[0][0]+=a.x*b.x; acc[0][1]+=a.x*b.y; acc[0][2]+=a.x*b.z; acc[0][3]+=a.x*b.w;
            acc[1][0]+=a.y*b.x; acc[1][1]+=a.y*b.y; acc[1][2]+=a.y*b.z; acc[1][3]+=a.y*b.w;
            acc[2][0]+=a.z*b.x; acc[2][1]+=a.z*b.y; acc[2][2]+=a.z*b.z; acc[2][3]+=a.z*b.w;
            acc[3][0]+=a.w*b.x; acc[3][1]+=a.w*b.y; acc[3][2]+=a.w*b.z; acc[3][3]+=a.w*b.w;
        }
    }
    int gc = bn + (tx << 2);
    float4 bz4 = make_float4(0.f, 0.f, 0.f, 0.f);
    if (bz == 0 && bias) bz4 = *(const float4*)(bias + gc);
#pragma unroll
    for (int i = 0; i < 4; ++i) {
        int gr = bm + (ty << 2) + i;
        if (gr < M) {
            float* cp = C + (size_t)gr * N + gc;
            atomicAdd(cp + 0, acc[i][0] + bz4.x); atomicAdd(cp + 1, acc[i][1] + bz4.y);
            atomicAdd(cp + 2, acc[i][2] + bz4.z); atomicAdd(cp + 3, acc[i][3] + bz4.w);
        }
    }
}

// ---- recompute masked softmax-over-L weights for batch b (deterministic;
// identical math to the verified softgate kernel, re-derived per block).
__device__ void sm_w(const KArgs& a, int phase, int b, float* shr,
                     float& w0o, float& w1o, float& ga0, float& ga1,
                     float& gb0o, float& gb1o) {
    int t = threadIdx.x;
    float ks[2], ga[2], gb2[2] = {0.f, 0.f};
#pragma unroll
    for (int i = 0; i < 2; ++i) {
        int l = t + (i << 8);
        size_t r = (size_t)b * Ls + l;
        const float* px = a.xd + r * 4;
        float gp = sigm(px[0] + a.sc[b] + a.gb[0]);
        if (phase == 0) {
            ga[i] = gp;
            ks[i] = 2.f * px[1] + gp * a.sc[32 + b];
        } else {
            float g = sigm(2.f * px[2] + gp * a.sc[64 + b] + a.sc[224 + b] + a.gb[2]);
            ga[i] = gp; gb2[i] = g;
            ks[i] = 4.f * px[3] + 2.f * gp * a.sc[96 + b] + g * a.sc[256 + b];
        }
        if (a.mask[r] == 0) ks[i] = -1e9f;
    }
    float mx = fmaxf(ks[0], ks[1]);
#pragma unroll
    for (int o = 32; o > 0; o >>= 1) mx = fmaxf(mx, __shfl_down(mx, o, 64));
    if ((t & 63) == 0) shr[t >> 6] = mx;
    __syncthreads();
    mx = fmaxf(fmaxf(shr[0], shr[1]), fmaxf(shr[2], shr[3]));
    __syncthreads();
    float e0 = expf(ks[0] - mx), e1 = expf(ks[1] - mx);
    float s = blk_sum4(e0 + e1, shr);
    float inv = 1.f / s;
    w0o = e0 * inv; w1o = e1 * inv;
    ga0 = ga[0]; ga1 = ga[1];
    gb0o = gb2[0]; gb1o = gb2[1];
}

// ---- coeff0: ca0 = sum(w*g) -> sc[320+b]  (mm0 coefA)
__device__ void coeff0_dev(const KArgs& a, int b, float* shr) {
    float w0, w1, ga0, ga1, u0, u1;
    sm_w(a, 0, b, shr, w0, w1, ga0, ga1, u0, u1);
    float ca = blk_sum4(w0 * ga0 + w1 * ga1, shr);
    if (threadIdx.x == 0) a.sc[320 + b] = ca;
}

// ---- coeff1: ca1/cb1 (mm1 coefs) + pool coeffs c11..c22, 1/s1, 1/s2 (ge)
__device__ void coeff1_dev(const KArgs& a, int b, float* shr) {
    int t = threadIdx.x;
    float w0, w1, ga0, ga1, g0, g1;
    sm_w(a, 1, b, shr, w0, w1, ga0, ga1, g0, g1);
    float ca = blk_sum4(w0 * ga0 + w1 * ga1, shr);
    if (t == 0) a.sc[352 + b] = ca;
    float cb = blk_sum4(w0 * g0 + w1 * g1, shr);
    if (t == 0) a.sc[384 + b] = cb;
    float q1a = a.pos1[(size_t)b * Ls + t], q1b = a.pos1[(size_t)b * Ls + t + 256];
    float q2a = a.pos2[(size_t)b * Ls + t], q2b = a.pos2[(size_t)b * Ls + t + 256];
    float s1 = blk_sum4(q1a + q1b, shr);
    float s2 = blk_sum4(q2a + q2b, shr);
    float c11 = blk_sum4(q1a * ga0 + q1b * ga1, shr);
    float c12 = blk_sum4(q1a * g0 + q1b * g1, shr);
    float c21 = blk_sum4(q2a * ga0 + q2b * ga1, shr);
    float c22 = blk_sum4(q2a * g0 + q2b * g1, shr);
    if (t == 0) {
        a.sc[448 + b] = c11; a.sc[480 + b] = c12;
        a.sc[512 + b] = c21; a.sc[544 + b] = c22;
        a.sc[576 + b] = 1.f / s1; a.sc[608 + b] = 1.f / s2;
    }
}

// ---- fused relation-attention + V-GEMV bank; jlin in [0,768): jt%3, b, kseg/96
__device__ void attn_gemv(const KArgs& a, int phase, int jlin,
                          float* xs, float* lw, float* shr) {
    int t = threadIdx.x;
    int jt = jlin % 3, b = (jlin / 3) % 32, kseg = jlin / 96;
    float v = -3.0e38f, g1 = 0.f;
    if (t < Cc) {
        if (phase == 0) v = a.pdots[t];
        else {
            g1 = sigm(a.pdots[194 + t] + a.sc[128 + b] + a.gb[1]);
            v = 2.f * a.pdots[97 + t] + g1 * a.sc[160 + b];
        }
    }
    if (phase == 1 && jt == 0 && kseg == 0 && t < Cc) a.g1buf[(size_t)b * Cc + t] = g1;
    float m = v;
#pragma unroll
    for (int o = 32; o > 0; o >>= 1) m = fmaxf(m, __shfl_down(m, o, 64));
    if ((t & 63) == 0) shr[t >> 6] = m;
    __syncthreads();
    m = fmaxf(fmaxf(shr[0], shr[1]), fmaxf(shr[2], shr[3]));
    __syncthreads();
    float e = (t < Cc) ? expf(v - m) : 0.f;
    float s = blk_sum4(e, shr);
    float wc = e / s;
    if (t < Cc) lw[t] = wc;
    float cg1 = blk_sum4(wc * g1, shr);   // publishes lw
    float alpha = (phase == 0) ? 1.f : 2.f;
    if (t < 96) {
        int d = kseg * 96 + t;
        const float* pc = a.p0b + d;
        float acc2 = 0.f;
#pragma unroll 4
        for (int c = 0; c < Cc; ++c) acc2 += lw[c] * pc[(size_t)c * Dd];
        float val = alpha * acc2;
        if (phase == 1) val += cg1 * a.av1[(size_t)b * Dd + d];
        xs[t] = val;
    }
    __syncthreads();
    const float* W = a.vw + (size_t)(phase == 0 ? 0 : 2) * Dd * Dd;
    const float* bias = a.vb + (phase == 0 ? 0 : 2) * Dd;
    float* outp = (phase == 0) ? a.avx1 : a.avx2;
    int j = jt * 256 + t;
    float acc = (kseg == 0) ? bias[j] : 0.f;
    const float* wp = W + (size_t)(kseg * 96) * Dd + j;
#pragma unroll 8
    for (int dd = 0; dd < 96; ++dd) acc += xs[dd] * wp[(size_t)dd * Dd];
    atomicAdd(&outp[(size_t)b * Dd + j], acc);
    const float* da[4]; const float* db[4]; int nd; float* dout;
    if (phase == 0) {
        da[0]=a.gw;          db[0]=nullptr;
        da[1]=a.kvecs+Dd;    db[1]=nullptr;
        da[2]=a.gw+3072;     db[2]=a.gw+3840;
        da[3]=a.kvecs+3*Dd;  db[3]=nullptr;
        nd = 4; dout = a.sc;
    } else {
        da[0]=a.gw+3072;     db[0]=nullptr;
        da[1]=a.kvecs+3*Dd;  db[1]=nullptr;
        nd = 2; dout = a.sc + 224;
    }
    for (int vv = 0; vv < nd; ++vv) {
        float wv = da[vv][j] + (db[vv] ? db[vv][j] : 0.f);
        float p = blk_sum4(acc * wv, shr);
        if (t == 0) atomicAdd(&dout[vv * 32 + b], p);
    }
    __syncthreads();
}

// ---- GEMV bank: out[b,:] += xs@Wseg
__device__ void mm_dev(const KArgs& a, int jlin, const float* S, float gamma,
                       const float* avA, const float* coefA, float multA,
                       const float* avB, const float* coefB, float multB,
                       const float* W, const float* bias, float* outp,
                       int ndots, const float* d0a, const float* d0b,
                       const float* d1a, const float* d2a, const float* d2b,
                       float* dout, float* xs, float* shr) {
    int t = threadIdx.x;
    int jt = jlin % 3, b = (jlin / 3) % 32, kseg = jlin / 96;
    if (t < 96) {
        int d = kseg * 96 + t;
        float v = gamma * S[(size_t)b * Dd + d];
        if (avA) v += multA * coefA[b] * avA[(size_t)b * Dd + d];
        if (avB) v += multB * coefB[b] * avB[(size_t)b * Dd + d];
        xs[t] = v;
    }
    __syncthreads();
    int j = jt * 256 + t;
    float acc = (kseg == 0 && bias) ? bias[j] : 0.f;
    const float* wp = W + (size_t)(kseg * 96) * Dd + j;
#pragma unroll 8
    for (int dd = 0; dd < 96; ++dd) acc += xs[dd] * wp[(size_t)dd * Dd];
    atomicAdd(&outp[(size_t)b * Dd + j], acc);
    if (ndots > 0) {
        float wv = d0a[j] + (d0b ? d0b[j] : 0.f);
        float p = blk_sum4(acc * wv, shr);
        if (t == 0) atomicAdd(&dout[b], p);
    }
    if (ndots > 1) {
        float p = blk_sum4(acc * d1a[j], shr);
        if (t == 0) atomicAdd(&dout[32 + b], p);
    }
    if (ndots > 2) {
        float wv = d2a[j] + (d2b ? d2b[j] : 0.f);
        float p = blk_sum4(acc * wv, shr);
        if (t == 0) atomicAdd(&dout[64 + b], p);
    }
}

// ---- ge bank: geb[b,:] += e1@W1seg + e2@W2seg (+fc1b at kseg 0)
__device__ void ge_dev(const KArgs& a, int jlin, float* xs, float* xs2) {
    int t = threadIdx.x;
    int jt = jlin % 3, b = (jlin / 3) % 32, kseg = jlin / 96;
    if (t < 96) {
        int d = kseg * 96 + t;
        float a1 = a.avx1[(size_t)b * Dd + d], a2 = a.avx2[(size_t)b * Dd + d];
        xs[t]  = (4.f * a.xp1[(size_t)b * Dd + d] + 2.f * a.sc[448 + b] * a1
                  + a.sc[480 + b] * a2) * a.sc[576 + b];
        xs2[t] = (4.f * a.xp2[(size_t)b * Dd + d] + 2.f * a.sc[512 + b] * a1
                  + a.sc[544 + b] * a2) * a.sc[608 + b];
    }
    __syncthreads();
    int j = jt * 256 + t;
    float a1 = 0.f, a2 = 0.f;
    const float* w1 = a.fc1w + (size_t)(Dd + kseg * 96) * Dd + j;
    const float* w2 = a.fc1w + (size_t)(2 * Dd + kseg * 96) * Dd + j;
#pragma unroll 8
    for (int dd = 0; dd < 96; ++dd) {
        a1 += xs[dd] * w1[(size_t)dd * Dd];
        a2 += xs2[dd] * w2[(size_t)dd * Dd];
    }
    float res = a1 + a2 + (kseg == 0 ? a.fc1b[j] : 0.f);
    atomicAdd(&a.geb[(size_t)b * Dd + j], res);
}

// ---- single bank: outp[b,:] += av[b,:]@fc1w0seg
__device__ void aw_one(const KArgs& a, int jlin, const float* av, float* outp, float* xs) {
    int t = threadIdx.x;
    int jt = jlin % 3, b = (jlin / 3) % 32, kseg = jlin / 96;
    if (t < 96) xs[t] = av[(size_t)b * Dd + kseg * 96 + t];
    __syncthreads();
    int j = jt * 256 + t;
    float acc = 0.f;
    const float* wp = a.fc1w + (size_t)(kseg * 96) * Dd + j;
#pragma unroll 8
    for (int dd = 0; dd < 96; ++dd) acc += xs[dd] * wp[(size_t)dd * Dd];
    atomicAdd(&outp[(size_t)b * Dd + j], acc);
}

// ---- passX: recompute softmax weights in-block, then weighted x0 sums
__device__ void passX_dev(const KArgs& a, int phase, int blk, float* S, bool dopos,
                          float* smw, float* shr) {
    int t = threadIdx.x;
    int b = blk >> 4, seg = blk & 15, l0 = seg * 32;
    {
        float w0, w1, u0, u1, u2, u3;
        sm_w(a, phase, b, shr, w0, w1, u0, u1, u2, u3);
        smw[t] = w0; smw[t + 256] = w1;
    }
    __syncthreads();
    if (t < 192) {
        int d4 = t << 2;
        const float* xb = a.x0 + ((size_t)b * Ls + l0) * Dd + d4;
        float4 as = make_float4(0.f,0.f,0.f,0.f);
        float4 a1 = make_float4(0.f,0.f,0.f,0.f);
        float4 a2 = make_float4(0.f,0.f,0.f,0.f);
        for (int l = 0; l < 32; ++l) {
            float4 xv = *(const float4*)(xb + (size_t)l * Dd);
            float wv = smw[l0 + l];
            as.x += wv*xv.x; as.y += wv*xv.y; as.z += wv*xv.z; as.w += wv*xv.w;
            if (dopos) {
                float q1 = a.pos1[(size_t)b * Ls + l0 + l], q2 = a.pos2[(size_t)b * Ls + l0 + l];
                a1.x += q1*xv.x; a1.y += q1*xv.y; a1.z += q1*xv.z; a1.w += q1*xv.w;
                a2.x += q2*xv.x; a2.y += q2*xv.y; a2.z += q2*xv.z; a2.w += q2*xv.w;
            }
        }
        float* ds = S + (size_t)b * Dd + d4;
        atomicAdd(ds+0, as.x); atomicAdd(ds+1, as.y); atomicAdd(ds+2, as.z); atomicAdd(ds+3, as.w);
        if (dopos) {
            float* d1 = a.xp1 + (size_t)b * Dd + d4;
            float* d2 = a.xp2 + (size_t)b * Dd + d4;
            atomicAdd(d1+0, a1.x); atomicAdd(d1+1, a1.y); atomicAdd(d1+2, a1.z); atomicAdd(d1+3, a1.w);
            atomicAdd(d2+0, a2.x); atomicAdd(d2+1, a2.y); atomicAdd(d2+2, a2.z); atomicAdd(d2+3, a2.w);
        }
    }
}

// ---- kvec dots body
__device__ void kvec_dot(const KArgs& a, int dot, int lane) {
    int idx = dot / Dd, d = dot - idx * Dd;
    const float* row = a.kw + ((size_t)idx * Dd + d) * Dd;
    const float* swk = a.sw + (size_t)idx * 2 * Dd + Dd;
    float sA = 0.f;
    for (int j = lane; j < Dd; j += 64) sA += row[j] * swk[j];
    sA = wred(sA);
    if (lane == 0) a.kvecs[dot] = sA;
}

// ---- xdots body: wave-per-row over rows [r0, Bb*Ls) step rstep
__device__ void xdots_dev(const KArgs& a, int r0, int rstep, int lane) {
    float4 gs0[3], k1r[3], gs2[3], k3r[3];
#pragma unroll
    for (int k = 0; k < 3; ++k) {
        int d = (lane << 2) + k * 256;
        float4 ga = *(const float4*)(a.gw + d);
        float4 gbv = *(const float4*)(a.gw + 768 + d);
        gs0[k] = make_float4(ga.x+gbv.x, ga.y+gbv.y, ga.z+gbv.z, ga.w+gbv.w);
        k1r[k] = *(const float4*)(a.kvecs + 768 + d);
        float4 g2a = *(const float4*)(a.gw + 3072 + d);
        float4 g2b = *(const float4*)(a.gw + 3840 + d);
        gs2[k] = make_float4(g2a.x+g2b.x, g2a.y+g2b.y, g2a.z+g2b.z, g2a.w+g2b.w);
        k3r[k] = *(const float4*)(a.kvecs + 2304 + d);
    }
    for (int r = r0; r < Bb * Ls; r += rstep) {
        const float* xr = a.x0 + (size_t)r * Dd;
        float s0 = 0.f, s1 = 0.f, s2 = 0.f, s3 = 0.f;
#pragma unroll
        for (int k = 0; k < 3; ++k) {
            float4 xv = *(const float4*)(xr + (lane << 2) + k * 256);
            s0 += xv.x*gs0[k].x + xv.y*gs0[k].y + xv.z*gs0[k].z + xv.w*gs0[k].w;
            s1 += xv.x*k1r[k].x + xv.y*k1r[k].y + xv.z*k1r[k].z + xv.w*k1r[k].w;
            s2 += xv.x*gs2[k].x + xv.y*gs2[k].y + xv.z*gs2[k].z + xv.w*gs2[k].w;
            s3 += xv.x*k3r[k].x + xv.y*k3r[k].y + xv.z*k3r[k].z + xv.w*k3r[k].w;
        }
        s0 = wred(s0); s1 = wred(s1); s2 = wred(s2); s3 = wred(s3);
        if (lane == 0) {
            float4 o4 = make_float4(s0, s1, s2, s3);
            *(float4*)(a.xd + (size_t)r * 4) = o4;
        }
    }
}

// ---- pdots body
__device__ void pdots_dev(const KArgs& a, int g2, int lane) {
    for (int k = 0; k < 4; ++k) {
        int j = g2 + k * 128;
        if (k == 3) { if (g2 >= 4) break; j = 384 + g2; }
        if (j >= 388) continue;
        int vv = j / Cc, r = j - vv * Cc;
        const float* va; const float* vb2 = nullptr;
        if (vv == 0) va = a.kvecs;
        else if (vv == 1) va = a.kvecs + 2 * Dd;
        else if (vv == 2) { va = a.gw + 1536; vb2 = a.gw + 2304; }
        else { va = a.gw + 4608; vb2 = a.gw + 5376; }
        const float* row = a.p0b + (size_t)r * Dd;
        float sA = 0.f;
        for (int jj = lane; jj < Dd; jj += 64)
            sA += row[jj] * (va[jj] + (vb2 ? vb2[jj] : 0.f));
        sA = wred(sA);
        if (lane == 0) a.pdots[j] = sA;
    }
}

// ---- logits body
__device__ void logits_dev(const KArgs& a, int r, float* shr) {
    int t = threadIdx.x;
    int b = r / Cc, c = r - b * Cc;
    float g1 = a.g1buf[r];
    float g2 = sigm(2.f * a.pdots[291 + c] + g1 * a.sc[192 + b] + a.sc[288 + b] + a.gb[3]);
    float ssum = 0.f;
#pragma unroll
    for (int sseg = 0; sseg < 3; ++sseg) {
        int d = t + sseg * 256;
        float h = tanhf(4.f * a.pp[(size_t)c * Dd + d]
                      + 2.f * g1 * a.aw1[(size_t)b * Dd + d]
                      + g2 * a.aw2[(size_t)b * Dd + d]
                      + a.geb[(size_t)b * Dd + d]);
        ssum += h * a.fc2w[d];
    }
    float tt = blk_sum4(ssum, shr);
    if (t == 0) a.out[r] = sigm(tt + a.fc2b[0]);
}

// ================= kernels (11-launch pipeline + small memset) =================
// K1: gemm1 split-K (192) || kvec dots + zero accumulators (320)
__global__ __launch_bounds__(NTHR) void k_g1kv(KArgs a) {
    __shared__ float As[1024], Ws[1024];
    int blk = blockIdx.x, t = threadIdx.x;
    int wv_ = t >> 6, lane = t & 63;
    if (blk < 192) {
        sgemm_dev(a.emb, a.rel_w, a.rel_b, a.p0b, Cc, Dd, Dd, 96,
                  blk % 12, (blk / 12) % 2, blk / 24, As, Ws);
    } else {
        for (size_t i = (size_t)(blk - 192) * NTHR + t; i < (size_t)a.zcount;
             i += (size_t)(NBLK - 192) * NTHR)
            a.zbase[i] = 0.f;
        for (int dot = (blk - 192) * 4 + wv_; dot < 3072; dot += (NBLK - 192) * 4)
            kvec_dot(a, dot, lane);
    }
}

// K2: ppGEMM split-K (96) || pdots (32)
__global__ __launch_bounds__(NTHR) void k_prep2(KArgs a) {
    __shared__ float As[1024], Ws[1024];
    int blk = blockIdx.x, t = threadIdx.x;
    int wv_ = t >> 6, lane = t & 63;
    if (blk < 96) {
        sgemm_dev(a.p0b, a.fc1w, nullptr, a.pp, Cc, Dd, Dd, 192,
                  blk % 12, (blk / 12) % 2, blk / 24, As, Ws);
    } else {
        pdots_dev(a, (blk - 96) * 4 + wv_, lane);
    }
}

// K3: attn phase 0 (768) || xdots (384) — independent, co-scheduled
__global__ __launch_bounds__(NTHR) void k_attn0x(KArgs a) {
    __shared__ float xs[96], lw[128], shr[16];
    int blk = blockIdx.x, t = threadIdx.x;
    int wv_ = t >> 6, lane = t & 63;
    if (blk < 768) attn_gemv(a, 0, blk, xs, lw, shr);
    else xdots_dev(a, (blk - 768) * 4 + wv_, 384 * 4, lane);
}

// K4: passX0 (512) || coeff0 (32)
__global__ __launch_bounds__(NTHR) void k_p3(KArgs a) {
    __shared__ float smw[512], shr[16];
    int blk = blockIdx.x;
    if (blk < 512) passX_dev(a, 0, blk, a.S0, true, smw, shr);
    else coeff0_dev(a, blk - 512, shr);
}

// K5: mm0 -> av1
__global__ __launch_bounds__(NTHR) void k_mm0(KArgs a) {
    __shared__ float xs[96], shr[16];
    mm_dev(a, blockIdx.x, a.S0, 2.f, a.avx1, a.sc + 320, 1.f, nullptr, nullptr, 0.f,
           a.vw + (size_t)1 * Dd * Dd, a.vb + Dd, a.av1,
           3, a.gw + 1536, nullptr, a.kvecs + 2 * Dd, a.gw + 4608, a.gw + 5376,
           a.sc + 128, xs, shr);
}

// K6: attn phase 1 (768) || aw1 (768)
__global__ __launch_bounds__(NTHR) void k_p5(KArgs a) {
    __shared__ float xs[96], lw[128], shr[16];
    int blk = blockIdx.x;
    if (blk < 768) attn_gemv(a, 1, blk, xs, lw, shr);
    else aw_one(a, blk - 768, a.av1, a.aw1, xs);
}

// K7: passX1 (512) || coeff1 (32)
__global__ __launch_bounds__(NTHR) void k_p6(KArgs a) {
    __shared__ float smw[512], shr[16];
    int blk = blockIdx.x;
    if (blk < 512) passX_dev(a, 1, blk, a.S1, false, smw, shr);
    else coeff1_dev(a, blk - 512, shr);
}

// K8: mm1 (768) || ge (768)
__global__ __launch_bounds__(NTHR) void k_p7(KArgs a) {
    __shared__ float xs[96], xs2[96], shr[16];
    int blk = blockIdx.x;
    if (blk < 768)
        mm_dev(a, blk, a.S1, 4.f, a.avx1, a.sc + 352, 2.f, a.avx2, a.sc + 384, 1.f,
               a.vw + (size_t)3 * Dd * Dd, a.vb + 3 * Dd, a.av2,
               1, a.gw + 4608, nullptr, nullptr, nullptr, nullptr,
               a.sc + 288, xs, shr);
    else ge_dev(a, blk - 768, xs, xs2);
}

// K9: aw2
__global__ __launch_bounds__(NTHR) void k_aw2(KArgs a) {
    __shared__ float xs[96];
    aw_one(a, blockIdx.x, a.av2, a.aw2, xs);
}

// K10: logits — one row per block (3104 blocks)
__global__ __launch_bounds__(NTHR) void k_logits(KArgs a) {
    __shared__ float shr[16];
    logits_dev(a, blockIdx.x, shr);
}

// K11: argmax
__global__ void k_argmax(KArgs a) {
    int t = threadIdx.x;
    if (t < Bb) {
        const float* row = a.out + (size_t)t * Cc;
        float best = row[0];
        int bi = 0;
        for (int c = 1; c < Cc; ++c) {
            float v = row[c];
            if (v > best) { best = v; bi = c; }
        }
        a.out[Bb * Cc + t] = (float)bi;
    }
}

extern "C" void kernel_launch(void* const* d_in, const int* in_sizes, int n_in,
                              void* d_out, int out_size, void* d_ws, size_t ws_size,
                              hipStream_t stream) {
    KArgs ka;
    ka.x0    = (const float*)d_in[0];
    ka.pos1  = (const float*)d_in[1];
    ka.pos2  = (const float*)d_in[2];
    ka.mask  = (const int*)d_in[3];
    ka.emb   = (const float*)d_in[4];
    ka.rel_w = (const float*)d_in[5];
    ka.rel_b = (const float*)d_in[6];
    // qw(7), qb(8) dead (softmax shift-invariance); kb(10), sb(14) dead (row-constant)
    ka.kw    = (const float*)d_in[9];
    ka.vw    = (const float*)d_in[11];
    ka.vb    = (const float*)d_in[12];
    ka.sw    = (const float*)d_in[13];
    ka.gw    = (const float*)d_in[15];
    ka.gb    = (const float*)d_in[16];
    ka.fc1w  = (const float*)d_in[17];
    ka.fc1b  = (const float*)d_in[18];
    ka.fc2w  = (const float*)d_in[19];
    ka.fc2b  = (const float*)d_in[20];
    ka.out   = (float*)d_out;

    float* ws = (float*)d_ws;
    size_t off = 0;
    const size_t PD = (size_t)Cc * Dd;
    const size_t BD = (size_t)Bb * Dd;
    // memset'd region (K1/K2 atomic targets, needed before K1): p0b, pp
    ka.p0b  = ws + off; off += PD;
    ka.pp   = ws + off; off += PD;
    size_t zbytes = off * sizeof(float);
    // zeroed in K1's kvec-blocks (first consumed in K3): sc .. geb
    size_t zstart = off;
    ka.sc   = ws + off; off += 640;
    ka.avx1 = ws + off; off += BD;
    ka.avx2 = ws + off; off += BD;
    ka.av1  = ws + off; off += BD;
    ka.av2  = ws + off; off += BD;
    ka.aw1  = ws + off; off += BD;
    ka.aw2  = ws + off; off += BD;
    ka.S0   = ws + off; off += BD;
    ka.S1   = ws + off; off += BD;
    ka.xp1  = ws + off; off += BD;
    ka.xp2  = ws + off; off += BD;
    ka.geb  = ws + off; off += BD;
    ka.zbase = ws + zstart;
    ka.zcount = (int)(off - zstart);
    // plain-store buffers (no zeroing needed)
    ka.kvecs = ws + off; off += (size_t)4 * Dd;
    ka.pdots = ws + off; off += 388;
    ka.g1buf = ws + off; off += (size_t)Bb * Cc;
    ka.xd    = ws + off; off += (size_t)Bb * Ls * 4;

    hipMemsetAsync((void*)ws, 0, zbytes, stream);
    k_g1kv<<<NBLK, NTHR, 0, stream>>>(ka);
    k_prep2<<<128, NTHR, 0, stream>>>(ka);
    k_attn0x<<<1152, NTHR, 0, stream>>>(ka);
    k_p3<<<544, NTHR, 0, stream>>>(ka);
    k_mm0<<<768, NTHR, 0, stream>>>(ka);
    k_p5<<<1536, NTHR, 0, stream>>>(ka);
    k_p6<<<544, NTHR, 0, stream>>>(ka);
    k_p7<<<1536, NTHR, 0, stream>>>(ka);
    k_aw2<<<768, NTHR, 0, stream>>>(ka);
    k_logits<<<Bb * Cc, NTHR, 0, stream>>>(ka);
    k_argmax<<<1, 64, 0, stream>>>(ka);
}

// Round 11
// 316.569 us; speedup vs baseline: 3.2480x; 1.0130x over previous
//
#include <hip/hip_runtime.h>
#include <math.h>

#define NBLK 512
#define NTHR 256
static const int Bb = 32, Ls = 512, Dd = 768, Cc = 97;

struct KArgs {
    const float *x0, *pos1, *pos2;
    const int* mask;
    const float *emb, *rel_w, *rel_b, *kw, *vw, *vb, *sw, *gw, *gb;
    const float *fc1w, *fc1b, *fc2w, *fc2b;
    float* out;
    float *p0b, *pp, *sc, *avx1v, *avx2, *av1, *av2, *aw1, *aw2, *S0, *S1, *xp1, *xp2, *geb;
    float *kvecs, *pdots, *g1buf, *xd;
    float* zbase;
    int zcount;
};

__device__ __forceinline__ float sigm(float x) { return 1.f / (1.f + expf(-x)); }

__device__ __forceinline__ float wred(float v) {
#pragma unroll
    for (int o = 32; o > 0; o >>= 1) v += __shfl_down(v, o, 64);
    return v;
}

__device__ __forceinline__ float blk_sum4(float v, float* shr) {
    v = wred(v);
    int t = threadIdx.x;
    if ((t & 63) == 0) shr[t >> 6] = v;
    __syncthreads();
    float r = shr[0] + shr[1] + shr[2] + shr[3];
    __syncthreads();
    return r;
}

// ---- split-K SGEMM tile: C += A[:,kb:kb+KC]@W[kb:kb+KC,:] (+bias at bz==0); C pre-zeroed
__device__ void sgemm_dev(const float* __restrict__ A, const float* __restrict__ W,
                          const float* __restrict__ bias, float* __restrict__ C,
                          int M, int N, int K, int KC, int bx, int by, int bz,
                          float* As, float* Ws) {
    int tid = threadIdx.x;
    int tx = tid & 15, ty = tid >> 4;
    int bn = bx * 64, bm = by * 64;
    int kb = bz * KC;
    int arow = tid >> 2, akq = (tid & 3) << 2;
    int wrow = tid >> 4, wcol = (tid & 15) << 2;
    int gar = bm + arow;
    bool aval = gar < M;
    const float* Ap = A + (size_t)gar * K + kb + akq;
    const float* Wp = W + (size_t)(kb + wrow) * N + bn + wcol;
    float acc[4][4] = {{0.f}};
    float4 a4 = make_float4(0.f, 0.f, 0.f, 0.f);
    if (aval) a4 = *(const float4*)Ap;
    float4 w4 = *(const float4*)Wp;
    for (int k0 = 0; k0 < KC; k0 += 16) {
        __syncthreads();
        As[(akq + 0) * 64 + arow] = a4.x; As[(akq + 1) * 64 + arow] = a4.y;
        As[(akq + 2) * 64 + arow] = a4.z; As[(akq + 3) * 64 + arow] = a4.w;
        *(float4*)&Ws[wrow * 64 + wcol] = w4;
        __syncthreads();
        if (k0 + 16 < KC) {
            if (aval) a4 = *(const float4*)(Ap + k0 + 16);
            w4 = *(const float4*)(Wp + (size_t)(k0 + 16) * N);
        }
#pragma unroll
        for (int kk = 0; kk < 16; ++kk) {
            float4 a = *(const float4*)&As[kk * 64 + (ty << 2)];
            float4 b = *(const float4*)&Ws[kk * 64 + (tx << 2)];
            acc[0][0]+=a.x*b.x; acc[0][1]+=a.x*b.y; acc[0][2]+=a.x*b.z; acc[0][3]+=a.x*b.w;
            acc[1][0]+=a.y*b.x; acc[1][1]+=a.y*b.y; acc[1][2]+=a.y*b.z; acc[1][3]+=a.y*b.w;
            acc[2][0]+=a.z*b.x; acc[2][1]+=a.z*b.y; acc[2][2]+=a.z*b.z; acc[2][3]+=a.z*b.w;
            acc[3][0]+=a.w*b.x; acc[3][1]+=a.w*b.y; acc[3][2]+=a.w*b.z; acc[3][3]+=a.w*b.w;
        }
    }
    int gc = bn + (tx << 2);
    float4 bz4 = make_float4(0.f, 0.f, 0.f, 0.f);
    if (bz == 0 && bias) bz4 = *(const float4*)(bias + gc);
#pragma unroll
    for (int i = 0; i < 4; ++i) {
        int gr = bm + (ty << 2) + i;
        if (gr < M) {
            float* cp = C + (size_t)gr * N + gc;
            atomicAdd(cp + 0, acc[i][0] + bz4.x); atomicAdd(cp + 1, acc[i][1] + bz4.y);
            atomicAdd(cp + 2, acc[i][2] + bz4.z); atomicAdd(cp + 3, acc[i][3] + bz4.w);
        }
    }
}

// ---- recompute masked softmax-over-L weights for batch b (deterministic)
__device__ void sm_w(const KArgs& a, int phase, int b, float* shr,
                     float& w0o, float& w1o, float& ga0, float& ga1,
                     float& gb0o, float& gb1o) {
    int t = threadIdx.x;
    float ks[2], ga[2], gb2[2] = {0.f, 0.f};
#pragma unroll
    for (int i = 0; i < 2; ++i) {
        int l = t + (i << 8);
        size_t r = (size_t)b * Ls + l;
        const float* px = a.xd + r * 4;
        float gp = sigm(px[0] + a.sc[b] + a.gb[0]);
        if (phase == 0) {
            ga[i] = gp;
            ks[i] = 2.f * px[1] + gp * a.sc[32 + b];
        } else {
            float g = sigm(2.f * px[2] + gp * a.sc[64 + b] + a.sc[224 + b] + a.gb[2]);
            ga[i] = gp; gb2[i] = g;
            ks[i] = 4.f * px[3] + 2.f * gp * a.sc[96 + b] + g * a.sc[256 + b];
        }
        if (a.mask[r] == 0) ks[i] = -1e9f;
    }
    float mx = fmaxf(ks[0], ks[1]);
#pragma unroll
    for (int o = 32; o > 0; o >>= 1) mx = fmaxf(mx, __shfl_down(mx, o, 64));
    if ((t & 63) == 0) shr[t >> 6] = mx;
    __syncthreads();
    mx = fmaxf(fmaxf(shr[0], shr[1]), fmaxf(shr[2], shr[3]));
    __syncthreads();
    float e0 = expf(ks[0] - mx), e1 = expf(ks[1] - mx);
    float s = blk_sum4(e0 + e1, shr);
    float inv = 1.f / s;
    w0o = e0 * inv; w1o = e1 * inv;
    ga0 = ga[0]; ga1 = ga[1];
    gb0o = gb2[0]; gb1o = gb2[1];
}

// ---- coeff0: ca0 = sum(w*g) -> sc[320+b]  (mm0 coefA)
__device__ void coeff0_dev(const KArgs& a, int b, float* shr) {
    float w0, w1, ga0, ga1, u0, u1;
    sm_w(a, 0, b, shr, w0, w1, ga0, ga1, u0, u1);
    float ca = blk_sum4(w0 * ga0 + w1 * ga1, shr);
    if (threadIdx.x == 0) a.sc[320 + b] = ca;
}

// ---- coeff1: ca1/cb1 (mm1 coefs) + pool coeffs c11..c22, 1/s1, 1/s2 (ge)
__device__ void coeff1_dev(const KArgs& a, int b, float* shr) {
    int t = threadIdx.x;
    float w0, w1, ga0, ga1, g0, g1;
    sm_w(a, 1, b, shr, w0, w1, ga0, ga1, g0, g1);
    float ca = blk_sum4(w0 * ga0 + w1 * ga1, shr);
    if (t == 0) a.sc[352 + b] = ca;
    float cb = blk_sum4(w0 * g0 + w1 * g1, shr);
    if (t == 0) a.sc[384 + b] = cb;
    float q1a = a.pos1[(size_t)b * Ls + t], q1b = a.pos1[(size_t)b * Ls + t + 256];
    float q2a = a.pos2[(size_t)b * Ls + t], q2b = a.pos2[(size_t)b * Ls + t + 256];
    float s1 = blk_sum4(q1a + q1b, shr);
    float s2 = blk_sum4(q2a + q2b, shr);
    float c11 = blk_sum4(q1a * ga0 + q1b * ga1, shr);
    float c12 = blk_sum4(q1a * g0 + q1b * g1, shr);
    float c21 = blk_sum4(q2a * ga0 + q2b * ga1, shr);
    float c22 = blk_sum4(q2a * g0 + q2b * g1, shr);
    if (t == 0) {
        a.sc[448 + b] = c11; a.sc[480 + b] = c12;
        a.sc[512 + b] = c21; a.sc[544 + b] = c22;
        a.sc[576 + b] = 1.f / s1; a.sc[608 + b] = 1.f / s2;
    }
}

// ---- phase-0 relation-attention: batch-independent. jlin in [0,24): jt%3, kseg/3.
// Writes avx1v[768] (single shared row) + broadcasts 4 scalar dots to sc[vv*32+0..31].
__device__ void attn0_gemv(const KArgs& a, int jlin, float* xs, float* lw, float* shr) {
    int t = threadIdx.x;
    int jt = jlin % 3, kseg = jlin / 3;
    float v = (t < Cc) ? a.pdots[t] : -3.0e38f;
    float m = v;
#pragma unroll
    for (int o = 32; o > 0; o >>= 1) m = fmaxf(m, __shfl_down(m, o, 64));
    if ((t & 63) == 0) shr[t >> 6] = m;
    __syncthreads();
    m = fmaxf(fmaxf(shr[0], shr[1]), fmaxf(shr[2], shr[3]));
    __syncthreads();
    float e = (t < Cc) ? expf(v - m) : 0.f;
    float s = blk_sum4(e, shr);
    if (t < Cc) lw[t] = e / s;
    __syncthreads();
    if (t < 96) {
        int d = kseg * 96 + t;
        const float* pc = a.p0b + d;
        float acc2 = 0.f;
#pragma unroll 4
        for (int c = 0; c < Cc; ++c) acc2 += lw[c] * pc[(size_t)c * Dd];
        xs[t] = acc2;                       // alpha = 1
    }
    __syncthreads();
    int j = jt * 256 + t;
    float acc = (kseg == 0) ? a.vb[j] : 0.f;
    const float* wp = a.vw + (size_t)(kseg * 96) * Dd + j;
#pragma unroll 8
    for (int dd = 0; dd < 96; ++dd) acc += xs[dd] * wp[(size_t)dd * Dd];
    atomicAdd(&a.avx1v[j], acc);
    const float* da[4]; const float* db[4];
    da[0]=a.gw;          db[0]=nullptr;
    da[1]=a.kvecs+Dd;    db[1]=nullptr;
    da[2]=a.gw+3072;     db[2]=a.gw+3840;
    da[3]=a.kvecs+3*Dd;  db[3]=nullptr;
    for (int vv = 0; vv < 4; ++vv) {
        float wv = da[vv][j] + (db[vv] ? db[vv][j] : 0.f);
        float p = blk_sum4(acc * wv, shr);
        if (t < 32) atomicAdd(&a.sc[vv * 32 + t], p);   // broadcast to all b slots
    }
    __syncthreads();
}

// ---- phase-1 relation-attention + V-GEMV bank; jlin in [0,768): jt%3, b, kseg/96
__device__ void attn1_gemv(const KArgs& a, int jlin, float* xs, float* lw, float* shr) {
    int t = threadIdx.x;
    int jt = jlin % 3, b = (jlin / 3) % 32, kseg = jlin / 96;
    float v = -3.0e38f, g1 = 0.f;
    if (t < Cc) {
        g1 = sigm(a.pdots[194 + t] + a.sc[128 + b] + a.gb[1]);
        v = 2.f * a.pdots[97 + t] + g1 * a.sc[160 + b];
    }
    if (jt == 0 && kseg == 0 && t < Cc) a.g1buf[(size_t)b * Cc + t] = g1;
    float m = v;
#pragma unroll
    for (int o = 32; o > 0; o >>= 1) m = fmaxf(m, __shfl_down(m, o, 64));
    if ((t & 63) == 0) shr[t >> 6] = m;
    __syncthreads();
    m = fmaxf(fmaxf(shr[0], shr[1]), fmaxf(shr[2], shr[3]));
    __syncthreads();
    float e = (t < Cc) ? expf(v - m) : 0.f;
    float s = blk_sum4(e, shr);
    float wc = e / s;
    if (t < Cc) lw[t] = wc;
    float cg1 = blk_sum4(wc * g1, shr);   // publishes lw
    if (t < 96) {
        int d = kseg * 96 + t;
        const float* pc = a.p0b + d;
        float acc2 = 0.f;
#pragma unroll 4
        for (int c = 0; c < Cc; ++c) acc2 += lw[c] * pc[(size_t)c * Dd];
        xs[t] = 2.f * acc2 + cg1 * a.av1[(size_t)b * Dd + d];
    }
    __syncthreads();
    const float* W = a.vw + (size_t)2 * Dd * Dd;
    const float* bias = a.vb + 2 * Dd;
    int j = jt * 256 + t;
    float acc = (kseg == 0) ? bias[j] : 0.f;
    const float* wp = W + (size_t)(kseg * 96) * Dd + j;
#pragma unroll 8
    for (int dd = 0; dd < 96; ++dd) acc += xs[dd] * wp[(size_t)dd * Dd];
    atomicAdd(&a.avx2[(size_t)b * Dd + j], acc);
    const float* da[2]; da[0] = a.gw + 3072; da[1] = a.kvecs + 3 * Dd;
    float* dout = a.sc + 224;
    for (int vv = 0; vv < 2; ++vv) {
        float p = blk_sum4(acc * da[vv][j], shr);
        if (t == 0) atomicAdd(&dout[vv * 32 + b], p);
    }
    __syncthreads();
}

// ---- GEMV bank: out[b,:] += xs@Wseg; avA indexed with stride strA per b (0 = shared row)
__device__ void mm_dev(const KArgs& a, int jlin, const float* S, float gamma,
                       const float* avA, size_t strA, const float* coefA, float multA,
                       const float* avB, const float* coefB, float multB,
                       const float* W, const float* bias, float* outp,
                       int ndots, const float* d0a, const float* d0b,
                       const float* d1a, const float* d2a, const float* d2b,
                       float* dout, float* xs, float* shr) {
    int t = threadIdx.x;
    int jt = jlin % 3, b = (jlin / 3) % 32, kseg = jlin / 96;
    if (t < 96) {
        int d = kseg * 96 + t;
        float v = gamma * S[(size_t)b * Dd + d];
        if (avA) v += multA * coefA[b] * avA[(size_t)b * strA + d];
        if (avB) v += multB * coefB[b] * avB[(size_t)b * Dd + d];
        xs[t] = v;
    }
    __syncthreads();
    int j = jt * 256 + t;
    float acc = (kseg == 0 && bias) ? bias[j] : 0.f;
    const float* wp = W + (size_t)(kseg * 96) * Dd + j;
#pragma unroll 8
    for (int dd = 0; dd < 96; ++dd) acc += xs[dd] * wp[(size_t)dd * Dd];
    atomicAdd(&outp[(size_t)b * Dd + j], acc);
    if (ndots > 0) {
        float wv = d0a[j] + (d0b ? d0b[j] : 0.f);
        float p = blk_sum4(acc * wv, shr);
        if (t == 0) atomicAdd(&dout[b], p);
    }
    if (ndots > 1) {
        float p = blk_sum4(acc * d1a[j], shr);
        if (t == 0) atomicAdd(&dout[32 + b], p);
    }
    if (ndots > 2) {
        float wv = d2a[j] + (d2b ? d2b[j] : 0.f);
        float p = blk_sum4(acc * wv, shr);
        if (t == 0) atomicAdd(&dout[64 + b], p);
    }
}

// ---- ge bank: geb[b,:] += e1@W1seg + e2@W2seg (+fc1b at kseg 0); avx1 is shared row
__device__ void ge_dev(const KArgs& a, int jlin, float* xs, float* xs2) {
    int t = threadIdx.x;
    int jt = jlin % 3, b = (jlin / 3) % 32, kseg = jlin / 96;
    if (t < 96) {
        int d = kseg * 96 + t;
        float a1 = a.avx1v[d], a2 = a.avx2[(size_t)b * Dd + d];
        xs[t]  = (4.f * a.xp1[(size_t)b * Dd + d] + 2.f * a.sc[448 + b] * a1
                  + a.sc[480 + b] * a2) * a.sc[576 + b];
        xs2[t] = (4.f * a.xp2[(size_t)b * Dd + d] + 2.f * a.sc[512 + b] * a1
                  + a.sc[544 + b] * a2) * a.sc[608 + b];
    }
    __syncthreads();
    int j = jt * 256 + t;
    float a1 = 0.f, a2 = 0.f;
    const float* w1 = a.fc1w + (size_t)(Dd + kseg * 96) * Dd + j;
    const float* w2 = a.fc1w + (size_t)(2 * Dd + kseg * 96) * Dd + j;
#pragma unroll 8
    for (int dd = 0; dd < 96; ++dd) {
        a1 += xs[dd] * w1[(size_t)dd * Dd];
        a2 += xs2[dd] * w2[(size_t)dd * Dd];
    }
    float res = a1 + a2 + (kseg == 0 ? a.fc1b[j] : 0.f);
    atomicAdd(&a.geb[(size_t)b * Dd + j], res);
}

// ---- single bank: outp[b,:] += av[b,:]@fc1w0seg
__device__ void aw_one(const KArgs& a, int jlin, const float* av, float* outp, float* xs) {
    int t = threadIdx.x;
    int jt = jlin % 3, b = (jlin / 3) % 32, kseg = jlin / 96;
    if (t < 96) xs[t] = av[(size_t)b * Dd + kseg * 96 + t];
    __syncthreads();
    int j = jt * 256 + t;
    float acc = 0.f;
    const float* wp = a.fc1w + (size_t)(kseg * 96) * Dd + j;
#pragma unroll 8
    for (int dd = 0; dd < 96; ++dd) acc += xs[dd] * wp[(size_t)dd * Dd];
    atomicAdd(&outp[(size_t)b * Dd + j], acc);
}

// ---- passX: recompute softmax weights in-block, then weighted x0 sums
__device__ void passX_dev(const KArgs& a, int phase, int blk, float* S, bool dopos,
                          float* smw, float* shr) {
    int t = threadIdx.x;
    int b = blk >> 4, seg = blk & 15, l0 = seg * 32;
    {
        float w0, w1, u0, u1, u2, u3;
        sm_w(a, phase, b, shr, w0, w1, u0, u1, u2, u3);
        smw[t] = w0; smw[t + 256] = w1;
    }
    __syncthreads();
    if (t < 192) {
        int d4 = t << 2;
        const float* xb = a.x0 + ((size_t)b * Ls + l0) * Dd + d4;
        float4 as = make_float4(0.f,0.f,0.f,0.f);
        float4 a1 = make_float4(0.f,0.f,0.f,0.f);
        float4 a2 = make_float4(0.f,0.f,0.f,0.f);
        for (int l = 0; l < 32; ++l) {
            float4 xv = *(const float4*)(xb + (size_t)l * Dd);
            float wv = smw[l0 + l];
            as.x += wv*xv.x; as.y += wv*xv.y; as.z += wv*xv.z; as.w += wv*xv.w;
            if (dopos) {
                float q1 = a.pos1[(size_t)b * Ls + l0 + l], q2 = a.pos2[(size_t)b * Ls + l0 + l];
                a1.x += q1*xv.x; a1.y += q1*xv.y; a1.z += q1*xv.z; a1.w += q1*xv.w;
                a2.x += q2*xv.x; a2.y += q2*xv.y; a2.z += q2*xv.z; a2.w += q2*xv.w;
            }
        }
        float* ds = S + (size_t)b * Dd + d4;
        atomicAdd(ds+0, as.x); atomicAdd(ds+1, as.y); atomicAdd(ds+2, as.z); atomicAdd(ds+3, as.w);
        if (dopos) {
            float* d1 = a.xp1 + (size_t)b * Dd + d4;
            float* d2 = a.xp2 + (size_t)b * Dd + d4;
            atomicAdd(d1+0, a1.x); atomicAdd(d1+1, a1.y); atomicAdd(d1+2, a1.z); atomicAdd(d1+3, a1.w);
            atomicAdd(d2+0, a2.x); atomicAdd(d2+1, a2.y); atomicAdd(d2+2, a2.z); atomicAdd(d2+3, a2.w);
        }
    }
}

// ---- kvec dots body
__device__ void kvec_dot(const KArgs& a, int dot, int lane) {
    int idx = dot / Dd, d = dot - idx * Dd;
    const float* row = a.kw + ((size_t)idx * Dd + d) * Dd;
    const float* swk = a.sw + (size_t)idx * 2 * Dd + Dd;
    float sA = 0.f;
    for (int j = lane; j < Dd; j += 64) sA += row[j] * swk[j];
    sA = wred(sA);
    if (lane == 0) a.kvecs[dot] = sA;
}

// ---- xdots body: wave-per-row over rows [r0, Bb*Ls) step rstep
__device__ void xdots_dev(const KArgs& a, int r0, int rstep, int lane) {
    float4 gs0[3], k1r[3], gs2[3], k3r[3];
#pragma unroll
    for (int k = 0; k < 3; ++k) {
        int d = (lane << 2) + k * 256;
        float4 ga = *(const float4*)(a.gw + d);
        float4 gbv = *(const float4*)(a.gw + 768 + d);
        gs0[k] = make_float4(ga.x+gbv.x, ga.y+gbv.y, ga.z+gbv.z, ga.w+gbv.w);
        k1r[k] = *(const float4*)(a.kvecs + 768 + d);
        float4 g2a = *(const float4*)(a.gw + 3072 + d);
        float4 g2b = *(const float4*)(a.gw + 3840 + d);
        gs2[k] = make_float4(g2a.x+g2b.x, g2a.y+g2b.y, g2a.z+g2b.z, g2a.w+g2b.w);
        k3r[k] = *(const float4*)(a.kvecs + 2304 + d);
    }
    for (int r = r0; r < Bb * Ls; r += rstep) {
        const float* xr = a.x0 + (size_t)r * Dd;
        float s0 = 0.f, s1 = 0.f, s2 = 0.f, s3 = 0.f;
#pragma unroll
        for (int k = 0; k < 3; ++k) {
            float4 xv = *(const float4*)(xr + (lane << 2) + k * 256);
            s0 += xv.x*gs0[k].x + xv.y*gs0[k].y + xv.z*gs0[k].z + xv.w*gs0[k].w;
            s1 += xv.x*k1r[k].x + xv.y*k1r[k].y + xv.z*k1r[k].z + xv.w*k1r[k].w;
            s2 += xv.x*gs2[k].x + xv.y*gs2[k].y + xv.z*gs2[k].z + xv.w*gs2[k].w;
            s3 += xv.x*k3r[k].x + xv.y*k3r[k].y + xv.z*k3r[k].z + xv.w*k3r[k].w;
        }
        s0 = wred(s0); s1 = wred(s1); s2 = wred(s2); s3 = wred(s3);
        if (lane == 0) {
            float4 o4 = make_float4(s0, s1, s2, s3);
            *(float4*)(a.xd + (size_t)r * 4) = o4;
        }
    }
}

// ---- pdots body
__device__ void pdots_dev(const KArgs& a, int g2, int lane) {
    for (int k = 0; k < 4; ++k) {
        int j = g2 + k * 128;
        if (k == 3) { if (g2 >= 4) break; j = 384 + g2; }
        if (j >= 388) continue;
        int vv = j / Cc, r = j - vv * Cc;
        const float* va; const float* vb2 = nullptr;
        if (vv == 0) va = a.kvecs;
        else if (vv == 1) va = a.kvecs + 2 * Dd;
        else if (vv == 2) { va = a.gw + 1536; vb2 = a.gw + 2304; }
        else { va = a.gw + 4608; vb2 = a.gw + 5376; }
        const float* row = a.p0b + (size_t)r * Dd;
        float sA = 0.f;
        for (int jj = lane; jj < Dd; jj += 64)
            sA += row[jj] * (va[jj] + (vb2 ? vb2[jj] : 0.f));
        sA = wred(sA);
        if (lane == 0) a.pdots[j] = sA;
    }
}

// ---- logits body
__device__ void logits_dev(const KArgs& a, int r, float* shr) {
    int t = threadIdx.x;
    int b = r / Cc, c = r - b * Cc;
    float g1 = a.g1buf[r];
    float g2 = sigm(2.f * a.pdots[291 + c] + g1 * a.sc[192 + b] + a.sc[288 + b] + a.gb[3]);
    float ssum = 0.f;
#pragma unroll
    for (int sseg = 0; sseg < 3; ++sseg) {
        int d = t + sseg * 256;
        float h = tanhf(4.f * a.pp[(size_t)c * Dd + d]
                      + 2.f * g1 * a.aw1[(size_t)b * Dd + d]
                      + g2 * a.aw2[(size_t)b * Dd + d]
                      + a.geb[(size_t)b * Dd + d]);
        ssum += h * a.fc2w[d];
    }
    float tt = blk_sum4(ssum, shr);
    if (t == 0) a.out[r] = sigm(tt + a.fc2b[0]);
}

// ================= kernels (11-launch pipeline + small memset) =================
// K1: gemm1 split-K (192) || kvec dots + zero accumulators (320)
__global__ __launch_bounds__(NTHR) void k_g1kv(KArgs a) {
    __shared__ float As[1024], Ws[1024];
    int blk = blockIdx.x, t = threadIdx.x;
    int wv_ = t >> 6, lane = t & 63;
    if (blk < 192) {
        sgemm_dev(a.emb, a.rel_w, a.rel_b, a.p0b, Cc, Dd, Dd, 96,
                  blk % 12, (blk / 12) % 2, blk / 24, As, Ws);
    } else {
        for (size_t i = (size_t)(blk - 192) * NTHR + t; i < (size_t)a.zcount;
             i += (size_t)(NBLK - 192) * NTHR)
            a.zbase[i] = 0.f;
        for (int dot = (blk - 192) * 4 + wv_; dot < 3072; dot += (NBLK - 192) * 4)
            kvec_dot(a, dot, lane);
    }
}

// K2: ppGEMM split-K (96) || pdots (32)
__global__ __launch_bounds__(NTHR) void k_prep2(KArgs a) {
    __shared__ float As[1024], Ws[1024];
    int blk = blockIdx.x, t = threadIdx.x;
    int wv_ = t >> 6, lane = t & 63;
    if (blk < 96) {
        sgemm_dev(a.p0b, a.fc1w, nullptr, a.pp, Cc, Dd, Dd, 192,
                  blk % 12, (blk / 12) % 2, blk / 24, As, Ws);
    } else {
        pdots_dev(a, (blk - 96) * 4 + wv_, lane);
    }
}

// K3: attn phase 0 (24, batch-free) || xdots (744)
__global__ __launch_bounds__(NTHR) void k_attn0x(KArgs a) {
    __shared__ float xs[96], lw[128], shr[16];
    int blk = blockIdx.x, t = threadIdx.x;
    int wv_ = t >> 6, lane = t & 63;
    if (blk < 24) attn0_gemv(a, blk, xs, lw, shr);
    else xdots_dev(a, (blk - 24) * 4 + wv_, 744 * 4, lane);
}

// K4: passX0 (512) || coeff0 (32)
__global__ __launch_bounds__(NTHR) void k_p3(KArgs a) {
    __shared__ float smw[512], shr[16];
    int blk = blockIdx.x;
    if (blk < 512) passX_dev(a, 0, blk, a.S0, true, smw, shr);
    else coeff0_dev(a, blk - 512, shr);
}

// K5: mm0 -> av1 (avA = shared avx1v row)
__global__ __launch_bounds__(NTHR) void k_mm0(KArgs a) {
    __shared__ float xs[96], shr[16];
    mm_dev(a, blockIdx.x, a.S0, 2.f, a.avx1v, 0, a.sc + 320, 1.f, nullptr, nullptr, 0.f,
           a.vw + (size_t)1 * Dd * Dd, a.vb + Dd, a.av1,
           3, a.gw + 1536, nullptr, a.kvecs + 2 * Dd, a.gw + 4608, a.gw + 5376,
           a.sc + 128, xs, shr);
}

// K6: attn phase 1 (768) || aw1 (768)
__global__ __launch_bounds__(NTHR) void k_p5(KArgs a) {
    __shared__ float xs[96], lw[128], shr[16];
    int blk = blockIdx.x;
    if (blk < 768) attn1_gemv(a, blk, xs, lw, shr);
    else aw_one(a, blk - 768, a.av1, a.aw1, xs);
}

// K7: passX1 (512) || coeff1 (32)
__global__ __launch_bounds__(NTHR) void k_p6(KArgs a) {
    __shared__ float smw[512], shr[16];
    int blk = blockIdx.x;
    if (blk < 512) passX_dev(a, 1, blk, a.S1, false, smw, shr);
    else coeff1_dev(a, blk - 512, shr);
}

// K8: mm1 (768) || ge (768)
__global__ __launch_bounds__(NTHR) void k_p7(KArgs a) {
    __shared__ float xs[96], xs2[96], shr[16];
    int blk = blockIdx.x;
    if (blk < 768)
        mm_dev(a, blk, a.S1, 4.f, a.avx1v, 0, a.sc + 352, 2.f, a.avx2, a.sc + 384, 1.f,
               a.vw + (size_t)3 * Dd * Dd, a.vb + 3 * Dd, a.av2,
               1, a.gw + 4608, nullptr, nullptr, nullptr, nullptr,
               a.sc + 288, xs, shr);
    else ge_dev(a, blk - 768, xs, xs2);
}

// K9: aw2
__global__ __launch_bounds__(NTHR) void k_aw2(KArgs a) {
    __shared__ float xs[96];
    aw_one(a, blockIdx.x, a.av2, a.aw2, xs);
}

// K10: logits — one row per block (3104 blocks)
__global__ __launch_bounds__(NTHR) void k_logits(KArgs a) {
    __shared__ float shr[16];
    logits_dev(a, blockIdx.x, shr);
}

// K11: argmax
__global__ void k_argmax(KArgs a) {
    int t = threadIdx.x;
    if (t < Bb) {
        const float* row = a.out + (size_t)t * Cc;
        float best = row[0];
        int bi = 0;
        for (int c = 1; c < Cc; ++c) {
            float v = row[c];
            if (v > best) { best = v; bi = c; }
        }
        a.out[Bb * Cc + t] = (float)bi;
    }
}

extern "C" void kernel_launch(void* const* d_in, const int* in_sizes, int n_in,
                              void* d_out, int out_size, void* d_ws, size_t ws_size,
                              hipStream_t stream) {
    KArgs ka;
    ka.x0    = (const float*)d_in[0];
    ka.pos1  = (const float*)d_in[1];
    ka.pos2  = (const float*)d_in[2];
    ka.mask  = (const int*)d_in[3];
    ka.emb   = (const float*)d_in[4];
    ka.rel_w = (const float*)d_in[5];
    ka.rel_b = (const float*)d_in[6];
    // qw(7), qb(8) dead (softmax shift-invariance); kb(10), sb(14) dead (row-constant)
    ka.kw    = (const float*)d_in[9];
    ka.vw    = (const float*)d_in[11];
    ka.vb    = (const float*)d_in[12];
    ka.sw    = (const float*)d_in[13];
    ka.gw    = (const float*)d_in[15];
    ka.gb    = (const float*)d_in[16];
    ka.fc1w  = (const float*)d_in[17];
    ka.fc1b  = (const float*)d_in[18];
    ka.fc2w  = (const float*)d_in[19];
    ka.fc2b  = (const float*)d_in[20];
    ka.out   = (float*)d_out;

    float* ws = (float*)d_ws;
    size_t off = 0;
    const size_t PD = (size_t)Cc * Dd;
    const size_t BD = (size_t)Bb * Dd;
    // memset'd region (K1/K2 atomic targets, needed before K1): p0b, pp
    ka.p0b  = ws + off; off += PD;
    ka.pp   = ws + off; off += PD;
    size_t zbytes = off * sizeof(float);
    // zeroed in K1's kvec-blocks (first consumed in K3): sc .. geb
    size_t zstart = off;
    ka.sc    = ws + off; off += 640;
    ka.avx1v = ws + off; off += Dd;
    ka.avx2  = ws + off; off += BD;
    ka.av1   = ws + off; off += BD;
    ka.av2   = ws + off; off += BD;
    ka.aw1   = ws + off; off += BD;
    ka.aw2   = ws + off; off += BD;
    ka.S0    = ws + off; off += BD;
    ka.S1    = ws + off; off += BD;
    ka.xp1   = ws + off; off += BD;
    ka.xp2   = ws + off; off += BD;
    ka.geb   = ws + off; off += BD;
    ka.zbase = ws + zstart;
    ka.zcount = (int)(off - zstart);
    // plain-store buffers (no zeroing needed)
    ka.kvecs = ws + off; off += (size_t)4 * Dd;
    ka.pdots = ws + off; off += 388;
    ka.g1buf = ws + off; off += (size_t)Bb * Cc;
    ka.xd    = ws + off; off += (size_t)Bb * Ls * 4;

    hipMemsetAsync((void*)ws, 0, zbytes, stream);
    k_g1kv<<<NBLK, NTHR, 0, stream>>>(ka);
    k_prep2<<<128, NTHR, 0, stream>>>(ka);
    k_attn0x<<<768, NTHR, 0, stream>>>(ka);
    k_p3<<<544, NTHR, 0, stream>>>(ka);
    k_mm0<<<768, NTHR, 0, stream>>>(ka);
    k_p5<<<1536, NTHR, 0, stream>>>(ka);
    k_p6<<<544, NTHR, 0, stream>>>(ka);
    k_p7<<<1536, NTHR, 0, stream>>>(ka);
    k_aw2<<<768, NTHR, 0, stream>>>(ka);
    k_logits<<<Bb * Cc, NTHR, 0, stream>>>(ka);
    k_argmax<<<1, 64, 0, stream>>>(ka);
}